// Round 1
// baseline (876.019 us; speedup 1.0000x reference)
//
#include <hip/hip_runtime.h>
#include <cstdint>
#include <cstddef>

#define B_   16
#define C_   512
#define N_   1024
#define M_   (B_*N_)
#define NH_  8
#define HD_  64
#define C3_  1536
#define CH_  2048

typedef __attribute__((ext_vector_type(8))) short bf16x8;
typedef __attribute__((ext_vector_type(4))) float f32x4;
typedef __attribute__((ext_vector_type(4))) unsigned short u16x4;

__device__ __forceinline__ unsigned short f2bf(float f) {
  union { float f; unsigned u; } v; v.f = f;
  unsigned r = v.u + 0x7fffu + ((v.u >> 16) & 1u);
  return (unsigned short)(r >> 16);
}
__device__ __forceinline__ float bf2f(unsigned short h) {
  union { unsigned u; float f; } v; v.u = ((unsigned)h) << 16;
  return v.f;
}
__device__ __forceinline__ void gl_lds16(const void* g, void* l) {
  __builtin_amdgcn_global_load_lds((const __attribute__((address_space(1))) void*)g,
                                   (__attribute__((address_space(3))) void*)l,
                                   16, 0, 0);
}

// ---------------- float -> bf16 weight conversion ----------------
__global__ __launch_bounds__(256) void k_f2b(const float* __restrict__ src,
                                             unsigned short* __restrict__ dst, int n) {
  int i = blockIdx.x * 256 + threadIdx.x;
  if (i < n) dst[i] = f2bf(src[i]);
}

// ---------------- transpose (B,C,N) f32 -> (B,N,C) f32 ----------------
__global__ __launch_bounds__(256) void k_transpose_cn(const float* __restrict__ x,
                                                      float* __restrict__ tok) {
  __shared__ float s[32][33];
  const int n0 = blockIdx.x * 32, c0 = blockIdx.y * 32, b = blockIdx.z;
  const int j = threadIdx.x & 31, i0 = threadIdx.x >> 5;
  #pragma unroll
  for (int k = 0; k < 4; ++k) {
    int i = i0 + k * 8;
    s[i][j] = x[(size_t)(b * C_ + c0 + i) * N_ + n0 + j];
  }
  __syncthreads();
  #pragma unroll
  for (int k = 0; k < 4; ++k) {
    int i = i0 + k * 8;
    tok[(size_t)(b * N_ + n0 + i) * C_ + c0 + j] = s[j][i];
  }
}

// ---------------- transpose (B,N,C) f32 -> (B,C,N) f32 ----------------
__global__ __launch_bounds__(256) void k_transpose_nc(const float* __restrict__ in,
                                                      float* __restrict__ out) {
  __shared__ float s[32][33];
  const int n0 = blockIdx.x * 32, c0 = blockIdx.y * 32, b = blockIdx.z;
  const int j = threadIdx.x & 31, i0 = threadIdx.x >> 5;
  #pragma unroll
  for (int k = 0; k < 4; ++k) {
    int i = i0 + k * 8;
    s[i][j] = in[(size_t)(b * N_ + n0 + i) * C_ + c0 + j];
  }
  __syncthreads();
  #pragma unroll
  for (int k = 0; k < 4; ++k) {
    int i = i0 + k * 8;
    out[(size_t)(b * C_ + c0 + i) * N_ + n0 + j] = s[j][i];
  }
}

// ---------------- V repack: qkv (M,1536) bf16 -> vt (B,NH,HD,N) bf16 ----------------
__global__ __launch_bounds__(256) void k_vrepack(const unsigned short* __restrict__ qkv,
                                                 unsigned short* __restrict__ vtg) {
  __shared__ unsigned short s[32][34];
  const int n0 = blockIdx.x * 32, d0 = blockIdx.y * 32, bh = blockIdx.z;
  const int b = bh >> 3, h = bh & 7;
  const int j = threadIdx.x & 31, i0 = threadIdx.x >> 5;
  #pragma unroll
  for (int k = 0; k < 4; ++k) {
    int i = i0 + k * 8;  // n-local
    s[i][j] = qkv[(size_t)(b * N_ + n0 + i) * C3_ + 1024 + h * 64 + d0 + j];
  }
  __syncthreads();
  #pragma unroll
  for (int k = 0; k < 4; ++k) {
    int i = i0 + k * 8;  // d-local
    vtg[(size_t)(bh * HD_ + d0 + i) * N_ + n0 + j] = s[j][i];
  }
}

// ---------------- LayerNorm (+ optional lf/hf head gates) ----------------
template<bool WITH>
__global__ __launch_bounds__(256) void k_ln(const float* __restrict__ tok,
    const float* __restrict__ w, const float* __restrict__ bia,
    const float* __restrict__ lfw, const float* __restrict__ lfb,
    const float* __restrict__ hfw, const float* __restrict__ hfb,
    const float* __restrict__ pa_s, const float* __restrict__ pa_b,
    unsigned short* __restrict__ lnout, float* __restrict__ lfout,
    float* __restrict__ hfout) {
  const int t = threadIdx.x, wv = t >> 6, l = t & 63;
  const int row = blockIdx.x * 4 + wv;
  const float* p = tok + (size_t)row * C_;
  float v[8];
  *(float4*)&v[0] = *(const float4*)(p + 4 * l);
  *(float4*)&v[4] = *(const float4*)(p + 256 + 4 * l);
  float s = 0.f, q = 0.f;
  #pragma unroll
  for (int i = 0; i < 8; ++i) { s += v[i]; q += v[i] * v[i]; }
  #pragma unroll
  for (int off = 1; off < 64; off <<= 1) { s += __shfl_xor(s, off); q += __shfl_xor(q, off); }
  float mu = s * (1.f / 512.f);
  float var = q * (1.f / 512.f) - mu * mu;
  float rstd = rsqrtf(var + 1e-5f);
  float wv8[8], bv8[8];
  *(float4*)&wv8[0] = *(const float4*)(w + 4 * l);
  *(float4*)&wv8[4] = *(const float4*)(w + 256 + 4 * l);
  *(float4*)&bv8[0] = *(const float4*)(bia + 4 * l);
  *(float4*)&bv8[4] = *(const float4*)(bia + 256 + 4 * l);
  float ln[8];
  #pragma unroll
  for (int i = 0; i < 8; ++i) ln[i] = (v[i] - mu) * rstd * wv8[i] + bv8[i];
  u16x4 o0 = { f2bf(ln[0]), f2bf(ln[1]), f2bf(ln[2]), f2bf(ln[3]) };
  u16x4 o1 = { f2bf(ln[4]), f2bf(ln[5]), f2bf(ln[6]), f2bf(ln[7]) };
  *(u16x4*)(lnout + (size_t)row * C_ + 4 * l) = o0;
  *(u16x4*)(lnout + (size_t)row * C_ + 256 + 4 * l) = o1;
  if (WITH) {
    float ps = pa_s[0], pb = pa_b[0];
    float d[8];
    #pragma unroll
    for (int i = 0; i < 8; ++i) { float r = fmaxf(ln[i], 0.f); d[i] = ps * r * r + pb; }
    float lacc[8], hacc[8];
    #pragma unroll
    for (int h = 0; h < 8; ++h) {
      float lw[8], hw[8];
      *(float4*)&lw[0] = *(const float4*)(lfw + h * C_ + 4 * l);
      *(float4*)&lw[4] = *(const float4*)(lfw + h * C_ + 256 + 4 * l);
      *(float4*)&hw[0] = *(const float4*)(hfw + h * C_ + 4 * l);
      *(float4*)&hw[4] = *(const float4*)(hfw + h * C_ + 256 + 4 * l);
      float la = 0.f, ha = 0.f;
      #pragma unroll
      for (int i = 0; i < 8; ++i) { la += d[i] * lw[i]; ha += d[i] * hw[i]; }
      lacc[h] = la; hacc[h] = ha;
    }
    #pragma unroll
    for (int h = 0; h < 8; ++h)
      #pragma unroll
      for (int off = 1; off < 64; off <<= 1) {
        lacc[h] += __shfl_xor(lacc[h], off);
        hacc[h] += __shfl_xor(hacc[h], off);
      }
    float lv = lacc[0], hv = hacc[0];
    #pragma unroll
    for (int h = 1; h < 8; ++h) { if (l == h) { lv = lacc[h]; hv = hacc[h]; } }
    if (l < 8) {
      lfout[(size_t)row * 8 + l] = tanhf(lv + lfb[l]);
      float z = hv + hfb[l];
      float sp = (z > 15.f) ? z : log1pf(__expf(z));
      float s2 = sp * sp;
      hfout[(size_t)row * 8 + l] = 2.f * s2 / (s2 + 0.3678f);
    }
  }
}

// ---------------- GEMM: A(M,K)bf16 x Bt(N,K)bf16, 128x128 tile ----------------
// EPI: 0 = bf16 out no bias (qkv); 1 = f32 out + bias (proj);
//      2 = bf16 out + bias + gelu (fc1); 3 = f32 out + bias (fc2)
template<int EPI>
__global__ __launch_bounds__(256) void k_gemm(const unsigned short* __restrict__ A,
    const unsigned short* __restrict__ Bt, const float* __restrict__ bias,
    void* __restrict__ outv, int Nn, int K) {
  __shared__ unsigned short Asm[128 * 32];
  __shared__ unsigned short Bsm[128 * 32];
  const int t = threadIdx.x, w = t >> 6, l = t & 63;
  const int lane15 = l & 15, quad = l >> 4;
  const int n0 = blockIdx.x * 128, m0 = blockIdx.y * 128;
  const int wm = w >> 1, wn = w & 1;
  f32x4 acc[4][4];
  #pragma unroll
  for (int i = 0; i < 4; ++i)
    #pragma unroll
    for (int j = 0; j < 4; ++j) acc[i][j] = (f32x4){0.f, 0.f, 0.f, 0.f};
  const unsigned short* Ab = A + (size_t)(m0 + (t >> 2)) * K + (t & 3) * 8;
  const unsigned short* Bb = Bt + (size_t)(n0 + (t >> 2)) * K + (t & 3) * 8;
  char* lA = (char*)Asm + w * 1024;
  char* lB = (char*)Bsm + w * 1024;
  const size_t rstep = (size_t)64 * K;
  for (int k0 = 0; k0 < K; k0 += 32) {
    gl_lds16(Ab + k0, lA);
    gl_lds16(Ab + rstep + k0, lA + 4096);
    gl_lds16(Bb + k0, lB);
    gl_lds16(Bb + rstep + k0, lB + 4096);
    __syncthreads();
    bf16x8 af[4], bg[4];
    #pragma unroll
    for (int i = 0; i < 4; ++i)
      af[i] = *(const bf16x8*)&Asm[(wm * 64 + i * 16 + lane15) * 32 + quad * 8];
    #pragma unroll
    for (int i = 0; i < 4; ++i)
      bg[i] = *(const bf16x8*)&Bsm[(wn * 64 + i * 16 + lane15) * 32 + quad * 8];
    #pragma unroll
    for (int i = 0; i < 4; ++i)
      #pragma unroll
      for (int j = 0; j < 4; ++j)
        acc[i][j] = __builtin_amdgcn_mfma_f32_16x16x32_bf16(af[i], bg[j], acc[i][j], 0, 0, 0);
    __syncthreads();
  }
  #pragma unroll
  for (int i = 0; i < 4; ++i) {
    int grow = m0 + wm * 64 + i * 16 + quad * 4;
    #pragma unroll
    for (int j = 0; j < 4; ++j) {
      int gcol = n0 + wn * 64 + j * 16 + lane15;
      float bs = (EPI == 0) ? 0.f : bias[gcol];
      #pragma unroll
      for (int r = 0; r < 4; ++r) {
        float vv = acc[i][j][r] + bs;
        size_t o = (size_t)(grow + r) * Nn + gcol;
        if (EPI == 0) ((unsigned short*)outv)[o] = f2bf(vv);
        else if (EPI == 1 || EPI == 3) ((float*)outv)[o] = vv;
        else {
          float g = 0.5f * vv * (1.f + erff(vv * 0.70710678118f));
          ((unsigned short*)outv)[o] = f2bf(g);
        }
      }
    }
  }
}

// ---------------- flash attention: per (b,h), 64-row Q tiles ----------------
__global__ __launch_bounds__(256) void k_flash(const unsigned short* __restrict__ qkv,
    const unsigned short* __restrict__ vtg, float* __restrict__ out) {
  const int t = threadIdx.x, w = t >> 6, l = t & 63;
  const int lane15 = l & 15, quad = l >> 4;
  const int q0 = blockIdx.x * 64;
  const int h = blockIdx.y, b = blockIdx.z;
  __shared__ unsigned short kt[64 * 64];
  __shared__ unsigned short vt[64 * 64];
  __shared__ unsigned short pl[4][16 * 72];

  bf16x8 aq0, aq1;
  {
    const unsigned short* qp = qkv + (size_t)(b * N_ + q0 + w * 16 + lane15) * C3_ + h * 64 + quad * 8;
    aq0 = *(const bf16x8*)qp;
    aq1 = *(const bf16x8*)(qp + 32);
  }
  f32x4 O[4];
  #pragma unroll
  for (int i = 0; i < 4; ++i) O[i] = (f32x4){0.f, 0.f, 0.f, 0.f};
  float mrun[4], lrun[4];
  #pragma unroll
  for (int r = 0; r < 4; ++r) { mrun[r] = -1e30f; lrun[r] = 0.f; }

  const unsigned short* kb = qkv + (size_t)(b * N_ + (t >> 3)) * C3_ + 512 + h * 64 + (t & 7) * 8;
  const unsigned short* vb = vtg + (size_t)((b * NH_ + h) * HD_ + (t >> 3)) * N_ + (t & 7) * 8;
  char* lK = (char*)kt + w * 1024;
  char* lV = (char*)vt + w * 1024;

  for (int kti = 0; kti < 16; ++kti) {
    gl_lds16(kb + (size_t)(kti * 64) * C3_, lK);
    gl_lds16(kb + (size_t)(kti * 64 + 32) * C3_, lK + 4096);
    gl_lds16(vb + kti * 64, lV);
    gl_lds16(vb + (size_t)32 * N_ + kti * 64, lV + 4096);
    __syncthreads();

    f32x4 S[4];
    #pragma unroll
    for (int nt = 0; nt < 4; ++nt) {
      bf16x8 bk0 = *(const bf16x8*)&kt[(nt * 16 + lane15) * 64 + quad * 8];
      bf16x8 bk1 = *(const bf16x8*)&kt[(nt * 16 + lane15) * 64 + 32 + quad * 8];
      f32x4 z = (f32x4){0.f, 0.f, 0.f, 0.f};
      z = __builtin_amdgcn_mfma_f32_16x16x32_bf16(aq0, bk0, z, 0, 0, 0);
      z = __builtin_amdgcn_mfma_f32_16x16x32_bf16(aq1, bk1, z, 0, 0, 0);
      S[nt] = z;
    }
    #pragma unroll
    for (int nt = 0; nt < 4; ++nt) S[nt] *= 0.125f;

    float al[4];
    #pragma unroll
    for (int r = 0; r < 4; ++r) {
      float m1 = fmaxf(fmaxf(S[0][r], S[1][r]), fmaxf(S[2][r], S[3][r]));
      m1 = fmaxf(m1, __shfl_xor(m1, 1));
      m1 = fmaxf(m1, __shfl_xor(m1, 2));
      m1 = fmaxf(m1, __shfl_xor(m1, 4));
      m1 = fmaxf(m1, __shfl_xor(m1, 8));
      float mnew = fmaxf(mrun[r], m1);
      al[r] = __expf(mrun[r] - mnew);
      mrun[r] = mnew;
      float rsum = 0.f;
      #pragma unroll
      for (int nt = 0; nt < 4; ++nt) {
        float pv = __expf(S[nt][r] - mnew);
        S[nt][r] = pv;
        rsum += pv;
      }
      rsum += __shfl_xor(rsum, 1);
      rsum += __shfl_xor(rsum, 2);
      rsum += __shfl_xor(rsum, 4);
      rsum += __shfl_xor(rsum, 8);
      lrun[r] = lrun[r] * al[r] + rsum;
    }
    #pragma unroll
    for (int nt = 0; nt < 4; ++nt)
      #pragma unroll
      for (int r = 0; r < 4; ++r)
        pl[w][(quad * 4 + r) * 72 + nt * 16 + lane15] = f2bf(S[nt][r]);
    #pragma unroll
    for (int dt = 0; dt < 4; ++dt)
      #pragma unroll
      for (int r = 0; r < 4; ++r) O[dt][r] *= al[r];

    bf16x8 ap0 = *(const bf16x8*)&pl[w][lane15 * 72 + quad * 8];
    bf16x8 ap1 = *(const bf16x8*)&pl[w][lane15 * 72 + 32 + quad * 8];
    #pragma unroll
    for (int dt = 0; dt < 4; ++dt) {
      bf16x8 bv0 = *(const bf16x8*)&vt[(dt * 16 + lane15) * 64 + quad * 8];
      bf16x8 bv1 = *(const bf16x8*)&vt[(dt * 16 + lane15) * 64 + 32 + quad * 8];
      O[dt] = __builtin_amdgcn_mfma_f32_16x16x32_bf16(ap0, bv0, O[dt], 0, 0, 0);
      O[dt] = __builtin_amdgcn_mfma_f32_16x16x32_bf16(ap1, bv1, O[dt], 0, 0, 0);
    }
    __syncthreads();
  }
  float inv[4];
  #pragma unroll
  for (int r = 0; r < 4; ++r) inv[r] = 1.f / lrun[r];
  size_t ob = (size_t)(b * N_ + q0 + w * 16) * C_ + h * 64;
  #pragma unroll
  for (int dt = 0; dt < 4; ++dt)
    #pragma unroll
    for (int r = 0; r < 4; ++r)
      out[ob + (size_t)(quad * 4 + r) * C_ + dt * 16 + lane15] = O[dt][r] * inv[r];
}

// ---------------- attention epilogue fuse -> y bf16 ----------------
__global__ __launch_bounds__(256) void k_fuse(const float* __restrict__ ao,
    const unsigned short* __restrict__ qkv, const float* __restrict__ lf,
    const float* __restrict__ hf, const float* __restrict__ lg,
    const float* __restrict__ hg, unsigned short* __restrict__ y) {
  int i = blockIdx.x * 256 + threadIdx.x;
  size_t e = (size_t)i * 4;
  int row = (int)(e >> 9);
  int c = (int)(e & 511);
  int hh = c >> 6;
  float4 a = *(const float4*)(ao + e);
  u16x4 vv = *(const u16x4*)(qkv + (size_t)row * C3_ + 1024 + c);
  float lfv = lf[row * 8 + hh];
  float hfv = hf[row * 8 + hh];
  float4 lg4 = *(const float4*)(lg + c);
  float4 hg4 = *(const float4*)(hg + c);
  float r0 = a.x + a.x * lfv * lg4.x + hfv * (bf2f(vv[0]) - a.x) * hg4.x;
  float r1 = a.y + a.y * lfv * lg4.y + hfv * (bf2f(vv[1]) - a.y) * hg4.y;
  float r2 = a.z + a.z * lfv * lg4.z + hfv * (bf2f(vv[2]) - a.z) * hg4.z;
  float r3 = a.w + a.w * lfv * lg4.w + hfv * (bf2f(vv[3]) - a.w) * hg4.w;
  u16x4 o = { f2bf(r0), f2bf(r1), f2bf(r2), f2bf(r3) };
  *(u16x4*)(y + e) = o;
}

// ---------------- spatial mean pool per (b,c) row ----------------
__global__ __launch_bounds__(256) void k_pool(const float* __restrict__ feat,
                                              float* __restrict__ pooled) {
  int row = blockIdx.x * 4 + (threadIdx.x >> 6);
  int l = threadIdx.x & 63;
  const float4* p = (const float4*)(feat + (size_t)row * N_);
  float4 a = p[l], b4 = p[l + 64], c4 = p[l + 128], d4 = p[l + 192];
  float s = a.x + a.y + a.z + a.w + b4.x + b4.y + b4.z + b4.w +
            c4.x + c4.y + c4.z + c4.w + d4.x + d4.y + d4.z + d4.w;
  #pragma unroll
  for (int off = 1; off < 64; off <<= 1) s += __shfl_xor(s, off);
  if (l == 0) pooled[row] = s * (1.f / 1024.f);
}

// ---------------- routing: pooled(B,C) -> routing(B,64) ----------------
__global__ __launch_bounds__(256) void k_routing(const float* __restrict__ pooled,
    const float* __restrict__ rw1, const float* __restrict__ rw1s,
    const float* __restrict__ rw1b, const float* __restrict__ rw2,
    float* __restrict__ routing) {
  const int b = blockIdx.x, t = threadIdx.x;
  __shared__ float plds[512];
  __shared__ float tile[64][65];
  __shared__ float hl[64];
  plds[t] = pooled[b * 512 + t];
  plds[t + 256] = pooled[b * 512 + t + 256];
  __syncthreads();
  float acc = 0.f;
  for (int c0 = 0; c0 < 512; c0 += 64) {
    #pragma unroll
    for (int kk = 0; kk < 16; ++kk) {
      int idx = kk * 256 + t;
      tile[idx >> 6][idx & 63] = rw1[(size_t)(idx >> 6) * 512 + c0 + (idx & 63)];
    }
    __syncthreads();
    if (t < 64) {
      #pragma unroll
      for (int i = 0; i < 64; ++i) acc += plds[c0 + i] * tile[t][i];
    }
    __syncthreads();
  }
  if (t < 64) {
    float r = fmaxf(acc, 0.f);
    hl[t] = rw1s[0] * r * r + rw1b[0];
  }
  __syncthreads();
  if (t < 64) {
    float r2 = 0.f;
    #pragma unroll
    for (int j = 0; j < 64; ++j) r2 += hl[j] * rw2[(size_t)t * 64 + j];
    routing[b * 64 + t] = tanhf(r2);
  }
}

// ---------------- per-plane 32x32 rfft2 * dyn -> irfft2 (+ residual plane) ----------------
__global__ __launch_bounds__(256) void k_freq(const float* __restrict__ feat,
    const float* __restrict__ routing, const float* __restrict__ fwtab,
    float* __restrict__ enh) {
  const int c = blockIdx.x, b = blockIdx.y, t = threadIdx.x;
  const int g = c >> 5, cc = c & 31;
  __shared__ float p[32 * 36];
  __shared__ float2 A2[32 * 17];
  __shared__ float2 G2[32 * 17];
  __shared__ float2 Z2[32 * 18];
  __shared__ float Ms[544];
  const size_t base = (size_t)(b * C_ + c) * N_;
  const float PI2_32 = 0.19634954084936207f;  // 2*pi/32

  #pragma unroll
  for (int k = 0; k < 4; ++k) {
    int n = k * 256 + t;
    p[(n >> 5) * 36 + (n & 31)] = feat[base + n];
  }
  float r0 = routing[b * 64 + g * 4 + 0];
  float r1 = routing[b * 64 + g * 4 + 1];
  float r2 = routing[b * 64 + g * 4 + 2];
  float r3 = routing[b * 64 + g * 4 + 3];
  for (int o = t; o < 544; o += 256) {
    float mv = r0 * fwtab[(0 * 32 + cc) * 544 + o] + r1 * fwtab[(1 * 32 + cc) * 544 + o] +
               r2 * fwtab[(2 * 32 + cc) * 544 + o] + r3 * fwtab[(3 * 32 + cc) * 544 + o];
    Ms[o] = mv * (1.f / 1024.f);
  }
  __syncthreads();
  // S1: row rfft (over w), output A2[h][fw], fw 0..16
  {
    int hh = t >> 3, f0 = t & 7;
    float4 pr[8];
    #pragma unroll
    for (int kk = 0; kk < 8; ++kk) pr[kk] = *(const float4*)&p[hh * 36 + kk * 4];
    for (int fw = f0; fw <= 16; fw += 8) {
      float dsn, dc;
      __sincosf(PI2_32 * (float)fw, &dsn, &dc);
      float cr = 1.f, si = 0.f, Re = 0.f, Im = 0.f;
      #pragma unroll
      for (int ww = 0; ww < 32; ++ww) {
        float pv = pr[ww >> 2][ww & 3];
        Re += pv * cr;
        Im -= pv * si;
        float cn = cr * dc - si * dsn;
        si = si * dc + cr * dsn;
        cr = cn;
      }
      A2[hh * 17 + fw] = make_float2(Re, Im);
    }
  }
  __syncthreads();
  // S2: column fft (over h), outputs (fh, fh+16), then scale by Ms -> G2
  for (int o = t; o < 272; o += 256) {
    int fh = o / 17, fw = o % 17;
    float dsn, dc;
    __sincosf(PI2_32 * (float)fh, &dsn, &dc);
    float cr = 1.f, si = 0.f, er = 0.f, ei = 0.f, odr = 0.f, odi = 0.f;
    #pragma unroll
    for (int hh = 0; hh < 32; ++hh) {
      float2 a = A2[hh * 17 + fw];
      float xr = a.x * cr + a.y * si;   // e^{-i theta}
      float xi = a.y * cr - a.x * si;
      er += xr; ei += xi;
      if (hh & 1) { odr -= xr; odi -= xi; } else { odr += xr; odi += xi; }
      float cn = cr * dc - si * dsn;
      si = si * dc + cr * dsn;
      cr = cn;
    }
    float m0 = Ms[fh * 17 + fw], m1 = Ms[(fh + 16) * 17 + fw];
    G2[fh * 17 + fw] = make_float2(er * m0, ei * m0);
    G2[(fh + 16) * 17 + fw] = make_float2(odr * m1, odi * m1);
  }
  __syncthreads();
  // S3: inverse column fft (over fh), outputs Z2[(h,h+16)][fw]
  for (int o = t; o < 272; o += 256) {
    int hh = o / 17, fw = o % 17;
    float dsn, dc;
    __sincosf(PI2_32 * (float)hh, &dsn, &dc);
    float cr = 1.f, si = 0.f, er = 0.f, ei = 0.f, odr = 0.f, odi = 0.f;
    #pragma unroll
    for (int fh = 0; fh < 32; ++fh) {
      float2 gv = G2[fh * 17 + fw];
      float xr = gv.x * cr - gv.y * si;  // e^{+i theta}
      float xi = gv.y * cr + gv.x * si;
      er += xr; ei += xi;
      if (fh & 1) { odr -= xr; odi -= xi; } else { odr += xr; odi += xi; }
      float cn = cr * dc - si * dsn;
      si = si * dc + cr * dsn;
      cr = cn;
    }
    Z2[hh * 18 + fw] = make_float2(er, ei);
    Z2[(hh + 16) * 18 + fw] = make_float2(odr, odi);
  }
  __syncthreads();
  // S4: inverse row rfft with Hermitian weights, outputs (w0, w0+16), add residual
  for (int o = t; o < 512; o += 256) {
    int hh = o >> 4, w0 = o & 15;
    float dsn, dc;
    __sincosf(PI2_32 * (float)w0, &dsn, &dc);
    float cr = 1.f, si = 0.f, ev = 0.f, ov = 0.f;
    #pragma unroll
    for (int fw = 0; fw <= 16; ++fw) {
      float2 z = Z2[hh * 18 + fw];
      float val = z.x * cr - z.y * si;
      float wg = (fw == 0 || fw == 16) ? 1.f : 2.f;
      ev += wg * val;
      ov += (fw & 1) ? -wg * val : wg * val;
      float cn = cr * dc - si * dsn;
      si = si * dc + cr * dsn;
      cr = cn;
    }
    enh[base + hh * 32 + w0] = ev + p[hh * 36 + w0];
    enh[base + hh * 32 + w0 + 16] = ov + p[hh * 36 + w0 + 16];
  }
}

// ---------------- tokens += gamma * enh^T ----------------
__global__ __launch_bounds__(256) void k_add_t(const float* __restrict__ enh,
    const float* __restrict__ gamma, float* __restrict__ tok) {
  __shared__ float s[32][33];
  const int n0 = blockIdx.x * 32, c0 = blockIdx.y * 32, b = blockIdx.z;
  const int j = threadIdx.x & 31, i0 = threadIdx.x >> 5;
  #pragma unroll
  for (int k = 0; k < 4; ++k) {
    int i = i0 + k * 8;
    s[i][j] = enh[(size_t)(b * C_ + c0 + i) * N_ + n0 + j];
  }
  __syncthreads();
  float gv = gamma[c0 + j];
  #pragma unroll
  for (int k = 0; k < 4; ++k) {
    int i = i0 + k * 8;
    size_t o = (size_t)(b * N_ + n0 + i) * C_ + c0 + j;
    tok[o] += gv * s[j][i];
  }
}

// ---------------- final: out = tokens^T + gamma2 * enh ----------------
__global__ __launch_bounds__(256) void k_final(const float* __restrict__ tok,
    const float* __restrict__ gamma, const float* __restrict__ enh,
    float* __restrict__ out) {
  __shared__ float s[32][33];
  const int n0 = blockIdx.x * 32, c0 = blockIdx.y * 32, b = blockIdx.z;
  const int j = threadIdx.x & 31, i0 = threadIdx.x >> 5;
  #pragma unroll
  for (int k = 0; k < 4; ++k) {
    int i = i0 + k * 8;
    s[i][j] = tok[(size_t)(b * N_ + n0 + i) * C_ + c0 + j];
  }
  __syncthreads();
  #pragma unroll
  for (int k = 0; k < 4; ++k) {
    int i = i0 + k * 8;   // c-local
    size_t o = (size_t)(b * C_ + c0 + i) * N_ + n0 + j;
    out[o] = s[j][i] + gamma[c0 + i] * enh[o];
  }
}

// =============================== launch ===============================
extern "C" void kernel_launch(void* const* d_in, const int* in_sizes, int n_in,
                              void* d_out, int out_size, void* d_ws, size_t ws_size,
                              hipStream_t stream) {
  (void)in_sizes; (void)n_in; (void)out_size; (void)ws_size;
  const float* x      = (const float*)d_in[0];
  const float* n1w    = (const float*)d_in[1];
  const float* n1b    = (const float*)d_in[2];
  const float* qkv_w  = (const float*)d_in[3];
  const float* proj_w = (const float*)d_in[4];
  const float* proj_b = (const float*)d_in[5];
  const float* pa_s   = (const float*)d_in[6];
  const float* pa_b   = (const float*)d_in[7];
  const float* lf_w   = (const float*)d_in[8];
  const float* lf_b   = (const float*)d_in[9];
  const float* hf_w   = (const float*)d_in[10];
  const float* hf_b   = (const float*)d_in[11];
  const float* lf_g   = (const float*)d_in[12];
  const float* hf_g   = (const float*)d_in[13];
  const float* f1rw1w = (const float*)d_in[14];
  const float* f1rw1s = (const float*)d_in[15];
  const float* f1rw1b = (const float*)d_in[16];
  const float* f1rw2w = (const float*)d_in[17];
  const float* f1fw   = (const float*)d_in[18];
  const float* gamma1 = (const float*)d_in[19];
  const float* n2w    = (const float*)d_in[20];
  const float* n2b    = (const float*)d_in[21];
  const float* fc1w   = (const float*)d_in[22];
  const float* fc1b   = (const float*)d_in[23];
  const float* fc2w   = (const float*)d_in[24];
  const float* fc2b   = (const float*)d_in[25];
  const float* f2rw1w = (const float*)d_in[26];
  const float* f2rw1s = (const float*)d_in[27];
  const float* f2rw1b = (const float*)d_in[28];
  const float* f2rw2w = (const float*)d_in[29];
  const float* f2fw   = (const float*)d_in[30];
  const float* gamma2 = (const float*)d_in[31];

  char* ws = (char*)d_ws;
  float*          tokens = (float*)(ws + 0);
  float*          f1buf  = (float*)(ws + 33554432ULL);
  float*          f2buf  = (float*)(ws + 67108864ULL);
  float*          f3buf  = (float*)(ws + 100663296ULL);
  unsigned short* regA   = (unsigned short*)(ws + 134217728ULL);  // qkv(50MB) then hact(64MB)
  unsigned short* abuf   = (unsigned short*)(ws + 201326592ULL);
  float*          lfbuf  = (float*)(ws + 218103808ULL);
  float*          hfbuf  = (float*)(ws + 218628096ULL);
  float*          pooled = (float*)(ws + 219152384ULL);
  float*          routing= (float*)(ws + 219185152ULL);
  unsigned short* wq     = (unsigned short*)(ws + 219189248ULL);
  unsigned short* wp     = (unsigned short*)(ws + 220762112ULL);
  unsigned short* w1     = (unsigned short*)(ws + 221286400ULL);
  unsigned short* w2     = (unsigned short*)(ws + 223383552ULL);

  // weights -> bf16
  k_f2b<<<3072, 256, 0, stream>>>(qkv_w, wq, 786432);
  k_f2b<<<1024, 256, 0, stream>>>(proj_w, wp, 262144);
  k_f2b<<<4096, 256, 0, stream>>>(fc1w, w1, 1048576);
  k_f2b<<<4096, 256, 0, stream>>>(fc2w, w2, 1048576);

  // tokens = transpose(x)
  k_transpose_cn<<<dim3(32, 16, 16), 256, 0, stream>>>(x, tokens);
  // LN1 + lf/hf
  k_ln<true><<<4096, 256, 0, stream>>>(tokens, n1w, n1b, lf_w, lf_b, hf_w, hf_b,
                                       pa_s, pa_b, abuf, lfbuf, hfbuf);
  // QKV
  k_gemm<0><<<dim3(12, 128), 256, 0, stream>>>(abuf, wq, n1b, regA, C3_, C_);
  // V repack for flash
  k_vrepack<<<dim3(32, 2, 128), 256, 0, stream>>>(regA, (unsigned short*)f2buf);
  // flash attention -> f1buf (M,512) f32
  k_flash<<<dim3(16, 8, 16), 256, 0, stream>>>(regA, (unsigned short*)f2buf, f1buf);
  // fuse lf/hf gates -> abuf bf16
  k_fuse<<<8192, 256, 0, stream>>>(f1buf, regA, lfbuf, hfbuf, lf_g, hf_g, abuf);
  // proj -> f1buf (M,512) f32
  k_gemm<1><<<dim3(4, 128), 256, 0, stream>>>(abuf, wp, proj_b, f1buf, C_, C_);
  // att_feat (B,C,N)
  k_transpose_nc<<<dim3(32, 16, 16), 256, 0, stream>>>(f1buf, f2buf);
  // freq scale 1
  k_pool<<<2048, 256, 0, stream>>>(f2buf, pooled);
  k_routing<<<16, 256, 0, stream>>>(pooled, f1rw1w, f1rw1s, f1rw1b, f1rw2w, routing);
  k_freq<<<dim3(512, 16), 256, 0, stream>>>(f2buf, routing, f1fw, f3buf);
  // tokens += gamma1 * enh^T
  k_add_t<<<dim3(32, 16, 16), 256, 0, stream>>>(f3buf, gamma1, tokens);
  // LN2
  k_ln<false><<<4096, 256, 0, stream>>>(tokens, n2w, n2b, nullptr, nullptr, nullptr,
                                        nullptr, nullptr, nullptr, abuf, nullptr, nullptr);
  // fc1 + gelu -> regA bf16 (M,2048)
  k_gemm<2><<<dim3(16, 128), 256, 0, stream>>>(abuf, w1, fc1b, regA, CH_, C_);
  // fc2 -> f1buf f32 (M,512)
  k_gemm<3><<<dim3(4, 128), 256, 0, stream>>>(regA, w2, fc2b, f1buf, C_, CH_);
  // mlp_feat (B,C,N)
  k_transpose_nc<<<dim3(32, 16, 16), 256, 0, stream>>>(f1buf, f2buf);
  // freq scale 2
  k_pool<<<2048, 256, 0, stream>>>(f2buf, pooled);
  k_routing<<<16, 256, 0, stream>>>(pooled, f2rw1w, f2rw1s, f2rw1b, f2rw2w, routing);
  k_freq<<<dim3(512, 16), 256, 0, stream>>>(f2buf, routing, f2fw, f3buf);
  // out = tokens^T + gamma2 * enh
  k_final<<<dim3(32, 16, 16), 256, 0, stream>>>(tokens, gamma2, f3buf, (float*)d_out);
}

// Round 2
// 835.195 us; speedup vs baseline: 1.0489x; 1.0489x over previous
//
#include <hip/hip_runtime.h>
#include <cstdint>
#include <cstddef>

#define B_   16
#define C_   512
#define N_   1024
#define M_   (B_*N_)
#define NH_  8
#define HD_  64
#define C3_  1536
#define CH_  2048

typedef __attribute__((ext_vector_type(8))) short bf16x8;
typedef __attribute__((ext_vector_type(4))) float f32x4;
typedef __attribute__((ext_vector_type(4))) unsigned short u16x4;

__device__ __forceinline__ unsigned short f2bf(float f) {
  union { float f; unsigned u; } v; v.f = f;
  unsigned r = v.u + 0x7fffu + ((v.u >> 16) & 1u);
  return (unsigned short)(r >> 16);
}
__device__ __forceinline__ float bf2f(unsigned short h) {
  union { unsigned u; float f; } v; v.u = ((unsigned)h) << 16;
  return v.f;
}
__device__ __forceinline__ unsigned f2u(float f) {
  union { float f; unsigned u; } v; v.f = f; return v.u;
}
__device__ __forceinline__ void gl_lds16(const void* g, void* l) {
  __builtin_amdgcn_global_load_lds((const __attribute__((address_space(1))) void*)g,
                                   (__attribute__((address_space(3))) void*)l,
                                   16, 0, 0);
}

// ---------------- float -> bf16 weight conversion ----------------
__global__ __launch_bounds__(256) void k_f2b(const float* __restrict__ src,
                                             unsigned short* __restrict__ dst, int n) {
  int i = blockIdx.x * 256 + threadIdx.x;
  if (i < n) dst[i] = f2bf(src[i]);
}

// ---------------- transpose (B,C,N) f32 -> (B,N,C) f32 ----------------
__global__ __launch_bounds__(256) void k_transpose_cn(const float* __restrict__ x,
                                                      float* __restrict__ tok) {
  __shared__ float s[32][33];
  const int n0 = blockIdx.x * 32, c0 = blockIdx.y * 32, b = blockIdx.z;
  const int j = threadIdx.x & 31, i0 = threadIdx.x >> 5;
  #pragma unroll
  for (int k = 0; k < 4; ++k) {
    int i = i0 + k * 8;
    s[i][j] = x[(size_t)(b * C_ + c0 + i) * N_ + n0 + j];
  }
  __syncthreads();
  #pragma unroll
  for (int k = 0; k < 4; ++k) {
    int i = i0 + k * 8;
    tok[(size_t)(b * N_ + n0 + i) * C_ + c0 + j] = s[j][i];
  }
}

// ---------------- transpose (B,N,C) f32 -> (B,C,N) f32 ----------------
__global__ __launch_bounds__(256) void k_transpose_nc(const float* __restrict__ in,
                                                      float* __restrict__ out) {
  __shared__ float s[32][33];
  const int n0 = blockIdx.x * 32, c0 = blockIdx.y * 32, b = blockIdx.z;
  const int j = threadIdx.x & 31, i0 = threadIdx.x >> 5;
  #pragma unroll
  for (int k = 0; k < 4; ++k) {
    int i = i0 + k * 8;
    s[i][j] = in[(size_t)(b * N_ + n0 + i) * C_ + c0 + j];
  }
  __syncthreads();
  #pragma unroll
  for (int k = 0; k < 4; ++k) {
    int i = i0 + k * 8;
    out[(size_t)(b * C_ + c0 + i) * N_ + n0 + j] = s[j][i];
  }
}

// ---------------- V repack: qkv (M,1536) bf16 -> vt (B,NH,HD,N) bf16 ----------------
__global__ __launch_bounds__(256) void k_vrepack(const unsigned short* __restrict__ qkv,
                                                 unsigned short* __restrict__ vtg) {
  __shared__ unsigned short s[32][34];
  const int n0 = blockIdx.x * 32, d0 = blockIdx.y * 32, bh = blockIdx.z;
  const int b = bh >> 3, h = bh & 7;
  const int j = threadIdx.x & 31, i0 = threadIdx.x >> 5;
  #pragma unroll
  for (int k = 0; k < 4; ++k) {
    int i = i0 + k * 8;  // n-local
    s[i][j] = qkv[(size_t)(b * N_ + n0 + i) * C3_ + 1024 + h * 64 + d0 + j];
  }
  __syncthreads();
  #pragma unroll
  for (int k = 0; k < 4; ++k) {
    int i = i0 + k * 8;  // d-local
    vtg[(size_t)(bh * HD_ + d0 + i) * N_ + n0 + j] = s[j][i];
  }
}

// ---------------- LayerNorm (+ optional lf/hf head gates) ----------------
template<bool WITH>
__global__ __launch_bounds__(256) void k_ln(const float* __restrict__ tok,
    const float* __restrict__ w, const float* __restrict__ bia,
    const float* __restrict__ lfw, const float* __restrict__ lfb,
    const float* __restrict__ hfw, const float* __restrict__ hfb,
    const float* __restrict__ pa_s, const float* __restrict__ pa_b,
    unsigned short* __restrict__ lnout, float* __restrict__ lfout,
    float* __restrict__ hfout) {
  const int t = threadIdx.x, wv = t >> 6, l = t & 63;
  const int row = blockIdx.x * 4 + wv;
  const float* p = tok + (size_t)row * C_;
  float v[8];
  *(float4*)&v[0] = *(const float4*)(p + 4 * l);
  *(float4*)&v[4] = *(const float4*)(p + 256 + 4 * l);
  float s = 0.f, q = 0.f;
  #pragma unroll
  for (int i = 0; i < 8; ++i) { s += v[i]; q += v[i] * v[i]; }
  #pragma unroll
  for (int off = 1; off < 64; off <<= 1) { s += __shfl_xor(s, off); q += __shfl_xor(q, off); }
  float mu = s * (1.f / 512.f);
  float var = q * (1.f / 512.f) - mu * mu;
  float rstd = rsqrtf(var + 1e-5f);
  float wv8[8], bv8[8];
  *(float4*)&wv8[0] = *(const float4*)(w + 4 * l);
  *(float4*)&wv8[4] = *(const float4*)(w + 256 + 4 * l);
  *(float4*)&bv8[0] = *(const float4*)(bia + 4 * l);
  *(float4*)&bv8[4] = *(const float4*)(bia + 256 + 4 * l);
  float ln[8];
  #pragma unroll
  for (int i = 0; i < 8; ++i) ln[i] = (v[i] - mu) * rstd * wv8[i] + bv8[i];
  u16x4 o0 = { f2bf(ln[0]), f2bf(ln[1]), f2bf(ln[2]), f2bf(ln[3]) };
  u16x4 o1 = { f2bf(ln[4]), f2bf(ln[5]), f2bf(ln[6]), f2bf(ln[7]) };
  *(u16x4*)(lnout + (size_t)row * C_ + 4 * l) = o0;
  *(u16x4*)(lnout + (size_t)row * C_ + 256 + 4 * l) = o1;
  if (WITH) {
    float ps = pa_s[0], pb = pa_b[0];
    float d[8];
    #pragma unroll
    for (int i = 0; i < 8; ++i) { float r = fmaxf(ln[i], 0.f); d[i] = ps * r * r + pb; }
    float lacc[8], hacc[8];
    #pragma unroll
    for (int h = 0; h < 8; ++h) {
      float lw[8], hw[8];
      *(float4*)&lw[0] = *(const float4*)(lfw + h * C_ + 4 * l);
      *(float4*)&lw[4] = *(const float4*)(lfw + h * C_ + 256 + 4 * l);
      *(float4*)&hw[0] = *(const float4*)(hfw + h * C_ + 4 * l);
      *(float4*)&hw[4] = *(const float4*)(hfw + h * C_ + 256 + 4 * l);
      float la = 0.f, ha = 0.f;
      #pragma unroll
      for (int i = 0; i < 8; ++i) { la += d[i] * lw[i]; ha += d[i] * hw[i]; }
      lacc[h] = la; hacc[h] = ha;
    }
    #pragma unroll
    for (int h = 0; h < 8; ++h)
      #pragma unroll
      for (int off = 1; off < 64; off <<= 1) {
        lacc[h] += __shfl_xor(lacc[h], off);
        hacc[h] += __shfl_xor(hacc[h], off);
      }
    float lv = lacc[0], hv = hacc[0];
    #pragma unroll
    for (int h = 1; h < 8; ++h) { if (l == h) { lv = lacc[h]; hv = hacc[h]; } }
    if (l < 8) {
      lfout[(size_t)row * 8 + l] = tanhf(lv + lfb[l]);
      float z = hv + hfb[l];
      float sp = (z > 15.f) ? z : log1pf(__expf(z));
      float s2 = sp * sp;
      hfout[(size_t)row * 8 + l] = 2.f * s2 / (s2 + 0.3678f);
    }
  }
}

// ---------------- GEMM: A(M,K)bf16 x Bt(N,K)bf16, 128x128 tile ----------------
// EPI: 0 = bf16 out no bias (qkv); 1 = f32 out + bias (proj);
//      2 = bf16 out + bias + gelu (fc1); 3 = f32 out + bias (fc2)
template<int EPI>
__global__ __launch_bounds__(256) void k_gemm(const unsigned short* __restrict__ A,
    const unsigned short* __restrict__ Bt, const float* __restrict__ bias,
    void* __restrict__ outv, int Nn, int K) {
  __shared__ unsigned short Asm[128 * 32];
  __shared__ unsigned short Bsm[128 * 32];
  const int t = threadIdx.x, w = t >> 6, l = t & 63;
  const int lane15 = l & 15, quad = l >> 4;
  const int n0 = blockIdx.x * 128, m0 = blockIdx.y * 128;
  const int wm = w >> 1, wn = w & 1;
  f32x4 acc[4][4];
  #pragma unroll
  for (int i = 0; i < 4; ++i)
    #pragma unroll
    for (int j = 0; j < 4; ++j) acc[i][j] = (f32x4){0.f, 0.f, 0.f, 0.f};
  const unsigned short* Ab = A + (size_t)(m0 + (t >> 2)) * K + (t & 3) * 8;
  const unsigned short* Bb = Bt + (size_t)(n0 + (t >> 2)) * K + (t & 3) * 8;
  char* lA = (char*)Asm + w * 1024;
  char* lB = (char*)Bsm + w * 1024;
  const size_t rstep = (size_t)64 * K;
  for (int k0 = 0; k0 < K; k0 += 32) {
    gl_lds16(Ab + k0, lA);
    gl_lds16(Ab + rstep + k0, lA + 4096);
    gl_lds16(Bb + k0, lB);
    gl_lds16(Bb + rstep + k0, lB + 4096);
    __syncthreads();
    bf16x8 af[4], bg[4];
    #pragma unroll
    for (int i = 0; i < 4; ++i)
      af[i] = *(const bf16x8*)&Asm[(wm * 64 + i * 16 + lane15) * 32 + quad * 8];
    #pragma unroll
    for (int i = 0; i < 4; ++i)
      bg[i] = *(const bf16x8*)&Bsm[(wn * 64 + i * 16 + lane15) * 32 + quad * 8];
    #pragma unroll
    for (int i = 0; i < 4; ++i)
      #pragma unroll
      for (int j = 0; j < 4; ++j)
        acc[i][j] = __builtin_amdgcn_mfma_f32_16x16x32_bf16(af[i], bg[j], acc[i][j], 0, 0, 0);
    __syncthreads();
  }
  #pragma unroll
  for (int i = 0; i < 4; ++i) {
    int grow = m0 + wm * 64 + i * 16 + quad * 4;
    #pragma unroll
    for (int j = 0; j < 4; ++j) {
      int gcol = n0 + wn * 64 + j * 16 + lane15;
      float bs = (EPI == 0) ? 0.f : bias[gcol];
      #pragma unroll
      for (int r = 0; r < 4; ++r) {
        float vv = acc[i][j][r] + bs;
        size_t o = (size_t)(grow + r) * Nn + gcol;
        if (EPI == 0) ((unsigned short*)outv)[o] = f2bf(vv);
        else if (EPI == 1 || EPI == 3) ((float*)outv)[o] = vv;
        else {
          float g = 0.5f * vv * (1.f + erff(vv * 0.70710678118f));
          ((unsigned short*)outv)[o] = f2bf(g);
        }
      }
    }
  }
}

// ---------------- flash attention v2: S^T formulation, padded LDS ----------------
// Per block: 64 Q rows, 4 waves (wave w: q rows q0+w*16..+15). Loop 16 K-tiles of 64.
// S^T = K·Q^T via mfma(A=K-frag, B=Q-frag): D[row=quad*4+r = n-local][col=lane15 = q].
// Softmax over n = rows: per-lane state for q=lane15; 2 shuffles per reduction.
// P^T packed to LDS (per-wave) rows q, read back as A-frag for PV (K=32).
__global__ __launch_bounds__(256) void k_flash(const unsigned short* __restrict__ qkv,
    const unsigned short* __restrict__ vtg, float* __restrict__ out) {
  const int t = threadIdx.x, w = t >> 6, l = t & 63;
  const int lane15 = l & 15, quad = l >> 4;
  const int q0 = blockIdx.x * 64;
  const int h = blockIdx.y, b = blockIdx.z;
  __shared__ __align__(16) unsigned short kt[64 * 72];
  __shared__ __align__(16) unsigned short vt[64 * 72];
  __shared__ __align__(16) unsigned short pl[4][16 * 72];

  // Q fragment (B-operand: B[k=c][col=q]), pre-scaled by hd^-0.5 = 0.125 (exact in bf16)
  bf16x8 aq0, aq1;
  {
    const unsigned short* qp = qkv + (size_t)(b * N_ + q0 + w * 16 + lane15) * C3_ + h * 64 + quad * 8;
    bf16x8 r0 = *(const bf16x8*)qp;
    bf16x8 r1 = *(const bf16x8*)(qp + 32);
    #pragma unroll
    for (int i = 0; i < 8; ++i) {
      aq0[i] = (short)f2bf(0.125f * bf2f((unsigned short)r0[i]));
      aq1[i] = (short)f2bf(0.125f * bf2f((unsigned short)r1[i]));
    }
  }
  f32x4 O[4];
  #pragma unroll
  for (int i = 0; i < 4; ++i) O[i] = (f32x4){0.f, 0.f, 0.f, 0.f};
  float mrun = -1e30f, lrun = 0.f;

  // staging: thread t loads rows sr and sr+32, 8 shorts at col sc
  const int sr = t >> 3;
  const int sc = (t & 7) * 8;
  const unsigned short* kb = qkv + (size_t)(b * N_ + sr) * C3_ + 512 + h * 64 + sc;
  const unsigned short* vb = vtg + (size_t)((b * NH_ + h) * HD_ + sr) * N_ + sc;
  bf16x8 gk0 = *(const bf16x8*)kb;
  bf16x8 gk1 = *(const bf16x8*)(kb + (size_t)32 * C3_);
  bf16x8 gv0 = *(const bf16x8*)vb;
  bf16x8 gv1 = *(const bf16x8*)(vb + 32 * N_);

  for (int kti = 0; kti < 16; ++kti) {
    __syncthreads();
    *(bf16x8*)&kt[sr * 72 + sc] = gk0;
    *(bf16x8*)&kt[(sr + 32) * 72 + sc] = gk1;
    *(bf16x8*)&vt[sr * 72 + sc] = gv0;
    *(bf16x8*)&vt[(sr + 32) * 72 + sc] = gv1;
    __syncthreads();
    if (kti < 15) {  // prefetch next tile while computing this one
      const unsigned short* kn = kb + (size_t)((kti + 1) * 64) * C3_;
      const unsigned short* vn = vb + (kti + 1) * 64;
      gk0 = *(const bf16x8*)kn;
      gk1 = *(const bf16x8*)(kn + (size_t)32 * C3_);
      gv0 = *(const bf16x8*)vn;
      gv1 = *(const bf16x8*)(vn + 32 * N_);
    }

    // S^T tiles: D[n-local][q]
    f32x4 S[4];
    #pragma unroll
    for (int nt = 0; nt < 4; ++nt) {
      bf16x8 ak0 = *(const bf16x8*)&kt[(nt * 16 + lane15) * 72 + quad * 8];
      bf16x8 ak1 = *(const bf16x8*)&kt[(nt * 16 + lane15) * 72 + 32 + quad * 8];
      f32x4 z = (f32x4){0.f, 0.f, 0.f, 0.f};
      z = __builtin_amdgcn_mfma_f32_16x16x32_bf16(ak0, aq0, z, 0, 0, 0);
      z = __builtin_amdgcn_mfma_f32_16x16x32_bf16(ak1, aq1, z, 0, 0, 0);
      S[nt] = z;
    }

    // online softmax over n (row dim): reduce 16 regs + quads (xor16, xor32)
    float m1 = S[0][0];
    #pragma unroll
    for (int nt = 0; nt < 4; ++nt)
      #pragma unroll
      for (int r = 0; r < 4; ++r) m1 = fmaxf(m1, S[nt][r]);
    m1 = fmaxf(m1, __shfl_xor(m1, 16));
    m1 = fmaxf(m1, __shfl_xor(m1, 32));
    float mnew = fmaxf(mrun, m1);
    float al = __expf(mrun - mnew);
    mrun = mnew;
    float rs = 0.f;
    #pragma unroll
    for (int nt = 0; nt < 4; ++nt)
      #pragma unroll
      for (int r = 0; r < 4; ++r) {
        float pv = __expf(S[nt][r] - mnew);
        S[nt][r] = pv;
        rs += pv;
      }
    rs += __shfl_xor(rs, 16);
    rs += __shfl_xor(rs, 32);
    lrun = lrun * al + rs;

    // pack P^T -> pl[q=lane15][n] (truncation round: attention path is x1e-4 gated)
    #pragma unroll
    for (int nt = 0; nt < 4; ++nt) {
      unsigned lo = __builtin_amdgcn_perm(f2u(S[nt][1]), f2u(S[nt][0]), 0x07060302u);
      unsigned hi = __builtin_amdgcn_perm(f2u(S[nt][3]), f2u(S[nt][2]), 0x07060302u);
      uint2 pk = make_uint2(lo, hi);
      *(uint2*)&pl[w][lane15 * 72 + nt * 16 + quad * 4] = pk;
    }

    // rescale O by al broadcast to row q = quad*4+r
    float alr[4];
    #pragma unroll
    for (int r = 0; r < 4; ++r) alr[r] = __shfl(al, quad * 4 + r);
    #pragma unroll
    for (int dt = 0; dt < 4; ++dt)
      #pragma unroll
      for (int r = 0; r < 4; ++r) O[dt][r] *= alr[r];

    // PV: O[q][d] += P[q][n] V[n][d], K=32 chunks over n
    #pragma unroll
    for (int nc = 0; nc < 2; ++nc) {
      bf16x8 ap = *(const bf16x8*)&pl[w][lane15 * 72 + nc * 32 + quad * 8];
      #pragma unroll
      for (int dt = 0; dt < 4; ++dt) {
        bf16x8 bv = *(const bf16x8*)&vt[(dt * 16 + lane15) * 72 + nc * 32 + quad * 8];
        O[dt] = __builtin_amdgcn_mfma_f32_16x16x32_bf16(ap, bv, O[dt], 0, 0, 0);
      }
    }
  }

  float inv = 1.f / lrun;  // valid for q=lane15 on every lane
  float invr[4];
  #pragma unroll
  for (int r = 0; r < 4; ++r) invr[r] = __shfl(inv, quad * 4 + r);
  size_t ob = (size_t)(b * N_ + q0 + w * 16) * C_ + h * 64;
  #pragma unroll
  for (int dt = 0; dt < 4; ++dt)
    #pragma unroll
    for (int r = 0; r < 4; ++r)
      out[ob + (size_t)(quad * 4 + r) * C_ + dt * 16 + lane15] = O[dt][r] * invr[r];
}

// ---------------- attention epilogue fuse -> y bf16 ----------------
__global__ __launch_bounds__(256) void k_fuse(const float* __restrict__ ao,
    const unsigned short* __restrict__ qkv, const float* __restrict__ lf,
    const float* __restrict__ hf, const float* __restrict__ lg,
    const float* __restrict__ hg, unsigned short* __restrict__ y) {
  int i = blockIdx.x * 256 + threadIdx.x;
  size_t e = (size_t)i * 4;
  int row = (int)(e >> 9);
  int c = (int)(e & 511);
  int hh = c >> 6;
  float4 a = *(const float4*)(ao + e);
  u16x4 vv = *(const u16x4*)(qkv + (size_t)row * C3_ + 1024 + c);
  float lfv = lf[row * 8 + hh];
  float hfv = hf[row * 8 + hh];
  float4 lg4 = *(const float4*)(lg + c);
  float4 hg4 = *(const float4*)(hg + c);
  float r0 = a.x + a.x * lfv * lg4.x + hfv * (bf2f(vv[0]) - a.x) * hg4.x;
  float r1 = a.y + a.y * lfv * lg4.y + hfv * (bf2f(vv[1]) - a.y) * hg4.y;
  float r2 = a.z + a.z * lfv * lg4.z + hfv * (bf2f(vv[2]) - a.z) * hg4.z;
  float r3 = a.w + a.w * lfv * lg4.w + hfv * (bf2f(vv[3]) - a.w) * hg4.w;
  u16x4 o = { f2bf(r0), f2bf(r1), f2bf(r2), f2bf(r3) };
  *(u16x4*)(y + e) = o;
}

// ---------------- spatial mean pool per (b,c) row ----------------
__global__ __launch_bounds__(256) void k_pool(const float* __restrict__ feat,
                                              float* __restrict__ pooled) {
  int row = blockIdx.x * 4 + (threadIdx.x >> 6);
  int l = threadIdx.x & 63;
  const float4* p = (const float4*)(feat + (size_t)row * N_);
  float4 a = p[l], b4 = p[l + 64], c4 = p[l + 128], d4 = p[l + 192];
  float s = a.x + a.y + a.z + a.w + b4.x + b4.y + b4.z + b4.w +
            c4.x + c4.y + c4.z + c4.w + d4.x + d4.y + d4.z + d4.w;
  #pragma unroll
  for (int off = 1; off < 64; off <<= 1) s += __shfl_xor(s, off);
  if (l == 0) pooled[row] = s * (1.f / 1024.f);
}

// ---------------- routing: pooled(B,C) -> routing(B,64) ----------------
__global__ __launch_bounds__(256) void k_routing(const float* __restrict__ pooled,
    const float* __restrict__ rw1, const float* __restrict__ rw1s,
    const float* __restrict__ rw1b, const float* __restrict__ rw2,
    float* __restrict__ routing) {
  const int b = blockIdx.x, t = threadIdx.x;
  __shared__ float plds[512];
  __shared__ float tile[64][65];
  __shared__ float hl[64];
  plds[t] = pooled[b * 512 + t];
  plds[t + 256] = pooled[b * 512 + t + 256];
  __syncthreads();
  float acc = 0.f;
  for (int c0 = 0; c0 < 512; c0 += 64) {
    #pragma unroll
    for (int kk = 0; kk < 16; ++kk) {
      int idx = kk * 256 + t;
      tile[idx >> 6][idx & 63] = rw1[(size_t)(idx >> 6) * 512 + c0 + (idx & 63)];
    }
    __syncthreads();
    if (t < 64) {
      #pragma unroll
      for (int i = 0; i < 64; ++i) acc += plds[c0 + i] * tile[t][i];
    }
    __syncthreads();
  }
  if (t < 64) {
    float r = fmaxf(acc, 0.f);
    hl[t] = rw1s[0] * r * r + rw1b[0];
  }
  __syncthreads();
  if (t < 64) {
    float r2 = 0.f;
    #pragma unroll
    for (int j = 0; j < 64; ++j) r2 += hl[j] * rw2[(size_t)t * 64 + j];
    routing[b * 64 + t] = tanhf(r2);
  }
}

// ---------------- per-plane 32x32 rfft2 * dyn -> irfft2 (+ residual plane) ----------------
__global__ __launch_bounds__(256) void k_freq(const float* __restrict__ feat,
    const float* __restrict__ routing, const float* __restrict__ fwtab,
    float* __restrict__ enh) {
  const int c = blockIdx.x, b = blockIdx.y, t = threadIdx.x;
  const int g = c >> 5, cc = c & 31;
  __shared__ float p[32 * 36];
  __shared__ float2 A2[32 * 17];
  __shared__ float2 G2[32 * 17];
  __shared__ float2 Z2[32 * 18];
  __shared__ float Ms[544];
  const size_t base = (size_t)(b * C_ + c) * N_;
  const float PI2_32 = 0.19634954084936207f;  // 2*pi/32

  #pragma unroll
  for (int k = 0; k < 4; ++k) {
    int n = k * 256 + t;
    p[(n >> 5) * 36 + (n & 31)] = feat[base + n];
  }
  float r0 = routing[b * 64 + g * 4 + 0];
  float r1 = routing[b * 64 + g * 4 + 1];
  float r2 = routing[b * 64 + g * 4 + 2];
  float r3 = routing[b * 64 + g * 4 + 3];
  for (int o = t; o < 544; o += 256) {
    float mv = r0 * fwtab[(0 * 32 + cc) * 544 + o] + r1 * fwtab[(1 * 32 + cc) * 544 + o] +
               r2 * fwtab[(2 * 32 + cc) * 544 + o] + r3 * fwtab[(3 * 32 + cc) * 544 + o];
    Ms[o] = mv * (1.f / 1024.f);
  }
  __syncthreads();
  // S1: row rfft (over w), output A2[h][fw], fw 0..16
  {
    int hh = t >> 3, f0 = t & 7;
    float4 pr[8];
    #pragma unroll
    for (int kk = 0; kk < 8; ++kk) pr[kk] = *(const float4*)&p[hh * 36 + kk * 4];
    for (int fw = f0; fw <= 16; fw += 8) {
      float dsn, dc;
      __sincosf(PI2_32 * (float)fw, &dsn, &dc);
      float cr = 1.f, si = 0.f, Re = 0.f, Im = 0.f;
      #pragma unroll
      for (int ww = 0; ww < 32; ++ww) {
        float pv = pr[ww >> 2][ww & 3];
        Re += pv * cr;
        Im -= pv * si;
        float cn = cr * dc - si * dsn;
        si = si * dc + cr * dsn;
        cr = cn;
      }
      A2[hh * 17 + fw] = make_float2(Re, Im);
    }
  }
  __syncthreads();
  // S2: column fft (over h), outputs (fh, fh+16), then scale by Ms -> G2
  for (int o = t; o < 272; o += 256) {
    int fh = o / 17, fw = o % 17;
    float dsn, dc;
    __sincosf(PI2_32 * (float)fh, &dsn, &dc);
    float cr = 1.f, si = 0.f, er = 0.f, ei = 0.f, odr = 0.f, odi = 0.f;
    #pragma unroll
    for (int hh = 0; hh < 32; ++hh) {
      float2 a = A2[hh * 17 + fw];
      float xr = a.x * cr + a.y * si;   // e^{-i theta}
      float xi = a.y * cr - a.x * si;
      er += xr; ei += xi;
      if (hh & 1) { odr -= xr; odi -= xi; } else { odr += xr; odi += xi; }
      float cn = cr * dc - si * dsn;
      si = si * dc + cr * dsn;
      cr = cn;
    }
    float m0 = Ms[fh * 17 + fw], m1 = Ms[(fh + 16) * 17 + fw];
    G2[fh * 17 + fw] = make_float2(er * m0, ei * m0);
    G2[(fh + 16) * 17 + fw] = make_float2(odr * m1, odi * m1);
  }
  __syncthreads();
  // S3: inverse column fft (over fh), outputs Z2[(h,h+16)][fw]
  for (int o = t; o < 272; o += 256) {
    int hh = o / 17, fw = o % 17;
    float dsn, dc;
    __sincosf(PI2_32 * (float)hh, &dsn, &dc);
    float cr = 1.f, si = 0.f, er = 0.f, ei = 0.f, odr = 0.f, odi = 0.f;
    #pragma unroll
    for (int fh = 0; fh < 32; ++fh) {
      float2 gv = G2[fh * 17 + fw];
      float xr = gv.x * cr - gv.y * si;  // e^{+i theta}
      float xi = gv.y * cr + gv.x * si;
      er += xr; ei += xi;
      if (fh & 1) { odr -= xr; odi -= xi; } else { odr += xr; odi += xi; }
      float cn = cr * dc - si * dsn;
      si = si * dc + cr * dsn;
      cr = cn;
    }
    Z2[hh * 18 + fw] = make_float2(er, ei);
    Z2[(hh + 16) * 18 + fw] = make_float2(odr, odi);
  }
  __syncthreads();
  // S4: inverse row rfft with Hermitian weights, outputs (w0, w0+16), add residual
  for (int o = t; o < 512; o += 256) {
    int hh = o >> 4, w0 = o & 15;
    float dsn, dc;
    __sincosf(PI2_32 * (float)w0, &dsn, &dc);
    float cr = 1.f, si = 0.f, ev = 0.f, ov = 0.f;
    #pragma unroll
    for (int fw = 0; fw <= 16; ++fw) {
      float2 z = Z2[hh * 18 + fw];
      float val = z.x * cr - z.y * si;
      float wg = (fw == 0 || fw == 16) ? 1.f : 2.f;
      ev += wg * val;
      ov += (fw & 1) ? -wg * val : wg * val;
      float cn = cr * dc - si * dsn;
      si = si * dc + cr * dsn;
      cr = cn;
    }
    enh[base + hh * 32 + w0] = ev + p[hh * 36 + w0];
    enh[base + hh * 32 + w0 + 16] = ov + p[hh * 36 + w0 + 16];
  }
}

// ---------------- tokens += gamma * enh^T ----------------
__global__ __launch_bounds__(256) void k_add_t(const float* __restrict__ enh,
    const float* __restrict__ gamma, float* __restrict__ tok) {
  __shared__ float s[32][33];
  const int n0 = blockIdx.x * 32, c0 = blockIdx.y * 32, b = blockIdx.z;
  const int j = threadIdx.x & 31, i0 = threadIdx.x >> 5;
  #pragma unroll
  for (int k = 0; k < 4; ++k) {
    int i = i0 + k * 8;
    s[i][j] = enh[(size_t)(b * C_ + c0 + i) * N_ + n0 + j];
  }
  __syncthreads();
  float gv = gamma[c0 + j];
  #pragma unroll
  for (int k = 0; k < 4; ++k) {
    int i = i0 + k * 8;
    size_t o = (size_t)(b * N_ + n0 + i) * C_ + c0 + j;
    tok[o] += gv * s[j][i];
  }
}

// ---------------- final: out = tokens^T + gamma2 * enh ----------------
__global__ __launch_bounds__(256) void k_final(const float* __restrict__ tok,
    const float* __restrict__ gamma, const float* __restrict__ enh,
    float* __restrict__ out) {
  __shared__ float s[32][33];
  const int n0 = blockIdx.x * 32, c0 = blockIdx.y * 32, b = blockIdx.z;
  const int j = threadIdx.x & 31, i0 = threadIdx.x >> 5;
  #pragma unroll
  for (int k = 0; k < 4; ++k) {
    int i = i0 + k * 8;
    s[i][j] = tok[(size_t)(b * N_ + n0 + i) * C_ + c0 + j];
  }
  __syncthreads();
  #pragma unroll
  for (int k = 0; k < 4; ++k) {
    int i = i0 + k * 8;   // c-local
    size_t o = (size_t)(b * C_ + c0 + i) * N_ + n0 + j;
    out[o] = s[j][i] + gamma[c0 + i] * enh[o];
  }
}

// =============================== launch ===============================
extern "C" void kernel_launch(void* const* d_in, const int* in_sizes, int n_in,
                              void* d_out, int out_size, void* d_ws, size_t ws_size,
                              hipStream_t stream) {
  (void)in_sizes; (void)n_in; (void)out_size; (void)ws_size;
  const float* x      = (const float*)d_in[0];
  const float* n1w    = (const float*)d_in[1];
  const float* n1b    = (const float*)d_in[2];
  const float* qkv_w  = (const float*)d_in[3];
  const float* proj_w = (const float*)d_in[4];
  const float* proj_b = (const float*)d_in[5];
  const float* pa_s   = (const float*)d_in[6];
  const float* pa_b   = (const float*)d_in[7];
  const float* lf_w   = (const float*)d_in[8];
  const float* lf_b   = (const float*)d_in[9];
  const float* hf_w   = (const float*)d_in[10];
  const float* hf_b   = (const float*)d_in[11];
  const float* lf_g   = (const float*)d_in[12];
  const float* hf_g   = (const float*)d_in[13];
  const float* f1rw1w = (const float*)d_in[14];
  const float* f1rw1s = (const float*)d_in[15];
  const float* f1rw1b = (const float*)d_in[16];
  const float* f1rw2w = (const float*)d_in[17];
  const float* f1fw   = (const float*)d_in[18];
  const float* gamma1 = (const float*)d_in[19];
  const float* n2w    = (const float*)d_in[20];
  const float* n2b    = (const float*)d_in[21];
  const float* fc1w   = (const float*)d_in[22];
  const float* fc1b   = (const float*)d_in[23];
  const float* fc2w   = (const float*)d_in[24];
  const float* fc2b   = (const float*)d_in[25];
  const float* f2rw1w = (const float*)d_in[26];
  const float* f2rw1s = (const float*)d_in[27];
  const float* f2rw1b = (const float*)d_in[28];
  const float* f2rw2w = (const float*)d_in[29];
  const float* f2fw   = (const float*)d_in[30];
  const float* gamma2 = (const float*)d_in[31];

  char* ws = (char*)d_ws;
  float*          tokens = (float*)(ws + 0);
  float*          f1buf  = (float*)(ws + 33554432ULL);
  float*          f2buf  = (float*)(ws + 67108864ULL);
  float*          f3buf  = (float*)(ws + 100663296ULL);
  unsigned short* regA   = (unsigned short*)(ws + 134217728ULL);  // qkv(50MB) then hact(64MB)
  unsigned short* abuf   = (unsigned short*)(ws + 201326592ULL);
  float*          lfbuf  = (float*)(ws + 218103808ULL);
  float*          hfbuf  = (float*)(ws + 218628096ULL);
  float*          pooled = (float*)(ws + 219152384ULL);
  float*          routing= (float*)(ws + 219185152ULL);
  unsigned short* wq     = (unsigned short*)(ws + 219189248ULL);
  unsigned short* wp     = (unsigned short*)(ws + 220762112ULL);
  unsigned short* w1     = (unsigned short*)(ws + 221286400ULL);
  unsigned short* w2     = (unsigned short*)(ws + 223383552ULL);

  // weights -> bf16
  k_f2b<<<3072, 256, 0, stream>>>(qkv_w, wq, 786432);
  k_f2b<<<1024, 256, 0, stream>>>(proj_w, wp, 262144);
  k_f2b<<<4096, 256, 0, stream>>>(fc1w, w1, 1048576);
  k_f2b<<<4096, 256, 0, stream>>>(fc2w, w2, 1048576);

  // tokens = transpose(x)
  k_transpose_cn<<<dim3(32, 16, 16), 256, 0, stream>>>(x, tokens);
  // LN1 + lf/hf
  k_ln<true><<<4096, 256, 0, stream>>>(tokens, n1w, n1b, lf_w, lf_b, hf_w, hf_b,
                                       pa_s, pa_b, abuf, lfbuf, hfbuf);
  // QKV
  k_gemm<0><<<dim3(12, 128), 256, 0, stream>>>(abuf, wq, n1b, regA, C3_, C_);
  // V repack for flash
  k_vrepack<<<dim3(32, 2, 128), 256, 0, stream>>>(regA, (unsigned short*)f2buf);
  // flash attention -> f1buf (M,512) f32
  k_flash<<<dim3(16, 8, 16), 256, 0, stream>>>(regA, (unsigned short*)f2buf, f1buf);
  // fuse lf/hf gates -> abuf bf16
  k_fuse<<<8192, 256, 0, stream>>>(f1buf, regA, lfbuf, hfbuf, lf_g, hf_g, abuf);
  // proj -> f1buf (M,512) f32
  k_gemm<1><<<dim3(4, 128), 256, 0, stream>>>(abuf, wp, proj_b, f1buf, C_, C_);
  // att_feat (B,C,N)
  k_transpose_nc<<<dim3(32, 16, 16), 256, 0, stream>>>(f1buf, f2buf);
  // freq scale 1
  k_pool<<<2048, 256, 0, stream>>>(f2buf, pooled);
  k_routing<<<16, 256, 0, stream>>>(pooled, f1rw1w, f1rw1s, f1rw1b, f1rw2w, routing);
  k_freq<<<dim3(512, 16), 256, 0, stream>>>(f2buf, routing, f1fw, f3buf);
  // tokens += gamma1 * enh^T
  k_add_t<<<dim3(32, 16, 16), 256, 0, stream>>>(f3buf, gamma1, tokens);
  // LN2
  k_ln<false><<<4096, 256, 0, stream>>>(tokens, n2w, n2b, nullptr, nullptr, nullptr,
                                        nullptr, nullptr, nullptr, abuf, nullptr, nullptr);
  // fc1 + gelu -> regA bf16 (M,2048)
  k_gemm<2><<<dim3(16, 128), 256, 0, stream>>>(abuf, w1, fc1b, regA, CH_, C_);
  // fc2 -> f1buf f32 (M,512)
  k_gemm<3><<<dim3(4, 128), 256, 0, stream>>>(regA, w2, fc2b, f1buf, C_, CH_);
  // mlp_feat (B,C,N)
  k_transpose_nc<<<dim3(32, 16, 16), 256, 0, stream>>>(f1buf, f2buf);
  // freq scale 2
  k_pool<<<2048, 256, 0, stream>>>(f2buf, pooled);
  k_routing<<<16, 256, 0, stream>>>(pooled, f2rw1w, f2rw1s, f2rw1b, f2rw2w, routing);
  k_freq<<<dim3(512, 16), 256, 0, stream>>>(f2buf, routing, f2fw, f3buf);
  // out = tokens^T + gamma2 * enh
  k_final<<<dim3(32, 16, 16), 256, 0, stream>>>(tokens, gamma2, f3buf, (float*)d_out);
}

// Round 3
// 627.233 us; speedup vs baseline: 1.3966x; 1.3316x over previous
//
#include <hip/hip_runtime.h>
#include <cstdint>
#include <cstddef>

#define B_   16
#define C_   512
#define N_   1024
#define M_   (B_*N_)
#define NH_  8
#define HD_  64
#define C3_  1536
#define CH_  2048

typedef __attribute__((ext_vector_type(8))) short bf16x8;
typedef __attribute__((ext_vector_type(4))) float f32x4;
typedef __attribute__((ext_vector_type(4))) unsigned short u16x4;

__device__ __forceinline__ unsigned short f2bf(float f) {
  union { float f; unsigned u; } v; v.f = f;
  unsigned r = v.u + 0x7fffu + ((v.u >> 16) & 1u);
  return (unsigned short)(r >> 16);
}
__device__ __forceinline__ float bf2f(unsigned short h) {
  union { unsigned u; float f; } v; v.u = ((unsigned)h) << 16;
  return v.f;
}
__device__ __forceinline__ unsigned f2u(float f) {
  union { float f; unsigned u; } v; v.f = f; return v.u;
}
__device__ __forceinline__ void gl_lds16(const void* g, void* l) {
  __builtin_amdgcn_global_load_lds((const __attribute__((address_space(1))) void*)g,
                                   (__attribute__((address_space(3))) void*)l,
                                   16, 0, 0);
}

// ---------------- float -> bf16 weight conversion ----------------
__global__ __launch_bounds__(256) void k_f2b(const float* __restrict__ src,
                                             unsigned short* __restrict__ dst, int n) {
  int i = blockIdx.x * 256 + threadIdx.x;
  if (i < n) dst[i] = f2bf(src[i]);
}

// ---------------- twiddle tables (bf16, stride 40), 5 tables of 32x40 ----------------
// t0: cos(2pi i j/32)  t1: sin  t2: -sin  t3: wg(j)*cos (j<17 else 0)  t4: -wg(j)*sin
__global__ __launch_bounds__(256) void k_twid(unsigned short* __restrict__ gtab) {
  int idx = blockIdx.x * 256 + threadIdx.x;
  if (idx >= 6400) return;
  int tab = idx / 1280, rem = idx % 1280;
  int i = rem / 40, j = rem % 40;
  float v = 0.f;
  if (j < 32) {
    float th = 0.19634954084936207f * (float)((i * j) & 31);
    float s, c;
    __sincosf(th, &s, &c);
    if (tab == 0) v = c;
    else if (tab == 1) v = s;
    else if (tab == 2) v = -s;
    else {
      float wg = (j == 0 || j == 16) ? 1.f : 2.f;
      if (j >= 17) wg = 0.f;
      v = (tab == 3) ? wg * c : -wg * s;
    }
  }
  gtab[idx] = f2bf(v);
}

// ---------------- transpose (B,C,N) f32 -> (B,N,C) f32 ----------------
__global__ __launch_bounds__(256) void k_transpose_cn(const float* __restrict__ x,
                                                      float* __restrict__ tok) {
  __shared__ float s[32][33];
  const int n0 = blockIdx.x * 32, c0 = blockIdx.y * 32, b = blockIdx.z;
  const int j = threadIdx.x & 31, i0 = threadIdx.x >> 5;
  #pragma unroll
  for (int k = 0; k < 4; ++k) {
    int i = i0 + k * 8;
    s[i][j] = x[(size_t)(b * C_ + c0 + i) * N_ + n0 + j];
  }
  __syncthreads();
  #pragma unroll
  for (int k = 0; k < 4; ++k) {
    int i = i0 + k * 8;
    tok[(size_t)(b * N_ + n0 + i) * C_ + c0 + j] = s[j][i];
  }
}

// ---------------- transpose (B,N,C) f32 -> (B,C,N) f32 ----------------
__global__ __launch_bounds__(256) void k_transpose_nc(const float* __restrict__ in,
                                                      float* __restrict__ out) {
  __shared__ float s[32][33];
  const int n0 = blockIdx.x * 32, c0 = blockIdx.y * 32, b = blockIdx.z;
  const int j = threadIdx.x & 31, i0 = threadIdx.x >> 5;
  #pragma unroll
  for (int k = 0; k < 4; ++k) {
    int i = i0 + k * 8;
    s[i][j] = in[(size_t)(b * N_ + n0 + i) * C_ + c0 + j];
  }
  __syncthreads();
  #pragma unroll
  for (int k = 0; k < 4; ++k) {
    int i = i0 + k * 8;
    out[(size_t)(b * C_ + c0 + i) * N_ + n0 + j] = s[j][i];
  }
}

// ---------------- V repack: qkv (M,1536) bf16 -> vt (B,NH,HD,N) bf16 ----------------
__global__ __launch_bounds__(256) void k_vrepack(const unsigned short* __restrict__ qkv,
                                                 unsigned short* __restrict__ vtg) {
  __shared__ unsigned short s[32][34];
  const int n0 = blockIdx.x * 32, d0 = blockIdx.y * 32, bh = blockIdx.z;
  const int b = bh >> 3, h = bh & 7;
  const int j = threadIdx.x & 31, i0 = threadIdx.x >> 5;
  #pragma unroll
  for (int k = 0; k < 4; ++k) {
    int i = i0 + k * 8;  // n-local
    s[i][j] = qkv[(size_t)(b * N_ + n0 + i) * C3_ + 1024 + h * 64 + d0 + j];
  }
  __syncthreads();
  #pragma unroll
  for (int k = 0; k < 4; ++k) {
    int i = i0 + k * 8;  // d-local
    vtg[(size_t)(bh * HD_ + d0 + i) * N_ + n0 + j] = s[j][i];
  }
}

// ---------------- LayerNorm (+ optional lf/hf head gates) ----------------
template<bool WITH>
__global__ __launch_bounds__(256) void k_ln(const float* __restrict__ tok,
    const float* __restrict__ w, const float* __restrict__ bia,
    const float* __restrict__ lfw, const float* __restrict__ lfb,
    const float* __restrict__ hfw, const float* __restrict__ hfb,
    const float* __restrict__ pa_s, const float* __restrict__ pa_b,
    unsigned short* __restrict__ lnout, float* __restrict__ lfout,
    float* __restrict__ hfout) {
  const int t = threadIdx.x, wv = t >> 6, l = t & 63;
  const int row = blockIdx.x * 4 + wv;
  const float* p = tok + (size_t)row * C_;
  float v[8];
  *(float4*)&v[0] = *(const float4*)(p + 4 * l);
  *(float4*)&v[4] = *(const float4*)(p + 256 + 4 * l);
  float s = 0.f, q = 0.f;
  #pragma unroll
  for (int i = 0; i < 8; ++i) { s += v[i]; q += v[i] * v[i]; }
  #pragma unroll
  for (int off = 1; off < 64; off <<= 1) { s += __shfl_xor(s, off); q += __shfl_xor(q, off); }
  float mu = s * (1.f / 512.f);
  float var = q * (1.f / 512.f) - mu * mu;
  float rstd = rsqrtf(var + 1e-5f);
  float wv8[8], bv8[8];
  *(float4*)&wv8[0] = *(const float4*)(w + 4 * l);
  *(float4*)&wv8[4] = *(const float4*)(w + 256 + 4 * l);
  *(float4*)&bv8[0] = *(const float4*)(bia + 4 * l);
  *(float4*)&bv8[4] = *(const float4*)(bia + 256 + 4 * l);
  float ln[8];
  #pragma unroll
  for (int i = 0; i < 8; ++i) ln[i] = (v[i] - mu) * rstd * wv8[i] + bv8[i];
  u16x4 o0 = { f2bf(ln[0]), f2bf(ln[1]), f2bf(ln[2]), f2bf(ln[3]) };
  u16x4 o1 = { f2bf(ln[4]), f2bf(ln[5]), f2bf(ln[6]), f2bf(ln[7]) };
  *(u16x4*)(lnout + (size_t)row * C_ + 4 * l) = o0;
  *(u16x4*)(lnout + (size_t)row * C_ + 256 + 4 * l) = o1;
  if (WITH) {
    float ps = pa_s[0], pb = pa_b[0];
    float d[8];
    #pragma unroll
    for (int i = 0; i < 8; ++i) { float r = fmaxf(ln[i], 0.f); d[i] = ps * r * r + pb; }
    float lacc[8], hacc[8];
    #pragma unroll
    for (int h = 0; h < 8; ++h) {
      float lw[8], hw[8];
      *(float4*)&lw[0] = *(const float4*)(lfw + h * C_ + 4 * l);
      *(float4*)&lw[4] = *(const float4*)(lfw + h * C_ + 256 + 4 * l);
      *(float4*)&hw[0] = *(const float4*)(hfw + h * C_ + 4 * l);
      *(float4*)&hw[4] = *(const float4*)(hfw + h * C_ + 256 + 4 * l);
      float la = 0.f, ha = 0.f;
      #pragma unroll
      for (int i = 0; i < 8; ++i) { la += d[i] * lw[i]; ha += d[i] * hw[i]; }
      lacc[h] = la; hacc[h] = ha;
    }
    #pragma unroll
    for (int h = 0; h < 8; ++h)
      #pragma unroll
      for (int off = 1; off < 64; off <<= 1) {
        lacc[h] += __shfl_xor(lacc[h], off);
        hacc[h] += __shfl_xor(hacc[h], off);
      }
    float lv = lacc[0], hv = hacc[0];
    #pragma unroll
    for (int h = 1; h < 8; ++h) { if (l == h) { lv = lacc[h]; hv = hacc[h]; } }
    if (l < 8) {
      lfout[(size_t)row * 8 + l] = tanhf(lv + lfb[l]);
      float z = hv + hfb[l];
      float sp = (z > 15.f) ? z : log1pf(__expf(z));
      float s2 = sp * sp;
      hfout[(size_t)row * 8 + l] = 2.f * s2 / (s2 + 0.3678f);
    }
  }
}

// ---------------- GEMM: A(M,K)bf16 x Bt(N,K)bf16, 128x128 tile ----------------
template<int EPI>
__global__ __launch_bounds__(256) void k_gemm(const unsigned short* __restrict__ A,
    const unsigned short* __restrict__ Bt, const float* __restrict__ bias,
    void* __restrict__ outv, int Nn, int K) {
  __shared__ unsigned short Asm[128 * 32];
  __shared__ unsigned short Bsm[128 * 32];
  const int t = threadIdx.x, w = t >> 6, l = t & 63;
  const int lane15 = l & 15, quad = l >> 4;
  const int n0 = blockIdx.x * 128, m0 = blockIdx.y * 128;
  const int wm = w >> 1, wn = w & 1;
  f32x4 acc[4][4];
  #pragma unroll
  for (int i = 0; i < 4; ++i)
    #pragma unroll
    for (int j = 0; j < 4; ++j) acc[i][j] = (f32x4){0.f, 0.f, 0.f, 0.f};
  const unsigned short* Ab = A + (size_t)(m0 + (t >> 2)) * K + (t & 3) * 8;
  const unsigned short* Bb = Bt + (size_t)(n0 + (t >> 2)) * K + (t & 3) * 8;
  char* lA = (char*)Asm + w * 1024;
  char* lB = (char*)Bsm + w * 1024;
  const size_t rstep = (size_t)64 * K;
  for (int k0 = 0; k0 < K; k0 += 32) {
    gl_lds16(Ab + k0, lA);
    gl_lds16(Ab + rstep + k0, lA + 4096);
    gl_lds16(Bb + k0, lB);
    gl_lds16(Bb + rstep + k0, lB + 4096);
    __syncthreads();
    bf16x8 af[4], bg[4];
    #pragma unroll
    for (int i = 0; i < 4; ++i)
      af[i] = *(const bf16x8*)&Asm[(wm * 64 + i * 16 + lane15) * 32 + quad * 8];
    #pragma unroll
    for (int i = 0; i < 4; ++i)
      bg[i] = *(const bf16x8*)&Bsm[(wn * 64 + i * 16 + lane15) * 32 + quad * 8];
    #pragma unroll
    for (int i = 0; i < 4; ++i)
      #pragma unroll
      for (int j = 0; j < 4; ++j)
        acc[i][j] = __builtin_amdgcn_mfma_f32_16x16x32_bf16(af[i], bg[j], acc[i][j], 0, 0, 0);
    __syncthreads();
  }
  #pragma unroll
  for (int i = 0; i < 4; ++i) {
    int grow = m0 + wm * 64 + i * 16 + quad * 4;
    #pragma unroll
    for (int j = 0; j < 4; ++j) {
      int gcol = n0 + wn * 64 + j * 16 + lane15;
      float bs = (EPI == 0) ? 0.f : bias[gcol];
      #pragma unroll
      for (int r = 0; r < 4; ++r) {
        float vv = acc[i][j][r] + bs;
        size_t o = (size_t)(grow + r) * Nn + gcol;
        if (EPI == 0) ((unsigned short*)outv)[o] = f2bf(vv);
        else if (EPI == 1 || EPI == 3) ((float*)outv)[o] = vv;
        else {
          float g = 0.5f * vv * (1.f + erff(vv * 0.70710678118f));
          ((unsigned short*)outv)[o] = f2bf(g);
        }
      }
    }
  }
}

// ---------------- flash attention v2: S^T formulation, padded LDS ----------------
__global__ __launch_bounds__(256) void k_flash(const unsigned short* __restrict__ qkv,
    const unsigned short* __restrict__ vtg, float* __restrict__ out) {
  const int t = threadIdx.x, w = t >> 6, l = t & 63;
  const int lane15 = l & 15, quad = l >> 4;
  const int q0 = blockIdx.x * 64;
  const int h = blockIdx.y, b = blockIdx.z;
  __shared__ __align__(16) unsigned short kt[64 * 72];
  __shared__ __align__(16) unsigned short vt[64 * 72];
  __shared__ __align__(16) unsigned short pl[4][16 * 72];

  bf16x8 aq0, aq1;
  {
    const unsigned short* qp = qkv + (size_t)(b * N_ + q0 + w * 16 + lane15) * C3_ + h * 64 + quad * 8;
    bf16x8 r0 = *(const bf16x8*)qp;
    bf16x8 r1 = *(const bf16x8*)(qp + 32);
    #pragma unroll
    for (int i = 0; i < 8; ++i) {
      aq0[i] = (short)f2bf(0.125f * bf2f((unsigned short)r0[i]));
      aq1[i] = (short)f2bf(0.125f * bf2f((unsigned short)r1[i]));
    }
  }
  f32x4 O[4];
  #pragma unroll
  for (int i = 0; i < 4; ++i) O[i] = (f32x4){0.f, 0.f, 0.f, 0.f};
  float mrun = -1e30f, lrun = 0.f;

  const int sr = t >> 3;
  const int sc = (t & 7) * 8;
  const unsigned short* kb = qkv + (size_t)(b * N_ + sr) * C3_ + 512 + h * 64 + sc;
  const unsigned short* vb = vtg + (size_t)((b * NH_ + h) * HD_ + sr) * N_ + sc;
  bf16x8 gk0 = *(const bf16x8*)kb;
  bf16x8 gk1 = *(const bf16x8*)(kb + (size_t)32 * C3_);
  bf16x8 gv0 = *(const bf16x8*)vb;
  bf16x8 gv1 = *(const bf16x8*)(vb + 32 * N_);

  for (int kti = 0; kti < 16; ++kti) {
    __syncthreads();
    *(bf16x8*)&kt[sr * 72 + sc] = gk0;
    *(bf16x8*)&kt[(sr + 32) * 72 + sc] = gk1;
    *(bf16x8*)&vt[sr * 72 + sc] = gv0;
    *(bf16x8*)&vt[(sr + 32) * 72 + sc] = gv1;
    __syncthreads();
    if (kti < 15) {
      const unsigned short* kn = kb + (size_t)((kti + 1) * 64) * C3_;
      const unsigned short* vn = vb + (kti + 1) * 64;
      gk0 = *(const bf16x8*)kn;
      gk1 = *(const bf16x8*)(kn + (size_t)32 * C3_);
      gv0 = *(const bf16x8*)vn;
      gv1 = *(const bf16x8*)(vn + 32 * N_);
    }

    f32x4 S[4];
    #pragma unroll
    for (int nt = 0; nt < 4; ++nt) {
      bf16x8 ak0 = *(const bf16x8*)&kt[(nt * 16 + lane15) * 72 + quad * 8];
      bf16x8 ak1 = *(const bf16x8*)&kt[(nt * 16 + lane15) * 72 + 32 + quad * 8];
      f32x4 z = (f32x4){0.f, 0.f, 0.f, 0.f};
      z = __builtin_amdgcn_mfma_f32_16x16x32_bf16(ak0, aq0, z, 0, 0, 0);
      z = __builtin_amdgcn_mfma_f32_16x16x32_bf16(ak1, aq1, z, 0, 0, 0);
      S[nt] = z;
    }

    float m1 = S[0][0];
    #pragma unroll
    for (int nt = 0; nt < 4; ++nt)
      #pragma unroll
      for (int r = 0; r < 4; ++r) m1 = fmaxf(m1, S[nt][r]);
    m1 = fmaxf(m1, __shfl_xor(m1, 16));
    m1 = fmaxf(m1, __shfl_xor(m1, 32));
    float mnew = fmaxf(mrun, m1);
    float al = __expf(mrun - mnew);
    mrun = mnew;
    float rs = 0.f;
    #pragma unroll
    for (int nt = 0; nt < 4; ++nt)
      #pragma unroll
      for (int r = 0; r < 4; ++r) {
        float pv = __expf(S[nt][r] - mnew);
        S[nt][r] = pv;
        rs += pv;
      }
    rs += __shfl_xor(rs, 16);
    rs += __shfl_xor(rs, 32);
    lrun = lrun * al + rs;

    #pragma unroll
    for (int nt = 0; nt < 4; ++nt) {
      unsigned lo = __builtin_amdgcn_perm(f2u(S[nt][1]), f2u(S[nt][0]), 0x07060302u);
      unsigned hi = __builtin_amdgcn_perm(f2u(S[nt][3]), f2u(S[nt][2]), 0x07060302u);
      uint2 pk = make_uint2(lo, hi);
      *(uint2*)&pl[w][lane15 * 72 + nt * 16 + quad * 4] = pk;
    }

    float alr[4];
    #pragma unroll
    for (int r = 0; r < 4; ++r) alr[r] = __shfl(al, quad * 4 + r);
    #pragma unroll
    for (int dt = 0; dt < 4; ++dt)
      #pragma unroll
      for (int r = 0; r < 4; ++r) O[dt][r] *= alr[r];

    #pragma unroll
    for (int nc = 0; nc < 2; ++nc) {
      bf16x8 ap = *(const bf16x8*)&pl[w][lane15 * 72 + nc * 32 + quad * 8];
      #pragma unroll
      for (int dt = 0; dt < 4; ++dt) {
        bf16x8 bv = *(const bf16x8*)&vt[(dt * 16 + lane15) * 72 + nc * 32 + quad * 8];
        O[dt] = __builtin_amdgcn_mfma_f32_16x16x32_bf16(ap, bv, O[dt], 0, 0, 0);
      }
    }
  }

  float inv = 1.f / lrun;
  float invr[4];
  #pragma unroll
  for (int r = 0; r < 4; ++r) invr[r] = __shfl(inv, quad * 4 + r);
  size_t ob = (size_t)(b * N_ + q0 + w * 16) * C_ + h * 64;
  #pragma unroll
  for (int dt = 0; dt < 4; ++dt)
    #pragma unroll
    for (int r = 0; r < 4; ++r)
      out[ob + (size_t)(quad * 4 + r) * C_ + dt * 16 + lane15] = O[dt][r] * invr[r];
}

// ---------------- attention epilogue fuse -> y bf16 ----------------
__global__ __launch_bounds__(256) void k_fuse(const float* __restrict__ ao,
    const unsigned short* __restrict__ qkv, const float* __restrict__ lf,
    const float* __restrict__ hf, const float* __restrict__ lg,
    const float* __restrict__ hg, unsigned short* __restrict__ y) {
  int i = blockIdx.x * 256 + threadIdx.x;
  size_t e = (size_t)i * 4;
  int row = (int)(e >> 9);
  int c = (int)(e & 511);
  int hh = c >> 6;
  float4 a = *(const float4*)(ao + e);
  u16x4 vv = *(const u16x4*)(qkv + (size_t)row * C3_ + 1024 + c);
  float lfv = lf[row * 8 + hh];
  float hfv = hf[row * 8 + hh];
  float4 lg4 = *(const float4*)(lg + c);
  float4 hg4 = *(const float4*)(hg + c);
  float r0 = a.x + a.x * lfv * lg4.x + hfv * (bf2f(vv[0]) - a.x) * hg4.x;
  float r1 = a.y + a.y * lfv * lg4.y + hfv * (bf2f(vv[1]) - a.y) * hg4.y;
  float r2 = a.z + a.z * lfv * lg4.z + hfv * (bf2f(vv[2]) - a.z) * hg4.z;
  float r3 = a.w + a.w * lfv * lg4.w + hfv * (bf2f(vv[3]) - a.w) * hg4.w;
  u16x4 o = { f2bf(r0), f2bf(r1), f2bf(r2), f2bf(r3) };
  *(u16x4*)(y + e) = o;
}

// ---------------- spatial mean pool per (b,c) row ----------------
__global__ __launch_bounds__(256) void k_pool(const float* __restrict__ feat,
                                              float* __restrict__ pooled) {
  int row = blockIdx.x * 4 + (threadIdx.x >> 6);
  int l = threadIdx.x & 63;
  const float4* p = (const float4*)(feat + (size_t)row * N_);
  float4 a = p[l], b4 = p[l + 64], c4 = p[l + 128], d4 = p[l + 192];
  float s = a.x + a.y + a.z + a.w + b4.x + b4.y + b4.z + b4.w +
            c4.x + c4.y + c4.z + c4.w + d4.x + d4.y + d4.z + d4.w;
  #pragma unroll
  for (int off = 1; off < 64; off <<= 1) s += __shfl_xor(s, off);
  if (l == 0) pooled[row] = s * (1.f / 1024.f);
}

// ---------------- routing: pooled(B,C) -> routing(B,64) ----------------
__global__ __launch_bounds__(256) void k_routing(const float* __restrict__ pooled,
    const float* __restrict__ rw1, const float* __restrict__ rw1s,
    const float* __restrict__ rw1b, const float* __restrict__ rw2,
    float* __restrict__ routing) {
  const int b = blockIdx.x, t = threadIdx.x;
  __shared__ float plds[512];
  __shared__ float tile[64][65];
  __shared__ float hl[64];
  plds[t] = pooled[b * 512 + t];
  plds[t + 256] = pooled[b * 512 + t + 256];
  __syncthreads();
  float acc = 0.f;
  for (int c0 = 0; c0 < 512; c0 += 64) {
    #pragma unroll
    for (int kk = 0; kk < 16; ++kk) {
      int idx = kk * 256 + t;
      tile[idx >> 6][idx & 63] = rw1[(size_t)(idx >> 6) * 512 + c0 + (idx & 63)];
    }
    __syncthreads();
    if (t < 64) {
      #pragma unroll
      for (int i = 0; i < 64; ++i) acc += plds[c0 + i] * tile[t][i];
    }
    __syncthreads();
  }
  if (t < 64) {
    float r = fmaxf(acc, 0.f);
    hl[t] = rw1s[0] * r * r + rw1b[0];
  }
  __syncthreads();
  if (t < 64) {
    float r2 = 0.f;
    #pragma unroll
    for (int j = 0; j < 64; ++j) r2 += hl[j] * rw2[(size_t)t * 64 + j];
    routing[b * 64 + t] = tanhf(r2);
  }
}

// ---------------- per-plane 32x32 rfft2 * dyn -> irfft2 via MFMA ----------------
// 4 chained 32x32x32 matmuls (mfma computes A·B^T with both operands stored
// row-major over k). Tables: Tc=cos sym, Ts=sin sym, Tsn=-sin, Tcw=wg*cos,
// Tswn=-wg*sin (irfft weights, zero for fw>=17). Mask padded to stride 32
// (zeros for fw>=17) kills the unused upper half-spectrum.
__global__ __launch_bounds__(256) void k_freq(const float* __restrict__ feat,
    const float* __restrict__ routing, const float* __restrict__ fwtab,
    const unsigned short* __restrict__ gtab, float* __restrict__ enh) {
  const int c = blockIdx.x, b = blockIdx.y, t = threadIdx.x;
  const int g = c >> 5, cc = c & 31;
  const int w = t >> 6, l = t & 63;
  const int lane15 = l & 15, quad = l >> 4;
  const int mt = w & 1, nt = w >> 1;
  __shared__ __align__(16) unsigned short Xbf[32 * 40];
  __shared__ __align__(16) float p[32 * 36];
  __shared__ __align__(16) unsigned short Tabs[6400];   // 5 tables, 32x40 each
  __shared__ __align__(16) unsigned short pl1r[32 * 40], pl1i[32 * 40];
  __shared__ __align__(16) unsigned short pl2r[32 * 40], pl2i[32 * 40];
  __shared__ __align__(16) unsigned short pl3r[32 * 40], pl3i[32 * 40];
  __shared__ float Ms[1024];
  const size_t base = (size_t)(b * C_ + c) * N_;

  // load plane: residual f32 + bf16 operand
  {
    float4 v = ((const float4*)(feat + base))[t];
    int hh = t >> 3, w4 = (t & 7) * 4;
    *(float4*)&p[hh * 36 + w4] = v;
    u16x4 xb = { f2bf(v.x), f2bf(v.y), f2bf(v.z), f2bf(v.w) };
    *(u16x4*)&Xbf[hh * 40 + w4] = xb;
  }
  // tables: 12800B contiguous copy
  {
    const uint4* src = (const uint4*)gtab;
    uint4* dst = (uint4*)Tabs;
    #pragma unroll
    for (int k = 0; k < 4; ++k) {
      int o = k * 256 + t;
      if (o < 800) dst[o] = src[o];
    }
  }
  // mask, stride-32 padded (zero for fw>=17), 1/1024 folded
  {
    float r0 = routing[b * 64 + g * 4 + 0];
    float r1 = routing[b * 64 + g * 4 + 1];
    float r2 = routing[b * 64 + g * 4 + 2];
    float r3 = routing[b * 64 + g * 4 + 3];
    const float* fb = fwtab + (size_t)cc * 544;
    #pragma unroll
    for (int k = 0; k < 4; ++k) {
      int o = k * 256 + t;
      int fh = o >> 5, fw = o & 31;
      float mv = 0.f;
      if (fw < 17) {
        int fi = fh * 17 + fw;
        mv = (r0 * fb[fi] + r1 * fb[17408 + fi] + r2 * fb[34816 + fi] +
              r3 * fb[52224 + fi]) * (1.f / 1024.f);
      }
      Ms[o] = mv;
    }
  }
  __syncthreads();

  const unsigned short* Tc  = Tabs;
  const unsigned short* Ts  = Tabs + 1280;
  const unsigned short* Tsn = Tabs + 2560;
  const unsigned short* Tcw = Tabs + 3840;
  const unsigned short* Tsw = Tabs + 5120;
  const int arow = (mt * 16 + lane15) * 40 + quad * 8;
  const int brow = (nt * 16 + lane15) * 40 + quad * 8;
  const int prow = (nt * 16 + lane15) * 40 + mt * 16 + quad * 4;
  const f32x4 zz = (f32x4){0.f, 0.f, 0.f, 0.f};

  // stage 1: Re[h][fw] = X·Tc^T, Im = X·Tsn^T
  {
    bf16x8 aX = *(const bf16x8*)&Xbf[arow];
    bf16x8 bC = *(const bf16x8*)&Tc[brow];
    bf16x8 bS = *(const bf16x8*)&Tsn[brow];
    f32x4 re = __builtin_amdgcn_mfma_f32_16x16x32_bf16(aX, bC, zz, 0, 0, 0);
    f32x4 im = __builtin_amdgcn_mfma_f32_16x16x32_bf16(aX, bS, zz, 0, 0, 0);
    uint2 pr = make_uint2(__builtin_amdgcn_perm(f2u(re[1]), f2u(re[0]), 0x07060302u),
                          __builtin_amdgcn_perm(f2u(re[3]), f2u(re[2]), 0x07060302u));
    uint2 pi = make_uint2(__builtin_amdgcn_perm(f2u(im[1]), f2u(im[0]), 0x07060302u),
                          __builtin_amdgcn_perm(f2u(im[3]), f2u(im[2]), 0x07060302u));
    *(uint2*)&pl1r[prow] = pr;
    *(uint2*)&pl1i[prow] = pi;
  }
  __syncthreads();
  // stage 2: Er = C·Re + S·Im, Ei = C·Im - S·Re; then mask
  {
    bf16x8 aC = *(const bf16x8*)&Tc[arow];
    bf16x8 aS = *(const bf16x8*)&Ts[arow];
    bf16x8 aN = *(const bf16x8*)&Tsn[arow];
    bf16x8 bR = *(const bf16x8*)&pl1r[brow];
    bf16x8 bI = *(const bf16x8*)&pl1i[brow];
    f32x4 er = __builtin_amdgcn_mfma_f32_16x16x32_bf16(aC, bR, zz, 0, 0, 0);
    er = __builtin_amdgcn_mfma_f32_16x16x32_bf16(aS, bI, er, 0, 0, 0);
    f32x4 ei = __builtin_amdgcn_mfma_f32_16x16x32_bf16(aC, bI, zz, 0, 0, 0);
    ei = __builtin_amdgcn_mfma_f32_16x16x32_bf16(aN, bR, ei, 0, 0, 0);
    #pragma unroll
    for (int r = 0; r < 4; ++r) {
      float mk = Ms[(mt * 16 + quad * 4 + r) * 32 + nt * 16 + lane15];
      er[r] *= mk; ei[r] *= mk;
    }
    uint2 pr = make_uint2(__builtin_amdgcn_perm(f2u(er[1]), f2u(er[0]), 0x07060302u),
                          __builtin_amdgcn_perm(f2u(er[3]), f2u(er[2]), 0x07060302u));
    uint2 pi = make_uint2(__builtin_amdgcn_perm(f2u(ei[1]), f2u(ei[0]), 0x07060302u),
                          __builtin_amdgcn_perm(f2u(ei[3]), f2u(ei[2]), 0x07060302u));
    *(uint2*)&pl2r[prow] = pr;
    *(uint2*)&pl2i[prow] = pi;
  }
  __syncthreads();
  // stage 3: Zr^T = Gr^T·C - Gi^T·S, Zi^T = Gi^T·C + Gr^T·S  (C,S symmetric)
  {
    bf16x8 aR = *(const bf16x8*)&pl2r[arow];
    bf16x8 aI = *(const bf16x8*)&pl2i[arow];
    bf16x8 bC = *(const bf16x8*)&Tc[brow];
    bf16x8 bS = *(const bf16x8*)&Ts[brow];
    bf16x8 bN = *(const bf16x8*)&Tsn[brow];
    f32x4 zr = __builtin_amdgcn_mfma_f32_16x16x32_bf16(aR, bC, zz, 0, 0, 0);
    zr = __builtin_amdgcn_mfma_f32_16x16x32_bf16(aI, bN, zr, 0, 0, 0);
    f32x4 zi = __builtin_amdgcn_mfma_f32_16x16x32_bf16(aI, bC, zz, 0, 0, 0);
    zi = __builtin_amdgcn_mfma_f32_16x16x32_bf16(aR, bS, zi, 0, 0, 0);
    uint2 pr = make_uint2(__builtin_amdgcn_perm(f2u(zr[1]), f2u(zr[0]), 0x07060302u),
                          __builtin_amdgcn_perm(f2u(zr[3]), f2u(zr[2]), 0x07060302u));
    uint2 pi = make_uint2(__builtin_amdgcn_perm(f2u(zi[1]), f2u(zi[0]), 0x07060302u),
                          __builtin_amdgcn_perm(f2u(zi[3]), f2u(zi[2]), 0x07060302u));
    *(uint2*)&pl3r[prow] = pr;
    *(uint2*)&pl3i[prow] = pi;
  }
  __syncthreads();
  // stage 4: Y^T[w][h] = Tcw·Zr^T + Tswn·Zi^T; add residual, store
  {
    bf16x8 aC = *(const bf16x8*)&Tcw[arow];
    bf16x8 aS = *(const bf16x8*)&Tsw[arow];
    bf16x8 bR = *(const bf16x8*)&pl3r[brow];
    bf16x8 bI = *(const bf16x8*)&pl3i[brow];
    f32x4 y = __builtin_amdgcn_mfma_f32_16x16x32_bf16(aC, bR, zz, 0, 0, 0);
    y = __builtin_amdgcn_mfma_f32_16x16x32_bf16(aS, bI, y, 0, 0, 0);
    int hh = nt * 16 + lane15, w0 = mt * 16 + quad * 4;
    float4 res = *(const float4*)&p[hh * 36 + w0];
    float4 o = make_float4(y[0] + res.x, y[1] + res.y, y[2] + res.z, y[3] + res.w);
    *(float4*)&enh[base + hh * 32 + w0] = o;
  }
}

// ---------------- tokens += gamma * enh^T ----------------
__global__ __launch_bounds__(256) void k_add_t(const float* __restrict__ enh,
    const float* __restrict__ gamma, float* __restrict__ tok) {
  __shared__ float s[32][33];
  const int n0 = blockIdx.x * 32, c0 = blockIdx.y * 32, b = blockIdx.z;
  const int j = threadIdx.x & 31, i0 = threadIdx.x >> 5;
  #pragma unroll
  for (int k = 0; k < 4; ++k) {
    int i = i0 + k * 8;
    s[i][j] = enh[(size_t)(b * C_ + c0 + i) * N_ + n0 + j];
  }
  __syncthreads();
  float gv = gamma[c0 + j];
  #pragma unroll
  for (int k = 0; k < 4; ++k) {
    int i = i0 + k * 8;
    size_t o = (size_t)(b * N_ + n0 + i) * C_ + c0 + j;
    tok[o] += gv * s[j][i];
  }
}

// ---------------- final: out = tokens^T + gamma2 * enh ----------------
__global__ __launch_bounds__(256) void k_final(const float* __restrict__ tok,
    const float* __restrict__ gamma, const float* __restrict__ enh,
    float* __restrict__ out) {
  __shared__ float s[32][33];
  const int n0 = blockIdx.x * 32, c0 = blockIdx.y * 32, b = blockIdx.z;
  const int j = threadIdx.x & 31, i0 = threadIdx.x >> 5;
  #pragma unroll
  for (int k = 0; k < 4; ++k) {
    int i = i0 + k * 8;
    s[i][j] = tok[(size_t)(b * N_ + n0 + i) * C_ + c0 + j];
  }
  __syncthreads();
  #pragma unroll
  for (int k = 0; k < 4; ++k) {
    int i = i0 + k * 8;   // c-local
    size_t o = (size_t)(b * C_ + c0 + i) * N_ + n0 + j;
    out[o] = s[j][i] + gamma[c0 + i] * enh[o];
  }
}

// =============================== launch ===============================
extern "C" void kernel_launch(void* const* d_in, const int* in_sizes, int n_in,
                              void* d_out, int out_size, void* d_ws, size_t ws_size,
                              hipStream_t stream) {
  (void)in_sizes; (void)n_in; (void)out_size; (void)ws_size;
  const float* x      = (const float*)d_in[0];
  const float* n1w    = (const float*)d_in[1];
  const float* n1b    = (const float*)d_in[2];
  const float* qkv_w  = (const float*)d_in[3];
  const float* proj_w = (const float*)d_in[4];
  const float* proj_b = (const float*)d_in[5];
  const float* pa_s   = (const float*)d_in[6];
  const float* pa_b   = (const float*)d_in[7];
  const float* lf_w   = (const float*)d_in[8];
  const float* lf_b   = (const float*)d_in[9];
  const float* hf_w   = (const float*)d_in[10];
  const float* hf_b   = (const float*)d_in[11];
  const float* lf_g   = (const float*)d_in[12];
  const float* hf_g   = (const float*)d_in[13];
  const float* f1rw1w = (const float*)d_in[14];
  const float* f1rw1s = (const float*)d_in[15];
  const float* f1rw1b = (const float*)d_in[16];
  const float* f1rw2w = (const float*)d_in[17];
  const float* f1fw   = (const float*)d_in[18];
  const float* gamma1 = (const float*)d_in[19];
  const float* n2w    = (const float*)d_in[20];
  const float* n2b    = (const float*)d_in[21];
  const float* fc1w   = (const float*)d_in[22];
  const float* fc1b   = (const float*)d_in[23];
  const float* fc2w   = (const float*)d_in[24];
  const float* fc2b   = (const float*)d_in[25];
  const float* f2rw1w = (const float*)d_in[26];
  const float* f2rw1s = (const float*)d_in[27];
  const float* f2rw1b = (const float*)d_in[28];
  const float* f2rw2w = (const float*)d_in[29];
  const float* f2fw   = (const float*)d_in[30];
  const float* gamma2 = (const float*)d_in[31];

  char* ws = (char*)d_ws;
  float*          tokens = (float*)(ws + 0);
  float*          f1buf  = (float*)(ws + 33554432ULL);
  float*          f2buf  = (float*)(ws + 67108864ULL);
  float*          f3buf  = (float*)(ws + 100663296ULL);
  unsigned short* regA   = (unsigned short*)(ws + 134217728ULL);
  unsigned short* abuf   = (unsigned short*)(ws + 201326592ULL);
  float*          lfbuf  = (float*)(ws + 218103808ULL);
  float*          hfbuf  = (float*)(ws + 218628096ULL);
  float*          pooled = (float*)(ws + 219152384ULL);
  float*          routing= (float*)(ws + 219185152ULL);
  unsigned short* wq     = (unsigned short*)(ws + 219189248ULL);
  unsigned short* wp     = (unsigned short*)(ws + 220762112ULL);
  unsigned short* w1     = (unsigned short*)(ws + 221286400ULL);
  unsigned short* w2     = (unsigned short*)(ws + 223383552ULL);
  unsigned short* gtab   = (unsigned short*)(ws + 225480704ULL);

  // weights -> bf16, twiddle tables
  k_f2b<<<3072, 256, 0, stream>>>(qkv_w, wq, 786432);
  k_f2b<<<1024, 256, 0, stream>>>(proj_w, wp, 262144);
  k_f2b<<<4096, 256, 0, stream>>>(fc1w, w1, 1048576);
  k_f2b<<<4096, 256, 0, stream>>>(fc2w, w2, 1048576);
  k_twid<<<25, 256, 0, stream>>>(gtab);

  k_transpose_cn<<<dim3(32, 16, 16), 256, 0, stream>>>(x, tokens);
  k_ln<true><<<4096, 256, 0, stream>>>(tokens, n1w, n1b, lf_w, lf_b, hf_w, hf_b,
                                       pa_s, pa_b, abuf, lfbuf, hfbuf);
  k_gemm<0><<<dim3(12, 128), 256, 0, stream>>>(abuf, wq, n1b, regA, C3_, C_);
  k_vrepack<<<dim3(32, 2, 128), 256, 0, stream>>>(regA, (unsigned short*)f2buf);
  k_flash<<<dim3(16, 8, 16), 256, 0, stream>>>(regA, (unsigned short*)f2buf, f1buf);
  k_fuse<<<8192, 256, 0, stream>>>(f1buf, regA, lfbuf, hfbuf, lf_g, hf_g, abuf);
  k_gemm<1><<<dim3(4, 128), 256, 0, stream>>>(abuf, wp, proj_b, f1buf, C_, C_);
  k_transpose_nc<<<dim3(32, 16, 16), 256, 0, stream>>>(f1buf, f2buf);
  k_pool<<<2048, 256, 0, stream>>>(f2buf, pooled);
  k_routing<<<16, 256, 0, stream>>>(pooled, f1rw1w, f1rw1s, f1rw1b, f1rw2w, routing);
  k_freq<<<dim3(512, 16), 256, 0, stream>>>(f2buf, routing, f1fw, gtab, f3buf);
  k_add_t<<<dim3(32, 16, 16), 256, 0, stream>>>(f3buf, gamma1, tokens);
  k_ln<false><<<4096, 256, 0, stream>>>(tokens, n2w, n2b, nullptr, nullptr, nullptr,
                                        nullptr, nullptr, nullptr, abuf, nullptr, nullptr);
  k_gemm<2><<<dim3(16, 128), 256, 0, stream>>>(abuf, w1, fc1b, regA, CH_, C_);
  k_gemm<3><<<dim3(4, 128), 256, 0, stream>>>(regA, w2, fc2b, f1buf, C_, CH_);
  k_transpose_nc<<<dim3(32, 16, 16), 256, 0, stream>>>(f1buf, f2buf);
  k_pool<<<2048, 256, 0, stream>>>(f2buf, pooled);
  k_routing<<<16, 256, 0, stream>>>(pooled, f2rw1w, f2rw1s, f2rw1b, f2rw2w, routing);
  k_freq<<<dim3(512, 16), 256, 0, stream>>>(f2buf, routing, f2fw, gtab, f3buf);
  k_final<<<dim3(32, 16, 16), 256, 0, stream>>>(tokens, gamma2, f3buf, (float*)d_out);
}

// Round 4
// 598.100 us; speedup vs baseline: 1.4647x; 1.0487x over previous
//
#include <hip/hip_runtime.h>
#include <cstdint>
#include <cstddef>

#define B_   16
#define C_   512
#define N_   1024
#define M_   (B_*N_)
#define NH_  8
#define HD_  64
#define C3_  1536
#define CH_  2048

typedef __attribute__((ext_vector_type(8))) short bf16x8;
typedef __attribute__((ext_vector_type(4))) float f32x4;
typedef __attribute__((ext_vector_type(4))) unsigned short u16x4;

__device__ __forceinline__ unsigned short f2bf(float f) {
  union { float f; unsigned u; } v; v.f = f;
  unsigned r = v.u + 0x7fffu + ((v.u >> 16) & 1u);
  return (unsigned short)(r >> 16);
}
__device__ __forceinline__ float bf2f(unsigned short h) {
  union { unsigned u; float f; } v; v.u = ((unsigned)h) << 16;
  return v.f;
}
__device__ __forceinline__ unsigned f2u(float f) {
  union { float f; unsigned u; } v; v.f = f; return v.u;
}
__device__ __forceinline__ void gl_lds16(const void* g, void* l) {
  __builtin_amdgcn_global_load_lds((const __attribute__((address_space(1))) void*)g,
                                   (__attribute__((address_space(3))) void*)l,
                                   16, 0, 0);
}

// ---------------- float -> bf16 weight conversion ----------------
__global__ __launch_bounds__(256) void k_f2b(const float* __restrict__ src,
                                             unsigned short* __restrict__ dst, int n) {
  int i = blockIdx.x * 256 + threadIdx.x;
  if (i < n) dst[i] = f2bf(src[i]);
}

// ---------------- twiddle tables (bf16, stride 40), 5 tables of 32x40 ----------------
__global__ __launch_bounds__(256) void k_twid(unsigned short* __restrict__ gtab) {
  int idx = blockIdx.x * 256 + threadIdx.x;
  if (idx >= 6400) return;
  int tab = idx / 1280, rem = idx % 1280;
  int i = rem / 40, j = rem % 40;
  float v = 0.f;
  if (j < 32) {
    float th = 0.19634954084936207f * (float)((i * j) & 31);
    float s, c;
    __sincosf(th, &s, &c);
    if (tab == 0) v = c;
    else if (tab == 1) v = s;
    else if (tab == 2) v = -s;
    else {
      float wg = (j == 0 || j == 16) ? 1.f : 2.f;
      if (j >= 17) wg = 0.f;
      v = (tab == 3) ? wg * c : -wg * s;
    }
  }
  gtab[idx] = f2bf(v);
}

// ---------------- transpose (B,C,N) f32 -> (B,N,C) f32 ----------------
__global__ __launch_bounds__(256) void k_transpose_cn(const float* __restrict__ x,
                                                      float* __restrict__ tok) {
  __shared__ float s[32][33];
  const int n0 = blockIdx.x * 32, c0 = blockIdx.y * 32, b = blockIdx.z;
  const int j = threadIdx.x & 31, i0 = threadIdx.x >> 5;
  #pragma unroll
  for (int k = 0; k < 4; ++k) {
    int i = i0 + k * 8;
    s[i][j] = x[(size_t)(b * C_ + c0 + i) * N_ + n0 + j];
  }
  __syncthreads();
  #pragma unroll
  for (int k = 0; k < 4; ++k) {
    int i = i0 + k * 8;
    tok[(size_t)(b * N_ + n0 + i) * C_ + c0 + j] = s[j][i];
  }
}

// ---------------- transpose (B,N,C) f32 -> (B,C,N) f32 ----------------
__global__ __launch_bounds__(256) void k_transpose_nc(const float* __restrict__ in,
                                                      float* __restrict__ out) {
  __shared__ float s[32][33];
  const int n0 = blockIdx.x * 32, c0 = blockIdx.y * 32, b = blockIdx.z;
  const int j = threadIdx.x & 31, i0 = threadIdx.x >> 5;
  #pragma unroll
  for (int k = 0; k < 4; ++k) {
    int i = i0 + k * 8;
    s[i][j] = in[(size_t)(b * N_ + n0 + i) * C_ + c0 + j];
  }
  __syncthreads();
  #pragma unroll
  for (int k = 0; k < 4; ++k) {
    int i = i0 + k * 8;
    out[(size_t)(b * C_ + c0 + i) * N_ + n0 + j] = s[j][i];
  }
}

// ---------------- V repack: qkv (M,1536) bf16 -> vt (B,NH,HD,N) bf16 ----------------
__global__ __launch_bounds__(256) void k_vrepack(const unsigned short* __restrict__ qkv,
                                                 unsigned short* __restrict__ vtg) {
  __shared__ unsigned short s[32][34];
  const int n0 = blockIdx.x * 32, d0 = blockIdx.y * 32, bh = blockIdx.z;
  const int b = bh >> 3, h = bh & 7;
  const int j = threadIdx.x & 31, i0 = threadIdx.x >> 5;
  #pragma unroll
  for (int k = 0; k < 4; ++k) {
    int i = i0 + k * 8;  // n-local
    s[i][j] = qkv[(size_t)(b * N_ + n0 + i) * C3_ + 1024 + h * 64 + d0 + j];
  }
  __syncthreads();
  #pragma unroll
  for (int k = 0; k < 4; ++k) {
    int i = i0 + k * 8;  // d-local
    vtg[(size_t)(bh * HD_ + d0 + i) * N_ + n0 + j] = s[j][i];
  }
}

// ---------------- LayerNorm (+ optional lf/hf head gates) ----------------
template<bool WITH>
__global__ __launch_bounds__(256) void k_ln(const float* __restrict__ tok,
    const float* __restrict__ w, const float* __restrict__ bia,
    const float* __restrict__ lfw, const float* __restrict__ lfb,
    const float* __restrict__ hfw, const float* __restrict__ hfb,
    const float* __restrict__ pa_s, const float* __restrict__ pa_b,
    unsigned short* __restrict__ lnout, float* __restrict__ lfout,
    float* __restrict__ hfout) {
  const int t = threadIdx.x, wv = t >> 6, l = t & 63;
  const int row = blockIdx.x * 4 + wv;
  const float* p = tok + (size_t)row * C_;
  float v[8];
  *(float4*)&v[0] = *(const float4*)(p + 4 * l);
  *(float4*)&v[4] = *(const float4*)(p + 256 + 4 * l);
  float s = 0.f, q = 0.f;
  #pragma unroll
  for (int i = 0; i < 8; ++i) { s += v[i]; q += v[i] * v[i]; }
  #pragma unroll
  for (int off = 1; off < 64; off <<= 1) { s += __shfl_xor(s, off); q += __shfl_xor(q, off); }
  float mu = s * (1.f / 512.f);
  float var = q * (1.f / 512.f) - mu * mu;
  float rstd = rsqrtf(var + 1e-5f);
  float wv8[8], bv8[8];
  *(float4*)&wv8[0] = *(const float4*)(w + 4 * l);
  *(float4*)&wv8[4] = *(const float4*)(w + 256 + 4 * l);
  *(float4*)&bv8[0] = *(const float4*)(bia + 4 * l);
  *(float4*)&bv8[4] = *(const float4*)(bia + 256 + 4 * l);
  float ln[8];
  #pragma unroll
  for (int i = 0; i < 8; ++i) ln[i] = (v[i] - mu) * rstd * wv8[i] + bv8[i];
  u16x4 o0 = { f2bf(ln[0]), f2bf(ln[1]), f2bf(ln[2]), f2bf(ln[3]) };
  u16x4 o1 = { f2bf(ln[4]), f2bf(ln[5]), f2bf(ln[6]), f2bf(ln[7]) };
  *(u16x4*)(lnout + (size_t)row * C_ + 4 * l) = o0;
  *(u16x4*)(lnout + (size_t)row * C_ + 256 + 4 * l) = o1;
  if (WITH) {
    float ps = pa_s[0], pb = pa_b[0];
    float d[8];
    #pragma unroll
    for (int i = 0; i < 8; ++i) { float r = fmaxf(ln[i], 0.f); d[i] = ps * r * r + pb; }
    float lacc[8], hacc[8];
    #pragma unroll
    for (int h = 0; h < 8; ++h) {
      float lw[8], hw[8];
      *(float4*)&lw[0] = *(const float4*)(lfw + h * C_ + 4 * l);
      *(float4*)&lw[4] = *(const float4*)(lfw + h * C_ + 256 + 4 * l);
      *(float4*)&hw[0] = *(const float4*)(hfw + h * C_ + 4 * l);
      *(float4*)&hw[4] = *(const float4*)(hfw + h * C_ + 256 + 4 * l);
      float la = 0.f, ha = 0.f;
      #pragma unroll
      for (int i = 0; i < 8; ++i) { la += d[i] * lw[i]; ha += d[i] * hw[i]; }
      lacc[h] = la; hacc[h] = ha;
    }
    #pragma unroll
    for (int h = 0; h < 8; ++h)
      #pragma unroll
      for (int off = 1; off < 64; off <<= 1) {
        lacc[h] += __shfl_xor(lacc[h], off);
        hacc[h] += __shfl_xor(hacc[h], off);
      }
    float lv = lacc[0], hv = hacc[0];
    #pragma unroll
    for (int h = 1; h < 8; ++h) { if (l == h) { lv = lacc[h]; hv = hacc[h]; } }
    if (l < 8) {
      lfout[(size_t)row * 8 + l] = tanhf(lv + lfb[l]);
      float z = hv + hfb[l];
      float sp = (z > 15.f) ? z : log1pf(__expf(z));
      float s2 = sp * sp;
      hfout[(size_t)row * 8 + l] = 2.f * s2 / (s2 + 0.3678f);
    }
  }
}

// ---------------- GEMM: A(M,K)bf16 x Bt(N,K)bf16, 128x128 tile ----------------
template<int EPI>
__global__ __launch_bounds__(256) void k_gemm(const unsigned short* __restrict__ A,
    const unsigned short* __restrict__ Bt, const float* __restrict__ bias,
    void* __restrict__ outv, int Nn, int K) {
  __shared__ unsigned short Asm[128 * 32];
  __shared__ unsigned short Bsm[128 * 32];
  const int t = threadIdx.x, w = t >> 6, l = t & 63;
  const int lane15 = l & 15, quad = l >> 4;
  const int n0 = blockIdx.x * 128, m0 = blockIdx.y * 128;
  const int wm = w >> 1, wn = w & 1;
  f32x4 acc[4][4];
  #pragma unroll
  for (int i = 0; i < 4; ++i)
    #pragma unroll
    for (int j = 0; j < 4; ++j) acc[i][j] = (f32x4){0.f, 0.f, 0.f, 0.f};
  const unsigned short* Ab = A + (size_t)(m0 + (t >> 2)) * K + (t & 3) * 8;
  const unsigned short* Bb = Bt + (size_t)(n0 + (t >> 2)) * K + (t & 3) * 8;
  char* lA = (char*)Asm + w * 1024;
  char* lB = (char*)Bsm + w * 1024;
  const size_t rstep = (size_t)64 * K;
  for (int k0 = 0; k0 < K; k0 += 32) {
    gl_lds16(Ab + k0, lA);
    gl_lds16(Ab + rstep + k0, lA + 4096);
    gl_lds16(Bb + k0, lB);
    gl_lds16(Bb + rstep + k0, lB + 4096);
    __syncthreads();
    bf16x8 af[4], bg[4];
    #pragma unroll
    for (int i = 0; i < 4; ++i)
      af[i] = *(const bf16x8*)&Asm[(wm * 64 + i * 16 + lane15) * 32 + quad * 8];
    #pragma unroll
    for (int i = 0; i < 4; ++i)
      bg[i] = *(const bf16x8*)&Bsm[(wn * 64 + i * 16 + lane15) * 32 + quad * 8];
    #pragma unroll
    for (int i = 0; i < 4; ++i)
      #pragma unroll
      for (int j = 0; j < 4; ++j)
        acc[i][j] = __builtin_amdgcn_mfma_f32_16x16x32_bf16(af[i], bg[j], acc[i][j], 0, 0, 0);
    __syncthreads();
  }
  #pragma unroll
  for (int i = 0; i < 4; ++i) {
    int grow = m0 + wm * 64 + i * 16 + quad * 4;
    #pragma unroll
    for (int j = 0; j < 4; ++j) {
      int gcol = n0 + wn * 64 + j * 16 + lane15;
      float bs = (EPI == 0) ? 0.f : bias[gcol];
      #pragma unroll
      for (int r = 0; r < 4; ++r) {
        float vv = acc[i][j][r] + bs;
        size_t o = (size_t)(grow + r) * Nn + gcol;
        if (EPI == 0) ((unsigned short*)outv)[o] = f2bf(vv);
        else if (EPI == 1 || EPI == 3) ((float*)outv)[o] = vv;
        else {
          float g = 0.5f * vv * (1.f + erff(vv * 0.70710678118f));
          ((unsigned short*)outv)[o] = f2bf(g);
        }
      }
    }
  }
}

// ---------------- flash attention v3: no-max softmax (exp2 domain), fused gates ----------------
// Scores s = q·k/8 are bounded (|s| << 80), so softmax = exp2(s*log2e)/sum without
// the max shift. Per-lane denominator accumulated across tiles, reduced once.
// Epilogue fuses: y = a + a*lf*lg + hf*(v - a)*hg, bf16 store (feeds proj GEMM).
__global__ __launch_bounds__(256) void k_flash(const unsigned short* __restrict__ qkv,
    const unsigned short* __restrict__ vtg, const float* __restrict__ lf,
    const float* __restrict__ hf, const float* __restrict__ lgam,
    const float* __restrict__ hgam, unsigned short* __restrict__ y) {
  const int t = threadIdx.x, w = t >> 6, l = t & 63;
  const int lane15 = l & 15, quad = l >> 4;
  const int q0 = blockIdx.x * 64;
  const int h = blockIdx.y, b = blockIdx.z;
  __shared__ __align__(16) unsigned short kt[64 * 72];
  __shared__ __align__(16) unsigned short vt[64 * 72];
  __shared__ __align__(16) unsigned short pl[4][16 * 72];

  // Q fragment pre-scaled by 0.125*log2(e) in f32 (single bf16 rounding)
  bf16x8 aq0, aq1;
  {
    const unsigned short* qp = qkv + (size_t)(b * N_ + q0 + w * 16 + lane15) * C3_ + h * 64 + quad * 8;
    bf16x8 r0 = *(const bf16x8*)qp;
    bf16x8 r1 = *(const bf16x8*)(qp + 32);
    #pragma unroll
    for (int i = 0; i < 8; ++i) {
      aq0[i] = (short)f2bf(0.1803368801111713f * bf2f((unsigned short)r0[i]));
      aq1[i] = (short)f2bf(0.1803368801111713f * bf2f((unsigned short)r1[i]));
    }
  }
  f32x4 O[4];
  #pragma unroll
  for (int i = 0; i < 4; ++i) O[i] = (f32x4){0.f, 0.f, 0.f, 0.f};
  float lsum = 0.f;

  const int sr = t >> 3;
  const int sc = (t & 7) * 8;
  const unsigned short* kb = qkv + (size_t)(b * N_ + sr) * C3_ + 512 + h * 64 + sc;
  const unsigned short* vb = vtg + (size_t)((b * NH_ + h) * HD_ + sr) * N_ + sc;
  bf16x8 gk0 = *(const bf16x8*)kb;
  bf16x8 gk1 = *(const bf16x8*)(kb + (size_t)32 * C3_);
  bf16x8 gv0 = *(const bf16x8*)vb;
  bf16x8 gv1 = *(const bf16x8*)(vb + 32 * N_);

  for (int kti = 0; kti < 16; ++kti) {
    __syncthreads();
    *(bf16x8*)&kt[sr * 72 + sc] = gk0;
    *(bf16x8*)&kt[(sr + 32) * 72 + sc] = gk1;
    *(bf16x8*)&vt[sr * 72 + sc] = gv0;
    *(bf16x8*)&vt[(sr + 32) * 72 + sc] = gv1;
    __syncthreads();
    if (kti < 15) {
      const unsigned short* kn = kb + (size_t)((kti + 1) * 64) * C3_;
      const unsigned short* vn = vb + (kti + 1) * 64;
      gk0 = *(const bf16x8*)kn;
      gk1 = *(const bf16x8*)(kn + (size_t)32 * C3_);
      gv0 = *(const bf16x8*)vn;
      gv1 = *(const bf16x8*)(vn + 32 * N_);
    }

    // S^T tiles: D[n-local][q]
    f32x4 S[4];
    #pragma unroll
    for (int nt = 0; nt < 4; ++nt) {
      bf16x8 ak0 = *(const bf16x8*)&kt[(nt * 16 + lane15) * 72 + quad * 8];
      bf16x8 ak1 = *(const bf16x8*)&kt[(nt * 16 + lane15) * 72 + 32 + quad * 8];
      f32x4 z = (f32x4){0.f, 0.f, 0.f, 0.f};
      z = __builtin_amdgcn_mfma_f32_16x16x32_bf16(ak0, aq0, z, 0, 0, 0);
      z = __builtin_amdgcn_mfma_f32_16x16x32_bf16(ak1, aq1, z, 0, 0, 0);
      S[nt] = z;
    }

    // P = exp2(S); per-lane denominator accumulate (reduced after loop)
    #pragma unroll
    for (int nt = 0; nt < 4; ++nt)
      #pragma unroll
      for (int r = 0; r < 4; ++r) {
        float pv = __builtin_amdgcn_exp2f(S[nt][r]);
        S[nt][r] = pv;
        lsum += pv;
      }

    // pack P^T -> pl[q=lane15][n]
    #pragma unroll
    for (int nt = 0; nt < 4; ++nt) {
      unsigned lo = __builtin_amdgcn_perm(f2u(S[nt][1]), f2u(S[nt][0]), 0x07060302u);
      unsigned hi = __builtin_amdgcn_perm(f2u(S[nt][3]), f2u(S[nt][2]), 0x07060302u);
      uint2 pk = make_uint2(lo, hi);
      *(uint2*)&pl[w][lane15 * 72 + nt * 16 + quad * 4] = pk;
    }

    // PV: O[q][d] += P[q][n] V[n][d]
    #pragma unroll
    for (int nc = 0; nc < 2; ++nc) {
      bf16x8 ap = *(const bf16x8*)&pl[w][lane15 * 72 + nc * 32 + quad * 8];
      #pragma unroll
      for (int dt = 0; dt < 4; ++dt) {
        bf16x8 bv = *(const bf16x8*)&vt[(dt * 16 + lane15) * 72 + nc * 32 + quad * 8];
        O[dt] = __builtin_amdgcn_mfma_f32_16x16x32_bf16(ap, bv, O[dt], 0, 0, 0);
      }
    }
  }

  lsum += __shfl_xor(lsum, 16);
  lsum += __shfl_xor(lsum, 32);
  float inv = 1.f / lsum;  // valid for q=lane15 on every lane
  float invr[4], lfr[4], hfr[4];
  #pragma unroll
  for (int r = 0; r < 4; ++r) {
    invr[r] = __shfl(inv, quad * 4 + r);
    int grow = b * N_ + q0 + w * 16 + quad * 4 + r;
    lfr[r] = lf[grow * 8 + h];
    hfr[r] = hf[grow * 8 + h];
  }
  const size_t rowb = (size_t)(b * N_ + q0 + w * 16 + quad * 4);
  #pragma unroll
  for (int dt = 0; dt < 4; ++dt) {
    int cc = h * 64 + dt * 16 + lane15;
    float lg = lgam[cc], hg = hgam[cc];
    #pragma unroll
    for (int r = 0; r < 4; ++r) {
      float a = O[dt][r] * invr[r];
      float vval = bf2f(qkv[(rowb + r) * C3_ + 1024 + cc]);
      float res = a + a * lfr[r] * lg + hfr[r] * (vval - a) * hg;
      y[(rowb + r) * C_ + cc] = f2bf(res);
    }
  }
}

// ---------------- spatial mean pool per (b,c) row ----------------
__global__ __launch_bounds__(256) void k_pool(const float* __restrict__ feat,
                                              float* __restrict__ pooled) {
  int row = blockIdx.x * 4 + (threadIdx.x >> 6);
  int l = threadIdx.x & 63;
  const float4* p = (const float4*)(feat + (size_t)row * N_);
  float4 a = p[l], b4 = p[l + 64], c4 = p[l + 128], d4 = p[l + 192];
  float s = a.x + a.y + a.z + a.w + b4.x + b4.y + b4.z + b4.w +
            c4.x + c4.y + c4.z + c4.w + d4.x + d4.y + d4.z + d4.w;
  #pragma unroll
  for (int off = 1; off < 64; off <<= 1) s += __shfl_xor(s, off);
  if (l == 0) pooled[row] = s * (1.f / 1024.f);
}

// ---------------- routing: pooled(B,C) -> routing(B,64) ----------------
__global__ __launch_bounds__(256) void k_routing(const float* __restrict__ pooled,
    const float* __restrict__ rw1, const float* __restrict__ rw1s,
    const float* __restrict__ rw1b, const float* __restrict__ rw2,
    float* __restrict__ routing) {
  const int b = blockIdx.x, t = threadIdx.x;
  __shared__ float plds[512];
  __shared__ float tile[64][65];
  __shared__ float hl[64];
  plds[t] = pooled[b * 512 + t];
  plds[t + 256] = pooled[b * 512 + t + 256];
  __syncthreads();
  float acc = 0.f;
  for (int c0 = 0; c0 < 512; c0 += 64) {
    #pragma unroll
    for (int kk = 0; kk < 16; ++kk) {
      int idx = kk * 256 + t;
      tile[idx >> 6][idx & 63] = rw1[(size_t)(idx >> 6) * 512 + c0 + (idx & 63)];
    }
    __syncthreads();
    if (t < 64) {
      #pragma unroll
      for (int i = 0; i < 64; ++i) acc += plds[c0 + i] * tile[t][i];
    }
    __syncthreads();
  }
  if (t < 64) {
    float r = fmaxf(acc, 0.f);
    hl[t] = rw1s[0] * r * r + rw1b[0];
  }
  __syncthreads();
  if (t < 64) {
    float r2 = 0.f;
    #pragma unroll
    for (int j = 0; j < 64; ++j) r2 += hl[j] * rw2[(size_t)t * 64 + j];
    routing[b * 64 + t] = tanhf(r2);
  }
}

// ---------------- per-plane 32x32 rfft2 * dyn -> irfft2 via MFMA ----------------
__global__ __launch_bounds__(256) void k_freq(const float* __restrict__ feat,
    const float* __restrict__ routing, const float* __restrict__ fwtab,
    const unsigned short* __restrict__ gtab, float* __restrict__ enh) {
  const int c = blockIdx.x, b = blockIdx.y, t = threadIdx.x;
  const int g = c >> 5, cc = c & 31;
  const int w = t >> 6, l = t & 63;
  const int lane15 = l & 15, quad = l >> 4;
  const int mt = w & 1, nt = w >> 1;
  __shared__ __align__(16) unsigned short Xbf[32 * 40];
  __shared__ __align__(16) float p[32 * 36];
  __shared__ __align__(16) unsigned short Tabs[6400];
  __shared__ __align__(16) unsigned short pl1r[32 * 40], pl1i[32 * 40];
  __shared__ __align__(16) unsigned short pl2r[32 * 40], pl2i[32 * 40];
  __shared__ __align__(16) unsigned short pl3r[32 * 40], pl3i[32 * 40];
  __shared__ float Ms[1024];
  const size_t base = (size_t)(b * C_ + c) * N_;

  {
    float4 v = ((const float4*)(feat + base))[t];
    int hh = t >> 3, w4 = (t & 7) * 4;
    *(float4*)&p[hh * 36 + w4] = v;
    u16x4 xb = { f2bf(v.x), f2bf(v.y), f2bf(v.z), f2bf(v.w) };
    *(u16x4*)&Xbf[hh * 40 + w4] = xb;
  }
  {
    const uint4* src = (const uint4*)gtab;
    uint4* dst = (uint4*)Tabs;
    #pragma unroll
    for (int k = 0; k < 4; ++k) {
      int o = k * 256 + t;
      if (o < 800) dst[o] = src[o];
    }
  }
  {
    float r0 = routing[b * 64 + g * 4 + 0];
    float r1 = routing[b * 64 + g * 4 + 1];
    float r2 = routing[b * 64 + g * 4 + 2];
    float r3 = routing[b * 64 + g * 4 + 3];
    const float* fb = fwtab + (size_t)cc * 544;
    #pragma unroll
    for (int k = 0; k < 4; ++k) {
      int o = k * 256 + t;
      int fh = o >> 5, fw = o & 31;
      float mv = 0.f;
      if (fw < 17) {
        int fi = fh * 17 + fw;
        mv = (r0 * fb[fi] + r1 * fb[17408 + fi] + r2 * fb[34816 + fi] +
              r3 * fb[52224 + fi]) * (1.f / 1024.f);
      }
      Ms[o] = mv;
    }
  }
  __syncthreads();

  const unsigned short* Tc  = Tabs;
  const unsigned short* Ts  = Tabs + 1280;
  const unsigned short* Tsn = Tabs + 2560;
  const unsigned short* Tcw = Tabs + 3840;
  const unsigned short* Tsw = Tabs + 5120;
  const int arow = (mt * 16 + lane15) * 40 + quad * 8;
  const int brow = (nt * 16 + lane15) * 40 + quad * 8;
  const int prow = (nt * 16 + lane15) * 40 + mt * 16 + quad * 4;
  const f32x4 zz = (f32x4){0.f, 0.f, 0.f, 0.f};

  {
    bf16x8 aX = *(const bf16x8*)&Xbf[arow];
    bf16x8 bC = *(const bf16x8*)&Tc[brow];
    bf16x8 bS = *(const bf16x8*)&Tsn[brow];
    f32x4 re = __builtin_amdgcn_mfma_f32_16x16x32_bf16(aX, bC, zz, 0, 0, 0);
    f32x4 im = __builtin_amdgcn_mfma_f32_16x16x32_bf16(aX, bS, zz, 0, 0, 0);
    uint2 pr = make_uint2(__builtin_amdgcn_perm(f2u(re[1]), f2u(re[0]), 0x07060302u),
                          __builtin_amdgcn_perm(f2u(re[3]), f2u(re[2]), 0x07060302u));
    uint2 pi = make_uint2(__builtin_amdgcn_perm(f2u(im[1]), f2u(im[0]), 0x07060302u),
                          __builtin_amdgcn_perm(f2u(im[3]), f2u(im[2]), 0x07060302u));
    *(uint2*)&pl1r[prow] = pr;
    *(uint2*)&pl1i[prow] = pi;
  }
  __syncthreads();
  {
    bf16x8 aC = *(const bf16x8*)&Tc[arow];
    bf16x8 aS = *(const bf16x8*)&Ts[arow];
    bf16x8 aN = *(const bf16x8*)&Tsn[arow];
    bf16x8 bR = *(const bf16x8*)&pl1r[brow];
    bf16x8 bI = *(const bf16x8*)&pl1i[brow];
    f32x4 er = __builtin_amdgcn_mfma_f32_16x16x32_bf16(aC, bR, zz, 0, 0, 0);
    er = __builtin_amdgcn_mfma_f32_16x16x32_bf16(aS, bI, er, 0, 0, 0);
    f32x4 ei = __builtin_amdgcn_mfma_f32_16x16x32_bf16(aC, bI, zz, 0, 0, 0);
    ei = __builtin_amdgcn_mfma_f32_16x16x32_bf16(aN, bR, ei, 0, 0, 0);
    #pragma unroll
    for (int r = 0; r < 4; ++r) {
      float mk = Ms[(mt * 16 + quad * 4 + r) * 32 + nt * 16 + lane15];
      er[r] *= mk; ei[r] *= mk;
    }
    uint2 pr = make_uint2(__builtin_amdgcn_perm(f2u(er[1]), f2u(er[0]), 0x07060302u),
                          __builtin_amdgcn_perm(f2u(er[3]), f2u(er[2]), 0x07060302u));
    uint2 pi = make_uint2(__builtin_amdgcn_perm(f2u(ei[1]), f2u(ei[0]), 0x07060302u),
                          __builtin_amdgcn_perm(f2u(ei[3]), f2u(ei[2]), 0x07060302u));
    *(uint2*)&pl2r[prow] = pr;
    *(uint2*)&pl2i[prow] = pi;
  }
  __syncthreads();
  {
    bf16x8 aR = *(const bf16x8*)&pl2r[arow];
    bf16x8 aI = *(const bf16x8*)&pl2i[arow];
    bf16x8 bC = *(const bf16x8*)&Tc[brow];
    bf16x8 bS = *(const bf16x8*)&Ts[brow];
    bf16x8 bN = *(const bf16x8*)&Tsn[brow];
    f32x4 zr = __builtin_amdgcn_mfma_f32_16x16x32_bf16(aR, bC, zz, 0, 0, 0);
    zr = __builtin_amdgcn_mfma_f32_16x16x32_bf16(aI, bN, zr, 0, 0, 0);
    f32x4 zi = __builtin_amdgcn_mfma_f32_16x16x32_bf16(aI, bC, zz, 0, 0, 0);
    zi = __builtin_amdgcn_mfma_f32_16x16x32_bf16(aR, bS, zi, 0, 0, 0);
    uint2 pr = make_uint2(__builtin_amdgcn_perm(f2u(zr[1]), f2u(zr[0]), 0x07060302u),
                          __builtin_amdgcn_perm(f2u(zr[3]), f2u(zr[2]), 0x07060302u));
    uint2 pi = make_uint2(__builtin_amdgcn_perm(f2u(zi[1]), f2u(zi[0]), 0x07060302u),
                          __builtin_amdgcn_perm(f2u(zi[3]), f2u(zi[2]), 0x07060302u));
    *(uint2*)&pl3r[prow] = pr;
    *(uint2*)&pl3i[prow] = pi;
  }
  __syncthreads();
  {
    bf16x8 aC = *(const bf16x8*)&Tcw[arow];
    bf16x8 aS = *(const bf16x8*)&Tsw[arow];
    bf16x8 bR = *(const bf16x8*)&pl3r[brow];
    bf16x8 bI = *(const bf16x8*)&pl3i[brow];
    f32x4 y = __builtin_amdgcn_mfma_f32_16x16x32_bf16(aC, bR, zz, 0, 0, 0);
    y = __builtin_amdgcn_mfma_f32_16x16x32_bf16(aS, bI, y, 0, 0, 0);
    int hh = nt * 16 + lane15, w0 = mt * 16 + quad * 4;
    float4 res = *(const float4*)&p[hh * 36 + w0];
    float4 o = make_float4(y[0] + res.x, y[1] + res.y, y[2] + res.z, y[3] + res.w);
    *(float4*)&enh[base + hh * 32 + w0] = o;
  }
}

// ---------------- tokens += gamma * enh^T ----------------
__global__ __launch_bounds__(256) void k_add_t(const float* __restrict__ enh,
    const float* __restrict__ gamma, float* __restrict__ tok) {
  __shared__ float s[32][33];
  const int n0 = blockIdx.x * 32, c0 = blockIdx.y * 32, b = blockIdx.z;
  const int j = threadIdx.x & 31, i0 = threadIdx.x >> 5;
  #pragma unroll
  for (int k = 0; k < 4; ++k) {
    int i = i0 + k * 8;
    s[i][j] = enh[(size_t)(b * C_ + c0 + i) * N_ + n0 + j];
  }
  __syncthreads();
  float gv = gamma[c0 + j];
  #pragma unroll
  for (int k = 0; k < 4; ++k) {
    int i = i0 + k * 8;
    size_t o = (size_t)(b * N_ + n0 + i) * C_ + c0 + j;
    tok[o] += gv * s[j][i];
  }
}

// ---------------- final: out = tokens^T + gamma2 * enh ----------------
__global__ __launch_bounds__(256) void k_final(const float* __restrict__ tok,
    const float* __restrict__ gamma, const float* __restrict__ enh,
    float* __restrict__ out) {
  __shared__ float s[32][33];
  const int n0 = blockIdx.x * 32, c0 = blockIdx.y * 32, b = blockIdx.z;
  const int j = threadIdx.x & 31, i0 = threadIdx.x >> 5;
  #pragma unroll
  for (int k = 0; k < 4; ++k) {
    int i = i0 + k * 8;
    s[i][j] = tok[(size_t)(b * N_ + n0 + i) * C_ + c0 + j];
  }
  __syncthreads();
  #pragma unroll
  for (int k = 0; k < 4; ++k) {
    int i = i0 + k * 8;   // c-local
    size_t o = (size_t)(b * C_ + c0 + i) * N_ + n0 + j;
    out[o] = s[j][i] + gamma[c0 + i] * enh[o];
  }
}

// =============================== launch ===============================
extern "C" void kernel_launch(void* const* d_in, const int* in_sizes, int n_in,
                              void* d_out, int out_size, void* d_ws, size_t ws_size,
                              hipStream_t stream) {
  (void)in_sizes; (void)n_in; (void)out_size; (void)ws_size;
  const float* x      = (const float*)d_in[0];
  const float* n1w    = (const float*)d_in[1];
  const float* n1b    = (const float*)d_in[2];
  const float* qkv_w  = (const float*)d_in[3];
  const float* proj_w = (const float*)d_in[4];
  const float* proj_b = (const float*)d_in[5];
  const float* pa_s   = (const float*)d_in[6];
  const float* pa_b   = (const float*)d_in[7];
  const float* lf_w   = (const float*)d_in[8];
  const float* lf_b   = (const float*)d_in[9];
  const float* hf_w   = (const float*)d_in[10];
  const float* hf_b   = (const float*)d_in[11];
  const float* lf_g   = (const float*)d_in[12];
  const float* hf_g   = (const float*)d_in[13];
  const float* f1rw1w = (const float*)d_in[14];
  const float* f1rw1s = (const float*)d_in[15];
  const float* f1rw1b = (const float*)d_in[16];
  const float* f1rw2w = (const float*)d_in[17];
  const float* f1fw   = (const float*)d_in[18];
  const float* gamma1 = (const float*)d_in[19];
  const float* n2w    = (const float*)d_in[20];
  const float* n2b    = (const float*)d_in[21];
  const float* fc1w   = (const float*)d_in[22];
  const float* fc1b   = (const float*)d_in[23];
  const float* fc2w   = (const float*)d_in[24];
  const float* fc2b   = (const float*)d_in[25];
  const float* f2rw1w = (const float*)d_in[26];
  const float* f2rw1s = (const float*)d_in[27];
  const float* f2rw1b = (const float*)d_in[28];
  const float* f2rw2w = (const float*)d_in[29];
  const float* f2fw   = (const float*)d_in[30];
  const float* gamma2 = (const float*)d_in[31];

  char* ws = (char*)d_ws;
  float*          tokens = (float*)(ws + 0);
  float*          f1buf  = (float*)(ws + 33554432ULL);
  float*          f2buf  = (float*)(ws + 67108864ULL);
  float*          f3buf  = (float*)(ws + 100663296ULL);
  unsigned short* regA   = (unsigned short*)(ws + 134217728ULL);
  unsigned short* abuf   = (unsigned short*)(ws + 201326592ULL);
  float*          lfbuf  = (float*)(ws + 218103808ULL);
  float*          hfbuf  = (float*)(ws + 218628096ULL);
  float*          pooled = (float*)(ws + 219152384ULL);
  float*          routing= (float*)(ws + 219185152ULL);
  unsigned short* wq     = (unsigned short*)(ws + 219189248ULL);
  unsigned short* wp     = (unsigned short*)(ws + 220762112ULL);
  unsigned short* w1     = (unsigned short*)(ws + 221286400ULL);
  unsigned short* w2     = (unsigned short*)(ws + 223383552ULL);
  unsigned short* gtab   = (unsigned short*)(ws + 225480704ULL);

  // weights -> bf16, twiddle tables
  k_f2b<<<3072, 256, 0, stream>>>(qkv_w, wq, 786432);
  k_f2b<<<1024, 256, 0, stream>>>(proj_w, wp, 262144);
  k_f2b<<<4096, 256, 0, stream>>>(fc1w, w1, 1048576);
  k_f2b<<<4096, 256, 0, stream>>>(fc2w, w2, 1048576);
  k_twid<<<25, 256, 0, stream>>>(gtab);

  k_transpose_cn<<<dim3(32, 16, 16), 256, 0, stream>>>(x, tokens);
  k_ln<true><<<4096, 256, 0, stream>>>(tokens, n1w, n1b, lf_w, lf_b, hf_w, hf_b,
                                       pa_s, pa_b, abuf, lfbuf, hfbuf);
  k_gemm<0><<<dim3(12, 128), 256, 0, stream>>>(abuf, wq, n1b, regA, C3_, C_);
  k_vrepack<<<dim3(32, 2, 128), 256, 0, stream>>>(regA, (unsigned short*)f2buf);
  // flash + fused gates -> abuf bf16 (proj input)
  k_flash<<<dim3(16, 8, 16), 256, 0, stream>>>(regA, (unsigned short*)f2buf,
                                               lfbuf, hfbuf, lf_g, hf_g, abuf);
  k_gemm<1><<<dim3(4, 128), 256, 0, stream>>>(abuf, wp, proj_b, f1buf, C_, C_);
  k_transpose_nc<<<dim3(32, 16, 16), 256, 0, stream>>>(f1buf, f2buf);
  k_pool<<<2048, 256, 0, stream>>>(f2buf, pooled);
  k_routing<<<16, 256, 0, stream>>>(pooled, f1rw1w, f1rw1s, f1rw1b, f1rw2w, routing);
  k_freq<<<dim3(512, 16), 256, 0, stream>>>(f2buf, routing, f1fw, gtab, f3buf);
  k_add_t<<<dim3(32, 16, 16), 256, 0, stream>>>(f3buf, gamma1, tokens);
  k_ln<false><<<4096, 256, 0, stream>>>(tokens, n2w, n2b, nullptr, nullptr, nullptr,
                                        nullptr, nullptr, nullptr, abuf, nullptr, nullptr);
  k_gemm<2><<<dim3(16, 128), 256, 0, stream>>>(abuf, w1, fc1b, regA, CH_, C_);
  k_gemm<3><<<dim3(4, 128), 256, 0, stream>>>(regA, w2, fc2b, f1buf, C_, CH_);
  k_transpose_nc<<<dim3(32, 16, 16), 256, 0, stream>>>(f1buf, f2buf);
  k_pool<<<2048, 256, 0, stream>>>(f2buf, pooled);
  k_routing<<<16, 256, 0, stream>>>(pooled, f2rw1w, f2rw1s, f2rw1b, f2rw2w, routing);
  k_freq<<<dim3(512, 16), 256, 0, stream>>>(f2buf, routing, f2fw, gtab, f3buf);
  k_final<<<dim3(32, 16, 16), 256, 0, stream>>>(tokens, gamma2, f3buf, (float*)d_out);
}

// Round 5
// 555.889 us; speedup vs baseline: 1.5759x; 1.0759x over previous
//
#include <hip/hip_runtime.h>
#include <cstdint>
#include <cstddef>

#define B_   16
#define C_   512
#define N_   1024
#define M_   (B_*N_)
#define NH_  8
#define HD_  64
#define C3_  1536
#define CH_  2048

typedef __attribute__((ext_vector_type(8))) short bf16x8;
typedef __attribute__((ext_vector_type(4))) float f32x4;
typedef __attribute__((ext_vector_type(4))) unsigned short u16x4;

__device__ __forceinline__ unsigned short f2bf(float f) {
  union { float f; unsigned u; } v; v.f = f;
  unsigned r = v.u + 0x7fffu + ((v.u >> 16) & 1u);
  return (unsigned short)(r >> 16);
}
__device__ __forceinline__ float bf2f(unsigned short h) {
  union { unsigned u; float f; } v; v.u = ((unsigned)h) << 16;
  return v.f;
}
__device__ __forceinline__ unsigned f2u(float f) {
  union { float f; unsigned u; } v; v.f = f; return v.u;
}

// ---------------- float -> bf16 weight conversion ----------------
__global__ __launch_bounds__(256) void k_f2b(const float* __restrict__ src,
                                             unsigned short* __restrict__ dst, int n) {
  int i = blockIdx.x * 256 + threadIdx.x;
  if (i < n) dst[i] = f2bf(src[i]);
}

// ---------------- twiddle tables (bf16, stride 40), 5 tables of 32x40 ----------------
__global__ __launch_bounds__(256) void k_twid(unsigned short* __restrict__ gtab) {
  int idx = blockIdx.x * 256 + threadIdx.x;
  if (idx >= 6400) return;
  int tab = idx / 1280, rem = idx % 1280;
  int i = rem / 40, j = rem % 40;
  float v = 0.f;
  if (j < 32) {
    float th = 0.19634954084936207f * (float)((i * j) & 31);
    float s, c;
    __sincosf(th, &s, &c);
    if (tab == 0) v = c;
    else if (tab == 1) v = s;
    else if (tab == 2) v = -s;
    else {
      float wg = (j == 0 || j == 16) ? 1.f : 2.f;
      if (j >= 17) wg = 0.f;
      v = (tab == 3) ? wg * c : -wg * s;
    }
  }
  gtab[idx] = f2bf(v);
}

// ---------------- transpose (B,C,N) f32 -> (B,N,C) f32 ----------------
__global__ __launch_bounds__(256) void k_transpose_cn(const float* __restrict__ x,
                                                      float* __restrict__ tok) {
  __shared__ float s[32][33];
  const int n0 = blockIdx.x * 32, c0 = blockIdx.y * 32, b = blockIdx.z;
  const int j = threadIdx.x & 31, i0 = threadIdx.x >> 5;
  #pragma unroll
  for (int k = 0; k < 4; ++k) {
    int i = i0 + k * 8;
    s[i][j] = x[(size_t)(b * C_ + c0 + i) * N_ + n0 + j];
  }
  __syncthreads();
  #pragma unroll
  for (int k = 0; k < 4; ++k) {
    int i = i0 + k * 8;
    tok[(size_t)(b * N_ + n0 + i) * C_ + c0 + j] = s[j][i];
  }
}

// ---------------- LayerNorm (+ optional lf/hf head gates) ----------------
template<bool WITH>
__global__ __launch_bounds__(256) void k_ln(const float* __restrict__ tok,
    const float* __restrict__ w, const float* __restrict__ bia,
    const float* __restrict__ lfw, const float* __restrict__ lfb,
    const float* __restrict__ hfw, const float* __restrict__ hfb,
    const float* __restrict__ pa_s, const float* __restrict__ pa_b,
    unsigned short* __restrict__ lnout, float* __restrict__ lfout,
    float* __restrict__ hfout) {
  const int t = threadIdx.x, wv = t >> 6, l = t & 63;
  const int row = blockIdx.x * 4 + wv;
  const float* p = tok + (size_t)row * C_;
  float v[8];
  *(float4*)&v[0] = *(const float4*)(p + 4 * l);
  *(float4*)&v[4] = *(const float4*)(p + 256 + 4 * l);
  float s = 0.f, q = 0.f;
  #pragma unroll
  for (int i = 0; i < 8; ++i) { s += v[i]; q += v[i] * v[i]; }
  #pragma unroll
  for (int off = 1; off < 64; off <<= 1) { s += __shfl_xor(s, off); q += __shfl_xor(q, off); }
  float mu = s * (1.f / 512.f);
  float var = q * (1.f / 512.f) - mu * mu;
  float rstd = rsqrtf(var + 1e-5f);
  float wv8[8], bv8[8];
  *(float4*)&wv8[0] = *(const float4*)(w + 4 * l);
  *(float4*)&wv8[4] = *(const float4*)(w + 256 + 4 * l);
  *(float4*)&bv8[0] = *(const float4*)(bia + 4 * l);
  *(float4*)&bv8[4] = *(const float4*)(bia + 256 + 4 * l);
  float ln[8];
  #pragma unroll
  for (int i = 0; i < 8; ++i) ln[i] = (v[i] - mu) * rstd * wv8[i] + bv8[i];
  u16x4 o0 = { f2bf(ln[0]), f2bf(ln[1]), f2bf(ln[2]), f2bf(ln[3]) };
  u16x4 o1 = { f2bf(ln[4]), f2bf(ln[5]), f2bf(ln[6]), f2bf(ln[7]) };
  *(u16x4*)(lnout + (size_t)row * C_ + 4 * l) = o0;
  *(u16x4*)(lnout + (size_t)row * C_ + 256 + 4 * l) = o1;
  if (WITH) {
    float ps = pa_s[0], pb = pa_b[0];
    float d[8];
    #pragma unroll
    for (int i = 0; i < 8; ++i) { float r = fmaxf(ln[i], 0.f); d[i] = ps * r * r + pb; }
    float lacc[8], hacc[8];
    #pragma unroll
    for (int h = 0; h < 8; ++h) {
      float lw[8], hw[8];
      *(float4*)&lw[0] = *(const float4*)(lfw + h * C_ + 4 * l);
      *(float4*)&lw[4] = *(const float4*)(lfw + h * C_ + 256 + 4 * l);
      *(float4*)&hw[0] = *(const float4*)(hfw + h * C_ + 4 * l);
      *(float4*)&hw[4] = *(const float4*)(hfw + h * C_ + 256 + 4 * l);
      float la = 0.f, ha = 0.f;
      #pragma unroll
      for (int i = 0; i < 8; ++i) { la += d[i] * lw[i]; ha += d[i] * hw[i]; }
      lacc[h] = la; hacc[h] = ha;
    }
    #pragma unroll
    for (int h = 0; h < 8; ++h)
      #pragma unroll
      for (int off = 1; off < 64; off <<= 1) {
        lacc[h] += __shfl_xor(lacc[h], off);
        hacc[h] += __shfl_xor(hacc[h], off);
      }
    float lv = lacc[0], hv = hacc[0];
    #pragma unroll
    for (int h = 1; h < 8; ++h) { if (l == h) { lv = lacc[h]; hv = hacc[h]; } }
    if (l < 8) {
      lfout[(size_t)row * 8 + l] = tanhf(lv + lfb[l]);
      float z = hv + hfb[l];
      float sp = (z > 15.f) ? z : log1pf(__expf(z));
      float s2 = sp * sp;
      hfout[(size_t)row * 8 + l] = 2.f * s2 / (s2 + 0.3678f);
    }
  }
}

// ---------------- GEMM v2: reg-prefetch staging, padded LDS, fused epilogues ----------
// EPI 0: qkv -> bf16 (M,1536) + V also scattered to vtg (B,NH*HD,N) transposed
// EPI 1: proj -> f32 stored TRANSPOSED to (B,C,N) + bias
// EPI 2: fc1  -> bf16 (M,2048) + bias + fast gelu
// EPI 3: fc2  -> f32 stored TRANSPOSED to (B,C,N) + bias
template<int EPI>
__global__ __launch_bounds__(256) void k_gemm(const unsigned short* __restrict__ A,
    const unsigned short* __restrict__ Bt, const float* __restrict__ bias,
    void* __restrict__ outv, unsigned short* __restrict__ vtg, int Nn, int K) {
  __shared__ __align__(16) unsigned short Asm[128 * 40];
  __shared__ __align__(16) unsigned short Bsm[128 * 40];
  const int t = threadIdx.x, w = t >> 6, l = t & 63;
  const int lane15 = l & 15, quad = l >> 4;
  const int n0 = blockIdx.x * 128, m0 = blockIdx.y * 128;
  const int wm = w >> 1, wn = w & 1;
  f32x4 acc[4][4];
  #pragma unroll
  for (int i = 0; i < 4; ++i)
    #pragma unroll
    for (int j = 0; j < 4; ++j) acc[i][j] = (f32x4){0.f, 0.f, 0.f, 0.f};
  const int sr = t >> 2, sc = (t & 3) * 8;
  const unsigned short* Ab = A + (size_t)(m0 + sr) * K + sc;
  const unsigned short* Bb = Bt + (size_t)(n0 + sr) * K + sc;
  const size_t rstep = (size_t)64 * K;
  bf16x8 ga0 = *(const bf16x8*)Ab;
  bf16x8 ga1 = *(const bf16x8*)(Ab + rstep);
  bf16x8 gb0 = *(const bf16x8*)Bb;
  bf16x8 gb1 = *(const bf16x8*)(Bb + rstep);
  for (int k0 = 0; k0 < K; k0 += 32) {
    __syncthreads();
    *(bf16x8*)&Asm[sr * 40 + sc] = ga0;
    *(bf16x8*)&Asm[(sr + 64) * 40 + sc] = ga1;
    *(bf16x8*)&Bsm[sr * 40 + sc] = gb0;
    *(bf16x8*)&Bsm[(sr + 64) * 40 + sc] = gb1;
    __syncthreads();
    if (k0 + 32 < K) {   // prefetch next K-tile while computing this one
      ga0 = *(const bf16x8*)(Ab + k0 + 32);
      ga1 = *(const bf16x8*)(Ab + rstep + k0 + 32);
      gb0 = *(const bf16x8*)(Bb + k0 + 32);
      gb1 = *(const bf16x8*)(Bb + rstep + k0 + 32);
    }
    bf16x8 af[4], bg[4];
    #pragma unroll
    for (int i = 0; i < 4; ++i)
      af[i] = *(const bf16x8*)&Asm[(wm * 64 + i * 16 + lane15) * 40 + quad * 8];
    #pragma unroll
    for (int i = 0; i < 4; ++i)
      bg[i] = *(const bf16x8*)&Bsm[(wn * 64 + i * 16 + lane15) * 40 + quad * 8];
    #pragma unroll
    for (int i = 0; i < 4; ++i)
      #pragma unroll
      for (int j = 0; j < 4; ++j)
        acc[i][j] = __builtin_amdgcn_mfma_f32_16x16x32_bf16(af[i], bg[j], acc[i][j], 0, 0, 0);
  }
  #pragma unroll
  for (int i = 0; i < 4; ++i) {
    int grow = m0 + wm * 64 + i * 16 + quad * 4;
    int bq = grow >> 10, nq = grow & 1023;
    #pragma unroll
    for (int j = 0; j < 4; ++j) {
      int gcol = n0 + wn * 64 + j * 16 + lane15;
      float bs = (EPI == 0) ? 0.f : bias[gcol];
      if (EPI == 1 || EPI == 3) {
        float4 o = make_float4(acc[i][j][0] + bs, acc[i][j][1] + bs,
                               acc[i][j][2] + bs, acc[i][j][3] + bs);
        *(float4*)&((float*)outv)[((size_t)(bq * C_ + gcol) << 10) + nq] = o;
      } else if (EPI == 0) {
        u16x4 pv;
        #pragma unroll
        for (int r = 0; r < 4; ++r) {
          unsigned short hv = f2bf(acc[i][j][r]);
          pv[r] = hv;
          ((unsigned short*)outv)[(size_t)(grow + r) * Nn + gcol] = hv;
        }
        if (gcol >= 1024)
          *(u16x4*)&vtg[((size_t)(bq * C_ + gcol - 1024) << 10) + nq] = pv;
      } else {
        #pragma unroll
        for (int r = 0; r < 4; ++r) {
          float vv = acc[i][j][r] + bs;
          // tanh-form gelu: x * sigmoid(2*0.79788456*(x + 0.044715 x^3)), exp2 domain
          float e = __builtin_amdgcn_exp2f(-(2.302118073f * vv +
                                             0.1029455568f * vv * vv * vv));
          float g = vv * __builtin_amdgcn_rcpf(1.f + e);
          ((unsigned short*)outv)[(size_t)(grow + r) * Nn + gcol] = f2bf(g);
        }
      }
    }
  }
}

// ---------------- flash attention v3: no-max softmax (exp2 domain), fused gates ----------------
__global__ __launch_bounds__(256) void k_flash(const unsigned short* __restrict__ qkv,
    const unsigned short* __restrict__ vtg, const float* __restrict__ lf,
    const float* __restrict__ hf, const float* __restrict__ lgam,
    const float* __restrict__ hgam, unsigned short* __restrict__ y) {
  const int t = threadIdx.x, w = t >> 6, l = t & 63;
  const int lane15 = l & 15, quad = l >> 4;
  const int q0 = blockIdx.x * 64;
  const int h = blockIdx.y, b = blockIdx.z;
  __shared__ __align__(16) unsigned short kt[64 * 72];
  __shared__ __align__(16) unsigned short vt[64 * 72];
  __shared__ __align__(16) unsigned short pl[4][16 * 72];

  bf16x8 aq0, aq1;
  {
    const unsigned short* qp = qkv + (size_t)(b * N_ + q0 + w * 16 + lane15) * C3_ + h * 64 + quad * 8;
    bf16x8 r0 = *(const bf16x8*)qp;
    bf16x8 r1 = *(const bf16x8*)(qp + 32);
    #pragma unroll
    for (int i = 0; i < 8; ++i) {
      aq0[i] = (short)f2bf(0.1803368801111713f * bf2f((unsigned short)r0[i]));
      aq1[i] = (short)f2bf(0.1803368801111713f * bf2f((unsigned short)r1[i]));
    }
  }
  f32x4 O[4];
  #pragma unroll
  for (int i = 0; i < 4; ++i) O[i] = (f32x4){0.f, 0.f, 0.f, 0.f};
  float lsum = 0.f;

  const int sr = t >> 3;
  const int sc = (t & 7) * 8;
  const unsigned short* kb = qkv + (size_t)(b * N_ + sr) * C3_ + 512 + h * 64 + sc;
  const unsigned short* vb = vtg + (size_t)((b * NH_ + h) * HD_ + sr) * N_ + sc;
  bf16x8 gk0 = *(const bf16x8*)kb;
  bf16x8 gk1 = *(const bf16x8*)(kb + (size_t)32 * C3_);
  bf16x8 gv0 = *(const bf16x8*)vb;
  bf16x8 gv1 = *(const bf16x8*)(vb + 32 * N_);

  for (int kti = 0; kti < 16; ++kti) {
    __syncthreads();
    *(bf16x8*)&kt[sr * 72 + sc] = gk0;
    *(bf16x8*)&kt[(sr + 32) * 72 + sc] = gk1;
    *(bf16x8*)&vt[sr * 72 + sc] = gv0;
    *(bf16x8*)&vt[(sr + 32) * 72 + sc] = gv1;
    __syncthreads();
    if (kti < 15) {
      const unsigned short* kn = kb + (size_t)((kti + 1) * 64) * C3_;
      const unsigned short* vn = vb + (kti + 1) * 64;
      gk0 = *(const bf16x8*)kn;
      gk1 = *(const bf16x8*)(kn + (size_t)32 * C3_);
      gv0 = *(const bf16x8*)vn;
      gv1 = *(const bf16x8*)(vn + 32 * N_);
    }

    f32x4 S[4];
    #pragma unroll
    for (int nt = 0; nt < 4; ++nt) {
      bf16x8 ak0 = *(const bf16x8*)&kt[(nt * 16 + lane15) * 72 + quad * 8];
      bf16x8 ak1 = *(const bf16x8*)&kt[(nt * 16 + lane15) * 72 + 32 + quad * 8];
      f32x4 z = (f32x4){0.f, 0.f, 0.f, 0.f};
      z = __builtin_amdgcn_mfma_f32_16x16x32_bf16(ak0, aq0, z, 0, 0, 0);
      z = __builtin_amdgcn_mfma_f32_16x16x32_bf16(ak1, aq1, z, 0, 0, 0);
      S[nt] = z;
    }

    #pragma unroll
    for (int nt = 0; nt < 4; ++nt)
      #pragma unroll
      for (int r = 0; r < 4; ++r) {
        float pv = __builtin_amdgcn_exp2f(S[nt][r]);
        S[nt][r] = pv;
        lsum += pv;
      }

    #pragma unroll
    for (int nt = 0; nt < 4; ++nt) {
      unsigned lo = __builtin_amdgcn_perm(f2u(S[nt][1]), f2u(S[nt][0]), 0x07060302u);
      unsigned hi = __builtin_amdgcn_perm(f2u(S[nt][3]), f2u(S[nt][2]), 0x07060302u);
      uint2 pk = make_uint2(lo, hi);
      *(uint2*)&pl[w][lane15 * 72 + nt * 16 + quad * 4] = pk;
    }

    #pragma unroll
    for (int nc = 0; nc < 2; ++nc) {
      bf16x8 ap = *(const bf16x8*)&pl[w][lane15 * 72 + nc * 32 + quad * 8];
      #pragma unroll
      for (int dt = 0; dt < 4; ++dt) {
        bf16x8 bv = *(const bf16x8*)&vt[(dt * 16 + lane15) * 72 + nc * 32 + quad * 8];
        O[dt] = __builtin_amdgcn_mfma_f32_16x16x32_bf16(ap, bv, O[dt], 0, 0, 0);
      }
    }
  }

  lsum += __shfl_xor(lsum, 16);
  lsum += __shfl_xor(lsum, 32);
  float inv = 1.f / lsum;
  float invr[4], lfr[4], hfr[4];
  #pragma unroll
  for (int r = 0; r < 4; ++r) {
    invr[r] = __shfl(inv, quad * 4 + r);
    int grow = b * N_ + q0 + w * 16 + quad * 4 + r;
    lfr[r] = lf[grow * 8 + h];
    hfr[r] = hf[grow * 8 + h];
  }
  const size_t rowb = (size_t)(b * N_ + q0 + w * 16 + quad * 4);
  #pragma unroll
  for (int dt = 0; dt < 4; ++dt) {
    int cc = h * 64 + dt * 16 + lane15;
    float lg = lgam[cc], hg = hgam[cc];
    #pragma unroll
    for (int r = 0; r < 4; ++r) {
      float a = O[dt][r] * invr[r];
      float vval = bf2f(qkv[(rowb + r) * C3_ + 1024 + cc]);
      float res = a + a * lfr[r] * lg + hfr[r] * (vval - a) * hg;
      y[(rowb + r) * C_ + cc] = f2bf(res);
    }
  }
}

// ---------------- spatial mean pool per (b,c) row ----------------
__global__ __launch_bounds__(256) void k_pool(const float* __restrict__ feat,
                                              float* __restrict__ pooled) {
  int row = blockIdx.x * 4 + (threadIdx.x >> 6);
  int l = threadIdx.x & 63;
  const float4* p = (const float4*)(feat + (size_t)row * N_);
  float4 a = p[l], b4 = p[l + 64], c4 = p[l + 128], d4 = p[l + 192];
  float s = a.x + a.y + a.z + a.w + b4.x + b4.y + b4.z + b4.w +
            c4.x + c4.y + c4.z + c4.w + d4.x + d4.y + d4.z + d4.w;
  #pragma unroll
  for (int off = 1; off < 64; off <<= 1) s += __shfl_xor(s, off);
  if (l == 0) pooled[row] = s * (1.f / 1024.f);
}

// ---------------- routing: pooled(B,C) -> routing(B,64) ----------------
__global__ __launch_bounds__(256) void k_routing(const float* __restrict__ pooled,
    const float* __restrict__ rw1, const float* __restrict__ rw1s,
    const float* __restrict__ rw1b, const float* __restrict__ rw2,
    float* __restrict__ routing) {
  const int b = blockIdx.x, t = threadIdx.x;
  __shared__ float plds[512];
  __shared__ float tile[64][65];
  __shared__ float hl[64];
  plds[t] = pooled[b * 512 + t];
  plds[t + 256] = pooled[b * 512 + t + 256];
  __syncthreads();
  float acc = 0.f;
  for (int c0 = 0; c0 < 512; c0 += 64) {
    #pragma unroll
    for (int kk = 0; kk < 16; ++kk) {
      int idx = kk * 256 + t;
      tile[idx >> 6][idx & 63] = rw1[(size_t)(idx >> 6) * 512 + c0 + (idx & 63)];
    }
    __syncthreads();
    if (t < 64) {
      #pragma unroll
      for (int i = 0; i < 64; ++i) acc += plds[c0 + i] * tile[t][i];
    }
    __syncthreads();
  }
  if (t < 64) {
    float r = fmaxf(acc, 0.f);
    hl[t] = rw1s[0] * r * r + rw1b[0];
  }
  __syncthreads();
  if (t < 64) {
    float r2 = 0.f;
    #pragma unroll
    for (int j = 0; j < 64; ++j) r2 += hl[j] * rw2[(size_t)t * 64 + j];
    routing[b * 64 + t] = tanhf(r2);
  }
}

// ---------------- per-plane 32x32 rfft2 * dyn -> irfft2 via MFMA ----------------
__global__ __launch_bounds__(256) void k_freq(const float* __restrict__ feat,
    const float* __restrict__ routing, const float* __restrict__ fwtab,
    const unsigned short* __restrict__ gtab, float* __restrict__ enh) {
  const int c = blockIdx.x, b = blockIdx.y, t = threadIdx.x;
  const int g = c >> 5, cc = c & 31;
  const int w = t >> 6, l = t & 63;
  const int lane15 = l & 15, quad = l >> 4;
  const int mt = w & 1, nt = w >> 1;
  __shared__ __align__(16) unsigned short Xbf[32 * 40];
  __shared__ __align__(16) float p[32 * 36];
  __shared__ __align__(16) unsigned short Tabs[6400];
  __shared__ __align__(16) unsigned short pl1r[32 * 40], pl1i[32 * 40];
  __shared__ __align__(16) unsigned short pl2r[32 * 40], pl2i[32 * 40];
  __shared__ __align__(16) unsigned short pl3r[32 * 40], pl3i[32 * 40];
  __shared__ float Ms[1024];
  const size_t base = (size_t)(b * C_ + c) * N_;

  {
    float4 v = ((const float4*)(feat + base))[t];
    int hh = t >> 3, w4 = (t & 7) * 4;
    *(float4*)&p[hh * 36 + w4] = v;
    u16x4 xb = { f2bf(v.x), f2bf(v.y), f2bf(v.z), f2bf(v.w) };
    *(u16x4*)&Xbf[hh * 40 + w4] = xb;
  }
  {
    const uint4* src = (const uint4*)gtab;
    uint4* dst = (uint4*)Tabs;
    #pragma unroll
    for (int k = 0; k < 4; ++k) {
      int o = k * 256 + t;
      if (o < 800) dst[o] = src[o];
    }
  }
  {
    float r0 = routing[b * 64 + g * 4 + 0];
    float r1 = routing[b * 64 + g * 4 + 1];
    float r2 = routing[b * 64 + g * 4 + 2];
    float r3 = routing[b * 64 + g * 4 + 3];
    const float* fb = fwtab + (size_t)cc * 544;
    #pragma unroll
    for (int k = 0; k < 4; ++k) {
      int o = k * 256 + t;
      int fh = o >> 5, fw = o & 31;
      float mv = 0.f;
      if (fw < 17) {
        int fi = fh * 17 + fw;
        mv = (r0 * fb[fi] + r1 * fb[17408 + fi] + r2 * fb[34816 + fi] +
              r3 * fb[52224 + fi]) * (1.f / 1024.f);
      }
      Ms[o] = mv;
    }
  }
  __syncthreads();

  const unsigned short* Tc  = Tabs;
  const unsigned short* Ts  = Tabs + 1280;
  const unsigned short* Tsn = Tabs + 2560;
  const unsigned short* Tcw = Tabs + 3840;
  const unsigned short* Tsw = Tabs + 5120;
  const int arow = (mt * 16 + lane15) * 40 + quad * 8;
  const int brow = (nt * 16 + lane15) * 40 + quad * 8;
  const int prow = (nt * 16 + lane15) * 40 + mt * 16 + quad * 4;
  const f32x4 zz = (f32x4){0.f, 0.f, 0.f, 0.f};

  {
    bf16x8 aX = *(const bf16x8*)&Xbf[arow];
    bf16x8 bC = *(const bf16x8*)&Tc[brow];
    bf16x8 bS = *(const bf16x8*)&Tsn[brow];
    f32x4 re = __builtin_amdgcn_mfma_f32_16x16x32_bf16(aX, bC, zz, 0, 0, 0);
    f32x4 im = __builtin_amdgcn_mfma_f32_16x16x32_bf16(aX, bS, zz, 0, 0, 0);
    uint2 pr = make_uint2(__builtin_amdgcn_perm(f2u(re[1]), f2u(re[0]), 0x07060302u),
                          __builtin_amdgcn_perm(f2u(re[3]), f2u(re[2]), 0x07060302u));
    uint2 pi = make_uint2(__builtin_amdgcn_perm(f2u(im[1]), f2u(im[0]), 0x07060302u),
                          __builtin_amdgcn_perm(f2u(im[3]), f2u(im[2]), 0x07060302u));
    *(uint2*)&pl1r[prow] = pr;
    *(uint2*)&pl1i[prow] = pi;
  }
  __syncthreads();
  {
    bf16x8 aC = *(const bf16x8*)&Tc[arow];
    bf16x8 aS = *(const bf16x8*)&Ts[arow];
    bf16x8 aN = *(const bf16x8*)&Tsn[arow];
    bf16x8 bR = *(const bf16x8*)&pl1r[brow];
    bf16x8 bI = *(const bf16x8*)&pl1i[brow];
    f32x4 er = __builtin_amdgcn_mfma_f32_16x16x32_bf16(aC, bR, zz, 0, 0, 0);
    er = __builtin_amdgcn_mfma_f32_16x16x32_bf16(aS, bI, er, 0, 0, 0);
    f32x4 ei = __builtin_amdgcn_mfma_f32_16x16x32_bf16(aC, bI, zz, 0, 0, 0);
    ei = __builtin_amdgcn_mfma_f32_16x16x32_bf16(aN, bR, ei, 0, 0, 0);
    #pragma unroll
    for (int r = 0; r < 4; ++r) {
      float mk = Ms[(mt * 16 + quad * 4 + r) * 32 + nt * 16 + lane15];
      er[r] *= mk; ei[r] *= mk;
    }
    uint2 pr = make_uint2(__builtin_amdgcn_perm(f2u(er[1]), f2u(er[0]), 0x07060302u),
                          __builtin_amdgcn_perm(f2u(er[3]), f2u(er[2]), 0x07060302u));
    uint2 pi = make_uint2(__builtin_amdgcn_perm(f2u(ei[1]), f2u(ei[0]), 0x07060302u),
                          __builtin_amdgcn_perm(f2u(ei[3]), f2u(ei[2]), 0x07060302u));
    *(uint2*)&pl2r[prow] = pr;
    *(uint2*)&pl2i[prow] = pi;
  }
  __syncthreads();
  {
    bf16x8 aR = *(const bf16x8*)&pl2r[arow];
    bf16x8 aI = *(const bf16x8*)&pl2i[arow];
    bf16x8 bC = *(const bf16x8*)&Tc[brow];
    bf16x8 bS = *(const bf16x8*)&Ts[brow];
    bf16x8 bN = *(const bf16x8*)&Tsn[brow];
    f32x4 zr = __builtin_amdgcn_mfma_f32_16x16x32_bf16(aR, bC, zz, 0, 0, 0);
    zr = __builtin_amdgcn_mfma_f32_16x16x32_bf16(aI, bN, zr, 0, 0, 0);
    f32x4 zi = __builtin_amdgcn_mfma_f32_16x16x32_bf16(aI, bC, zz, 0, 0, 0);
    zi = __builtin_amdgcn_mfma_f32_16x16x32_bf16(aR, bS, zi, 0, 0, 0);
    uint2 pr = make_uint2(__builtin_amdgcn_perm(f2u(zr[1]), f2u(zr[0]), 0x07060302u),
                          __builtin_amdgcn_perm(f2u(zr[3]), f2u(zr[2]), 0x07060302u));
    uint2 pi = make_uint2(__builtin_amdgcn_perm(f2u(zi[1]), f2u(zi[0]), 0x07060302u),
                          __builtin_amdgcn_perm(f2u(zi[3]), f2u(zi[2]), 0x07060302u));
    *(uint2*)&pl3r[prow] = pr;
    *(uint2*)&pl3i[prow] = pi;
  }
  __syncthreads();
  {
    bf16x8 aC = *(const bf16x8*)&Tcw[arow];
    bf16x8 aS = *(const bf16x8*)&Tsw[arow];
    bf16x8 bR = *(const bf16x8*)&pl3r[brow];
    bf16x8 bI = *(const bf16x8*)&pl3i[brow];
    f32x4 y = __builtin_amdgcn_mfma_f32_16x16x32_bf16(aC, bR, zz, 0, 0, 0);
    y = __builtin_amdgcn_mfma_f32_16x16x32_bf16(aS, bI, y, 0, 0, 0);
    int hh = nt * 16 + lane15, w0 = mt * 16 + quad * 4;
    float4 res = *(const float4*)&p[hh * 36 + w0];
    float4 o = make_float4(y[0] + res.x, y[1] + res.y, y[2] + res.z, y[3] + res.w);
    *(float4*)&enh[base + hh * 32 + w0] = o;
  }
}

// ---------------- tokens += gamma * enh^T ----------------
__global__ __launch_bounds__(256) void k_add_t(const float* __restrict__ enh,
    const float* __restrict__ gamma, float* __restrict__ tok) {
  __shared__ float s[32][33];
  const int n0 = blockIdx.x * 32, c0 = blockIdx.y * 32, b = blockIdx.z;
  const int j = threadIdx.x & 31, i0 = threadIdx.x >> 5;
  #pragma unroll
  for (int k = 0; k < 4; ++k) {
    int i = i0 + k * 8;
    s[i][j] = enh[(size_t)(b * C_ + c0 + i) * N_ + n0 + j];
  }
  __syncthreads();
  float gv = gamma[c0 + j];
  #pragma unroll
  for (int k = 0; k < 4; ++k) {
    int i = i0 + k * 8;
    size_t o = (size_t)(b * N_ + n0 + i) * C_ + c0 + j;
    tok[o] += gv * s[j][i];
  }
}

// ---------------- final: out = tokens^T + gamma2 * enh ----------------
__global__ __launch_bounds__(256) void k_final(const float* __restrict__ tok,
    const float* __restrict__ gamma, const float* __restrict__ enh,
    float* __restrict__ out) {
  __shared__ float s[32][33];
  const int n0 = blockIdx.x * 32, c0 = blockIdx.y * 32, b = blockIdx.z;
  const int j = threadIdx.x & 31, i0 = threadIdx.x >> 5;
  #pragma unroll
  for (int k = 0; k < 4; ++k) {
    int i = i0 + k * 8;
    s[i][j] = tok[(size_t)(b * N_ + n0 + i) * C_ + c0 + j];
  }
  __syncthreads();
  #pragma unroll
  for (int k = 0; k < 4; ++k) {
    int i = i0 + k * 8;   // c-local
    size_t o = (size_t)(b * C_ + c0 + i) * N_ + n0 + j;
    out[o] = s[j][i] + gamma[c0 + i] * enh[o];
  }
}

// =============================== launch ===============================
extern "C" void kernel_launch(void* const* d_in, const int* in_sizes, int n_in,
                              void* d_out, int out_size, void* d_ws, size_t ws_size,
                              hipStream_t stream) {
  (void)in_sizes; (void)n_in; (void)out_size; (void)ws_size;
  const float* x      = (const float*)d_in[0];
  const float* n1w    = (const float*)d_in[1];
  const float* n1b    = (const float*)d_in[2];
  const float* qkv_w  = (const float*)d_in[3];
  const float* proj_w = (const float*)d_in[4];
  const float* proj_b = (const float*)d_in[5];
  const float* pa_s   = (const float*)d_in[6];
  const float* pa_b   = (const float*)d_in[7];
  const float* lf_w   = (const float*)d_in[8];
  const float* lf_b   = (const float*)d_in[9];
  const float* hf_w   = (const float*)d_in[10];
  const float* hf_b   = (const float*)d_in[11];
  const float* lf_g   = (const float*)d_in[12];
  const float* hf_g   = (const float*)d_in[13];
  const float* f1rw1w = (const float*)d_in[14];
  const float* f1rw1s = (const float*)d_in[15];
  const float* f1rw1b = (const float*)d_in[16];
  const float* f1rw2w = (const float*)d_in[17];
  const float* f1fw   = (const float*)d_in[18];
  const float* gamma1 = (const float*)d_in[19];
  const float* n2w    = (const float*)d_in[20];
  const float* n2b    = (const float*)d_in[21];
  const float* fc1w   = (const float*)d_in[22];
  const float* fc1b   = (const float*)d_in[23];
  const float* fc2w   = (const float*)d_in[24];
  const float* fc2b   = (const float*)d_in[25];
  const float* f2rw1w = (const float*)d_in[26];
  const float* f2rw1s = (const float*)d_in[27];
  const float* f2rw1b = (const float*)d_in[28];
  const float* f2rw2w = (const float*)d_in[29];
  const float* f2fw   = (const float*)d_in[30];
  const float* gamma2 = (const float*)d_in[31];

  char* ws = (char*)d_ws;
  float*          tokens = (float*)(ws + 0);
  float*          f1buf  = (float*)(ws + 33554432ULL);
  float*          f2buf  = (float*)(ws + 67108864ULL);
  float*          f3buf  = (float*)(ws + 100663296ULL);
  unsigned short* regA   = (unsigned short*)(ws + 134217728ULL);
  unsigned short* abuf   = (unsigned short*)(ws + 201326592ULL);
  float*          lfbuf  = (float*)(ws + 218103808ULL);
  float*          hfbuf  = (float*)(ws + 218628096ULL);
  float*          pooled = (float*)(ws + 219152384ULL);
  float*          routing= (float*)(ws + 219185152ULL);
  unsigned short* wq     = (unsigned short*)(ws + 219189248ULL);
  unsigned short* wp     = (unsigned short*)(ws + 220762112ULL);
  unsigned short* w1     = (unsigned short*)(ws + 221286400ULL);
  unsigned short* w2     = (unsigned short*)(ws + 223383552ULL);
  unsigned short* gtab   = (unsigned short*)(ws + 225480704ULL);
  unsigned short* vtg    = (unsigned short*)f1buf;   // 32 MB region reused for V^T

  // weights -> bf16, twiddle tables
  k_f2b<<<3072, 256, 0, stream>>>(qkv_w, wq, 786432);
  k_f2b<<<1024, 256, 0, stream>>>(proj_w, wp, 262144);
  k_f2b<<<4096, 256, 0, stream>>>(fc1w, w1, 1048576);
  k_f2b<<<4096, 256, 0, stream>>>(fc2w, w2, 1048576);
  k_twid<<<25, 256, 0, stream>>>(gtab);

  k_transpose_cn<<<dim3(32, 16, 16), 256, 0, stream>>>(x, tokens);
  k_ln<true><<<4096, 256, 0, stream>>>(tokens, n1w, n1b, lf_w, lf_b, hf_w, hf_b,
                                       pa_s, pa_b, abuf, lfbuf, hfbuf);
  // QKV GEMM; V additionally scattered to vtg (transposed) -- replaces k_vrepack
  k_gemm<0><<<dim3(12, 128), 256, 0, stream>>>(abuf, wq, n1b, regA, vtg, C3_, C_);
  // flash + fused gates -> abuf bf16 (proj input)
  k_flash<<<dim3(16, 8, 16), 256, 0, stream>>>(regA, vtg, lfbuf, hfbuf, lf_g, hf_g, abuf);
  // proj -> f2buf stored TRANSPOSED (B,C,N) -- replaces transpose_nc
  k_gemm<1><<<dim3(4, 128), 256, 0, stream>>>(abuf, wp, proj_b, f2buf, nullptr, C_, C_);
  k_pool<<<2048, 256, 0, stream>>>(f2buf, pooled);
  k_routing<<<16, 256, 0, stream>>>(pooled, f1rw1w, f1rw1s, f1rw1b, f1rw2w, routing);
  k_freq<<<dim3(512, 16), 256, 0, stream>>>(f2buf, routing, f1fw, gtab, f3buf);
  k_add_t<<<dim3(32, 16, 16), 256, 0, stream>>>(f3buf, gamma1, tokens);
  k_ln<false><<<4096, 256, 0, stream>>>(tokens, n2w, n2b, nullptr, nullptr, nullptr,
                                        nullptr, nullptr, nullptr, abuf, nullptr, nullptr);
  // fc1 + fast gelu -> regA bf16 (M,2048)
  k_gemm<2><<<dim3(16, 128), 256, 0, stream>>>(abuf, w1, fc1b, regA, nullptr, CH_, C_);
  // fc2 -> f2buf stored TRANSPOSED (B,C,N) -- replaces transpose_nc
  k_gemm<3><<<dim3(4, 128), 256, 0, stream>>>(regA, w2, fc2b, f2buf, nullptr, C_, CH_);
  k_pool<<<2048, 256, 0, stream>>>(f2buf, pooled);
  k_routing<<<16, 256, 0, stream>>>(pooled, f2rw1w, f2rw1s, f2rw1b, f2rw2w, routing);
  k_freq<<<dim3(512, 16), 256, 0, stream>>>(f2buf, routing, f2fw, gtab, f3buf);
  k_final<<<dim3(32, 16, 16), 256, 0, stream>>>(tokens, gamma2, f3buf, (float*)d_out);
}

// Round 6
// 555.037 us; speedup vs baseline: 1.5783x; 1.0015x over previous
//
#include <hip/hip_runtime.h>
#include <cstdint>
#include <cstddef>

#define B_   16
#define C_   512
#define N_   1024
#define M_   (B_*N_)
#define NH_  8
#define HD_  64
#define C3_  1536
#define CH_  2048

typedef __attribute__((ext_vector_type(8))) short bf16x8;
typedef __attribute__((ext_vector_type(4))) float f32x4;
typedef __attribute__((ext_vector_type(4))) unsigned short u16x4;

__device__ __forceinline__ unsigned short f2bf(float f) {
  union { float f; unsigned u; } v; v.f = f;
  unsigned r = v.u + 0x7fffu + ((v.u >> 16) & 1u);
  return (unsigned short)(r >> 16);
}
__device__ __forceinline__ float bf2f(unsigned short h) {
  union { unsigned u; float f; } v; v.u = ((unsigned)h) << 16;
  return v.f;
}
__device__ __forceinline__ unsigned f2u(float f) {
  union { float f; unsigned u; } v; v.f = f; return v.u;
}

// ---------------- float -> bf16 weight conversion ----------------
__global__ __launch_bounds__(256) void k_f2b(const float* __restrict__ src,
                                             unsigned short* __restrict__ dst, int n) {
  int i = blockIdx.x * 256 + threadIdx.x;
  if (i < n) dst[i] = f2bf(src[i]);
}

// ---------------- twiddle tables (bf16, stride 40), 5 tables of 32x40 ----------------
__global__ __launch_bounds__(256) void k_twid(unsigned short* __restrict__ gtab) {
  int idx = blockIdx.x * 256 + threadIdx.x;
  if (idx >= 6400) return;
  int tab = idx / 1280, rem = idx % 1280;
  int i = rem / 40, j = rem % 40;
  float v = 0.f;
  if (j < 32) {
    float th = 0.19634954084936207f * (float)((i * j) & 31);
    float s, c;
    __sincosf(th, &s, &c);
    if (tab == 0) v = c;
    else if (tab == 1) v = s;
    else if (tab == 2) v = -s;
    else {
      float wg = (j == 0 || j == 16) ? 1.f : 2.f;
      if (j >= 17) wg = 0.f;
      v = (tab == 3) ? wg * c : -wg * s;
    }
  }
  gtab[idx] = f2bf(v);
}

// ---------------- transpose (B,C,N) f32 -> (B,N,C) f32 ----------------
__global__ __launch_bounds__(256) void k_transpose_cn(const float* __restrict__ x,
                                                      float* __restrict__ tok) {
  __shared__ float s[32][33];
  const int n0 = blockIdx.x * 32, c0 = blockIdx.y * 32, b = blockIdx.z;
  const int j = threadIdx.x & 31, i0 = threadIdx.x >> 5;
  #pragma unroll
  for (int k = 0; k < 4; ++k) {
    int i = i0 + k * 8;
    s[i][j] = x[(size_t)(b * C_ + c0 + i) * N_ + n0 + j];
  }
  __syncthreads();
  #pragma unroll
  for (int k = 0; k < 4; ++k) {
    int i = i0 + k * 8;
    tok[(size_t)(b * N_ + n0 + i) * C_ + c0 + j] = s[j][i];
  }
}

// ---------------- LayerNorm (+ optional lf/hf head gates) ----------------
template<bool WITH>
__global__ __launch_bounds__(256) void k_ln(const float* __restrict__ tok,
    const float* __restrict__ w, const float* __restrict__ bia,
    const float* __restrict__ lfw, const float* __restrict__ lfb,
    const float* __restrict__ hfw, const float* __restrict__ hfb,
    const float* __restrict__ pa_s, const float* __restrict__ pa_b,
    unsigned short* __restrict__ lnout, float* __restrict__ lfout,
    float* __restrict__ hfout) {
  const int t = threadIdx.x, wv = t >> 6, l = t & 63;
  const int row = blockIdx.x * 4 + wv;
  const float* p = tok + (size_t)row * C_;
  float v[8];
  *(float4*)&v[0] = *(const float4*)(p + 4 * l);
  *(float4*)&v[4] = *(const float4*)(p + 256 + 4 * l);
  float s = 0.f, q = 0.f;
  #pragma unroll
  for (int i = 0; i < 8; ++i) { s += v[i]; q += v[i] * v[i]; }
  #pragma unroll
  for (int off = 1; off < 64; off <<= 1) { s += __shfl_xor(s, off); q += __shfl_xor(q, off); }
  float mu = s * (1.f / 512.f);
  float var = q * (1.f / 512.f) - mu * mu;
  float rstd = rsqrtf(var + 1e-5f);
  float wv8[8], bv8[8];
  *(float4*)&wv8[0] = *(const float4*)(w + 4 * l);
  *(float4*)&wv8[4] = *(const float4*)(w + 256 + 4 * l);
  *(float4*)&bv8[0] = *(const float4*)(bia + 4 * l);
  *(float4*)&bv8[4] = *(const float4*)(bia + 256 + 4 * l);
  float ln[8];
  #pragma unroll
  for (int i = 0; i < 8; ++i) ln[i] = (v[i] - mu) * rstd * wv8[i] + bv8[i];
  u16x4 o0 = { f2bf(ln[0]), f2bf(ln[1]), f2bf(ln[2]), f2bf(ln[3]) };
  u16x4 o1 = { f2bf(ln[4]), f2bf(ln[5]), f2bf(ln[6]), f2bf(ln[7]) };
  *(u16x4*)(lnout + (size_t)row * C_ + 4 * l) = o0;
  *(u16x4*)(lnout + (size_t)row * C_ + 256 + 4 * l) = o1;
  if (WITH) {
    float ps = pa_s[0], pb = pa_b[0];
    float d[8];
    #pragma unroll
    for (int i = 0; i < 8; ++i) { float r = fmaxf(ln[i], 0.f); d[i] = ps * r * r + pb; }
    float lacc[8], hacc[8];
    #pragma unroll
    for (int h = 0; h < 8; ++h) {
      float lw[8], hw[8];
      *(float4*)&lw[0] = *(const float4*)(lfw + h * C_ + 4 * l);
      *(float4*)&lw[4] = *(const float4*)(lfw + h * C_ + 256 + 4 * l);
      *(float4*)&hw[0] = *(const float4*)(hfw + h * C_ + 4 * l);
      *(float4*)&hw[4] = *(const float4*)(hfw + h * C_ + 256 + 4 * l);
      float la = 0.f, ha = 0.f;
      #pragma unroll
      for (int i = 0; i < 8; ++i) { la += d[i] * lw[i]; ha += d[i] * hw[i]; }
      lacc[h] = la; hacc[h] = ha;
    }
    #pragma unroll
    for (int h = 0; h < 8; ++h)
      #pragma unroll
      for (int off = 1; off < 64; off <<= 1) {
        lacc[h] += __shfl_xor(lacc[h], off);
        hacc[h] += __shfl_xor(hacc[h], off);
      }
    float lv = lacc[0], hv = hacc[0];
    #pragma unroll
    for (int h = 1; h < 8; ++h) { if (l == h) { lv = lacc[h]; hv = hacc[h]; } }
    if (l < 8) {
      lfout[(size_t)row * 8 + l] = tanhf(lv + lfb[l]);
      float z = hv + hfb[l];
      float sp = (z > 15.f) ? z : log1pf(__expf(z));
      float s2 = sp * sp;
      hfout[(size_t)row * 8 + l] = 2.f * s2 / (s2 + 0.3678f);
    }
  }
}

// ---------------- GEMM v2: reg-prefetch staging, padded LDS, fused epilogues ----------
template<int EPI>
__global__ __launch_bounds__(256) void k_gemm(const unsigned short* __restrict__ A,
    const unsigned short* __restrict__ Bt, const float* __restrict__ bias,
    void* __restrict__ outv, unsigned short* __restrict__ vtg, int Nn, int K) {
  __shared__ __align__(16) unsigned short Asm[128 * 40];
  __shared__ __align__(16) unsigned short Bsm[128 * 40];
  const int t = threadIdx.x, w = t >> 6, l = t & 63;
  const int lane15 = l & 15, quad = l >> 4;
  const int n0 = blockIdx.x * 128, m0 = blockIdx.y * 128;
  const int wm = w >> 1, wn = w & 1;
  f32x4 acc[4][4];
  #pragma unroll
  for (int i = 0; i < 4; ++i)
    #pragma unroll
    for (int j = 0; j < 4; ++j) acc[i][j] = (f32x4){0.f, 0.f, 0.f, 0.f};
  const int sr = t >> 2, sc = (t & 3) * 8;
  const unsigned short* Ab = A + (size_t)(m0 + sr) * K + sc;
  const unsigned short* Bb = Bt + (size_t)(n0 + sr) * K + sc;
  const size_t rstep = (size_t)64 * K;
  bf16x8 ga0 = *(const bf16x8*)Ab;
  bf16x8 ga1 = *(const bf16x8*)(Ab + rstep);
  bf16x8 gb0 = *(const bf16x8*)Bb;
  bf16x8 gb1 = *(const bf16x8*)(Bb + rstep);
  for (int k0 = 0; k0 < K; k0 += 32) {
    __syncthreads();
    *(bf16x8*)&Asm[sr * 40 + sc] = ga0;
    *(bf16x8*)&Asm[(sr + 64) * 40 + sc] = ga1;
    *(bf16x8*)&Bsm[sr * 40 + sc] = gb0;
    *(bf16x8*)&Bsm[(sr + 64) * 40 + sc] = gb1;
    __syncthreads();
    if (k0 + 32 < K) {
      ga0 = *(const bf16x8*)(Ab + k0 + 32);
      ga1 = *(const bf16x8*)(Ab + rstep + k0 + 32);
      gb0 = *(const bf16x8*)(Bb + k0 + 32);
      gb1 = *(const bf16x8*)(Bb + rstep + k0 + 32);
    }
    bf16x8 af[4], bg[4];
    #pragma unroll
    for (int i = 0; i < 4; ++i)
      af[i] = *(const bf16x8*)&Asm[(wm * 64 + i * 16 + lane15) * 40 + quad * 8];
    #pragma unroll
    for (int i = 0; i < 4; ++i)
      bg[i] = *(const bf16x8*)&Bsm[(wn * 64 + i * 16 + lane15) * 40 + quad * 8];
    #pragma unroll
    for (int i = 0; i < 4; ++i)
      #pragma unroll
      for (int j = 0; j < 4; ++j)
        acc[i][j] = __builtin_amdgcn_mfma_f32_16x16x32_bf16(af[i], bg[j], acc[i][j], 0, 0, 0);
  }
  #pragma unroll
  for (int i = 0; i < 4; ++i) {
    int grow = m0 + wm * 64 + i * 16 + quad * 4;
    int bq = grow >> 10, nq = grow & 1023;
    #pragma unroll
    for (int j = 0; j < 4; ++j) {
      int gcol = n0 + wn * 64 + j * 16 + lane15;
      float bs = (EPI == 0) ? 0.f : bias[gcol];
      if (EPI == 1 || EPI == 3) {
        float4 o = make_float4(acc[i][j][0] + bs, acc[i][j][1] + bs,
                               acc[i][j][2] + bs, acc[i][j][3] + bs);
        *(float4*)&((float*)outv)[((size_t)(bq * C_ + gcol) << 10) + nq] = o;
      } else if (EPI == 0) {
        u16x4 pv;
        #pragma unroll
        for (int r = 0; r < 4; ++r) {
          unsigned short hv = f2bf(acc[i][j][r]);
          pv[r] = hv;
          ((unsigned short*)outv)[(size_t)(grow + r) * Nn + gcol] = hv;
        }
        if (gcol >= 1024)
          *(u16x4*)&vtg[((size_t)(bq * C_ + gcol - 1024) << 10) + nq] = pv;
      } else {
        #pragma unroll
        for (int r = 0; r < 4; ++r) {
          float vv = acc[i][j][r] + bs;
          float e = __builtin_amdgcn_exp2f(-(2.302118073f * vv +
                                             0.1029455568f * vv * vv * vv));
          float g = vv * __builtin_amdgcn_rcpf(1.f + e);
          ((unsigned short*)outv)[(size_t)(grow + r) * Nn + gcol] = f2bf(g);
        }
      }
    }
  }
}

// ---------------- flash attention v4: 128-row Q tiles, no-max softmax, fused gates ----
// Each block: 128 q rows (2 groups of 64), 4 waves; wave w owns q columns
// {q0+qg*64+w*16+lane15}. K/V staged once per block -> 2x HBM reuse and
// 32 MFMA per wave per staged tile (vs 16 in v3).
__global__ __launch_bounds__(256) void k_flash(const unsigned short* __restrict__ qkv,
    const unsigned short* __restrict__ vtg, const float* __restrict__ lf,
    const float* __restrict__ hf, const float* __restrict__ lgam,
    const float* __restrict__ hgam, unsigned short* __restrict__ y) {
  const int t = threadIdx.x, w = t >> 6, l = t & 63;
  const int lane15 = l & 15, quad = l >> 4;
  const int q0 = blockIdx.x * 128;
  const int h = blockIdx.y, b = blockIdx.z;
  __shared__ __align__(16) unsigned short kt[64 * 72];
  __shared__ __align__(16) unsigned short vt[64 * 72];
  __shared__ __align__(16) unsigned short pl[4][2][16 * 72];

  // Q fragments for both 64-row groups, pre-scaled by 0.125*log2(e)
  bf16x8 aq[2][2];
  #pragma unroll
  for (int qg = 0; qg < 2; ++qg) {
    const unsigned short* qp = qkv + (size_t)(b * N_ + q0 + qg * 64 + w * 16 + lane15) * C3_ + h * 64 + quad * 8;
    bf16x8 r0 = *(const bf16x8*)qp;
    bf16x8 r1 = *(const bf16x8*)(qp + 32);
    #pragma unroll
    for (int i = 0; i < 8; ++i) {
      aq[qg][0][i] = (short)f2bf(0.1803368801111713f * bf2f((unsigned short)r0[i]));
      aq[qg][1][i] = (short)f2bf(0.1803368801111713f * bf2f((unsigned short)r1[i]));
    }
  }
  f32x4 O[2][4];
  #pragma unroll
  for (int qg = 0; qg < 2; ++qg)
    #pragma unroll
    for (int i = 0; i < 4; ++i) O[qg][i] = (f32x4){0.f, 0.f, 0.f, 0.f};
  float lsum[2] = {0.f, 0.f};

  const int sr = t >> 3;
  const int sc = (t & 7) * 8;
  const unsigned short* kb = qkv + (size_t)(b * N_ + sr) * C3_ + 512 + h * 64 + sc;
  const unsigned short* vb = vtg + (size_t)((b * NH_ + h) * HD_ + sr) * N_ + sc;
  bf16x8 gk0 = *(const bf16x8*)kb;
  bf16x8 gk1 = *(const bf16x8*)(kb + (size_t)32 * C3_);
  bf16x8 gv0 = *(const bf16x8*)vb;
  bf16x8 gv1 = *(const bf16x8*)(vb + 32 * N_);

  for (int kti = 0; kti < 16; ++kti) {
    __syncthreads();
    *(bf16x8*)&kt[sr * 72 + sc] = gk0;
    *(bf16x8*)&kt[(sr + 32) * 72 + sc] = gk1;
    *(bf16x8*)&vt[sr * 72 + sc] = gv0;
    *(bf16x8*)&vt[(sr + 32) * 72 + sc] = gv1;
    __syncthreads();
    if (kti < 15) {
      const unsigned short* kn = kb + (size_t)((kti + 1) * 64) * C3_;
      const unsigned short* vn = vb + (kti + 1) * 64;
      gk0 = *(const bf16x8*)kn;
      gk1 = *(const bf16x8*)(kn + (size_t)32 * C3_);
      gv0 = *(const bf16x8*)vn;
      gv1 = *(const bf16x8*)(vn + 32 * N_);
    }

    #pragma unroll
    for (int qg = 0; qg < 2; ++qg) {
      // S^T: D[n-local][q]
      f32x4 S[4];
      #pragma unroll
      for (int nt = 0; nt < 4; ++nt) {
        bf16x8 ak0 = *(const bf16x8*)&kt[(nt * 16 + lane15) * 72 + quad * 8];
        bf16x8 ak1 = *(const bf16x8*)&kt[(nt * 16 + lane15) * 72 + 32 + quad * 8];
        f32x4 z = (f32x4){0.f, 0.f, 0.f, 0.f};
        z = __builtin_amdgcn_mfma_f32_16x16x32_bf16(ak0, aq[qg][0], z, 0, 0, 0);
        z = __builtin_amdgcn_mfma_f32_16x16x32_bf16(ak1, aq[qg][1], z, 0, 0, 0);
        S[nt] = z;
      }
      float ls = 0.f;
      #pragma unroll
      for (int nt = 0; nt < 4; ++nt)
        #pragma unroll
        for (int r = 0; r < 4; ++r) {
          float pv = __builtin_amdgcn_exp2f(S[nt][r]);
          S[nt][r] = pv;
          ls += pv;
        }
      lsum[qg] += ls;
      #pragma unroll
      for (int nt = 0; nt < 4; ++nt) {
        unsigned lo = __builtin_amdgcn_perm(f2u(S[nt][1]), f2u(S[nt][0]), 0x07060302u);
        unsigned hi = __builtin_amdgcn_perm(f2u(S[nt][3]), f2u(S[nt][2]), 0x07060302u);
        uint2 pk = make_uint2(lo, hi);
        *(uint2*)&pl[w][qg][lane15 * 72 + nt * 16 + quad * 4] = pk;
      }
      #pragma unroll
      for (int nc = 0; nc < 2; ++nc) {
        bf16x8 ap = *(const bf16x8*)&pl[w][qg][lane15 * 72 + nc * 32 + quad * 8];
        #pragma unroll
        for (int dt = 0; dt < 4; ++dt) {
          bf16x8 bv = *(const bf16x8*)&vt[(dt * 16 + lane15) * 72 + nc * 32 + quad * 8];
          O[qg][dt] = __builtin_amdgcn_mfma_f32_16x16x32_bf16(ap, bv, O[qg][dt], 0, 0, 0);
        }
      }
    }
  }

  #pragma unroll
  for (int qg = 0; qg < 2; ++qg) {
    float ls = lsum[qg];
    ls += __shfl_xor(ls, 16);
    ls += __shfl_xor(ls, 32);
    float inv = 1.f / ls;
    float invr[4], lfr[4], hfr[4];
    #pragma unroll
    for (int r = 0; r < 4; ++r) {
      invr[r] = __shfl(inv, quad * 4 + r);
      int grow = b * N_ + q0 + qg * 64 + w * 16 + quad * 4 + r;
      lfr[r] = lf[grow * 8 + h];
      hfr[r] = hf[grow * 8 + h];
    }
    const size_t rowb = (size_t)(b * N_ + q0 + qg * 64 + w * 16 + quad * 4);
    #pragma unroll
    for (int dt = 0; dt < 4; ++dt) {
      int cc = h * 64 + dt * 16 + lane15;
      float lg = lgam[cc], hg = hgam[cc];
      #pragma unroll
      for (int r = 0; r < 4; ++r) {
        float a = O[qg][dt][r] * invr[r];
        float vval = bf2f(qkv[(rowb + r) * C3_ + 1024 + cc]);
        float res = a + a * lfr[r] * lg + hfr[r] * (vval - a) * hg;
        y[(rowb + r) * C_ + cc] = f2bf(res);
      }
    }
  }
}

// ---------------- spatial mean pool per (b,c) row ----------------
__global__ __launch_bounds__(256) void k_pool(const float* __restrict__ feat,
                                              float* __restrict__ pooled) {
  int row = blockIdx.x * 4 + (threadIdx.x >> 6);
  int l = threadIdx.x & 63;
  const float4* p = (const float4*)(feat + (size_t)row * N_);
  float4 a = p[l], b4 = p[l + 64], c4 = p[l + 128], d4 = p[l + 192];
  float s = a.x + a.y + a.z + a.w + b4.x + b4.y + b4.z + b4.w +
            c4.x + c4.y + c4.z + c4.w + d4.x + d4.y + d4.z + d4.w;
  #pragma unroll
  for (int off = 1; off < 64; off <<= 1) s += __shfl_xor(s, off);
  if (l == 0) pooled[row] = s * (1.f / 1024.f);
}

// ---------------- routing: pooled(B,C) -> routing(B,64) ----------------
__global__ __launch_bounds__(256) void k_routing(const float* __restrict__ pooled,
    const float* __restrict__ rw1, const float* __restrict__ rw1s,
    const float* __restrict__ rw1b, const float* __restrict__ rw2,
    float* __restrict__ routing) {
  const int b = blockIdx.x, t = threadIdx.x;
  __shared__ float plds[512];
  __shared__ float tile[64][65];
  __shared__ float hl[64];
  plds[t] = pooled[b * 512 + t];
  plds[t + 256] = pooled[b * 512 + t + 256];
  __syncthreads();
  float acc = 0.f;
  for (int c0 = 0; c0 < 512; c0 += 64) {
    #pragma unroll
    for (int kk = 0; kk < 16; ++kk) {
      int idx = kk * 256 + t;
      tile[idx >> 6][idx & 63] = rw1[(size_t)(idx >> 6) * 512 + c0 + (idx & 63)];
    }
    __syncthreads();
    if (t < 64) {
      #pragma unroll
      for (int i = 0; i < 64; ++i) acc += plds[c0 + i] * tile[t][i];
    }
    __syncthreads();
  }
  if (t < 64) {
    float r = fmaxf(acc, 0.f);
    hl[t] = rw1s[0] * r * r + rw1b[0];
  }
  __syncthreads();
  if (t < 64) {
    float r2 = 0.f;
    #pragma unroll
    for (int j = 0; j < 64; ++j) r2 += hl[j] * rw2[(size_t)t * 64 + j];
    routing[b * 64 + t] = tanhf(r2);
  }
}

// ---------------- per-plane 32x32 rfft2 * dyn -> irfft2 via MFMA ----------------
__global__ __launch_bounds__(256) void k_freq(const float* __restrict__ feat,
    const float* __restrict__ routing, const float* __restrict__ fwtab,
    const unsigned short* __restrict__ gtab, float* __restrict__ enh) {
  const int c = blockIdx.x, b = blockIdx.y, t = threadIdx.x;
  const int g = c >> 5, cc = c & 31;
  const int w = t >> 6, l = t & 63;
  const int lane15 = l & 15, quad = l >> 4;
  const int mt = w & 1, nt = w >> 1;
  __shared__ __align__(16) unsigned short Xbf[32 * 40];
  __shared__ __align__(16) float p[32 * 36];
  __shared__ __align__(16) unsigned short Tabs[6400];
  __shared__ __align__(16) unsigned short pl1r[32 * 40], pl1i[32 * 40];
  __shared__ __align__(16) unsigned short pl2r[32 * 40], pl2i[32 * 40];
  __shared__ __align__(16) unsigned short pl3r[32 * 40], pl3i[32 * 40];
  __shared__ float Ms[1024];
  const size_t base = (size_t)(b * C_ + c) * N_;

  {
    float4 v = ((const float4*)(feat + base))[t];
    int hh = t >> 3, w4 = (t & 7) * 4;
    *(float4*)&p[hh * 36 + w4] = v;
    u16x4 xb = { f2bf(v.x), f2bf(v.y), f2bf(v.z), f2bf(v.w) };
    *(u16x4*)&Xbf[hh * 40 + w4] = xb;
  }
  {
    const uint4* src = (const uint4*)gtab;
    uint4* dst = (uint4*)Tabs;
    #pragma unroll
    for (int k = 0; k < 4; ++k) {
      int o = k * 256 + t;
      if (o < 800) dst[o] = src[o];
    }
  }
  {
    float r0 = routing[b * 64 + g * 4 + 0];
    float r1 = routing[b * 64 + g * 4 + 1];
    float r2 = routing[b * 64 + g * 4 + 2];
    float r3 = routing[b * 64 + g * 4 + 3];
    const float* fb = fwtab + (size_t)cc * 544;
    #pragma unroll
    for (int k = 0; k < 4; ++k) {
      int o = k * 256 + t;
      int fh = o >> 5, fw = o & 31;
      float mv = 0.f;
      if (fw < 17) {
        int fi = fh * 17 + fw;
        mv = (r0 * fb[fi] + r1 * fb[17408 + fi] + r2 * fb[34816 + fi] +
              r3 * fb[52224 + fi]) * (1.f / 1024.f);
      }
      Ms[o] = mv;
    }
  }
  __syncthreads();

  const unsigned short* Tc  = Tabs;
  const unsigned short* Ts  = Tabs + 1280;
  const unsigned short* Tsn = Tabs + 2560;
  const unsigned short* Tcw = Tabs + 3840;
  const unsigned short* Tsw = Tabs + 5120;
  const int arow = (mt * 16 + lane15) * 40 + quad * 8;
  const int brow = (nt * 16 + lane15) * 40 + quad * 8;
  const int prow = (nt * 16 + lane15) * 40 + mt * 16 + quad * 4;
  const f32x4 zz = (f32x4){0.f, 0.f, 0.f, 0.f};

  {
    bf16x8 aX = *(const bf16x8*)&Xbf[arow];
    bf16x8 bC = *(const bf16x8*)&Tc[brow];
    bf16x8 bS = *(const bf16x8*)&Tsn[brow];
    f32x4 re = __builtin_amdgcn_mfma_f32_16x16x32_bf16(aX, bC, zz, 0, 0, 0);
    f32x4 im = __builtin_amdgcn_mfma_f32_16x16x32_bf16(aX, bS, zz, 0, 0, 0);
    uint2 pr = make_uint2(__builtin_amdgcn_perm(f2u(re[1]), f2u(re[0]), 0x07060302u),
                          __builtin_amdgcn_perm(f2u(re[3]), f2u(re[2]), 0x07060302u));
    uint2 pi = make_uint2(__builtin_amdgcn_perm(f2u(im[1]), f2u(im[0]), 0x07060302u),
                          __builtin_amdgcn_perm(f2u(im[3]), f2u(im[2]), 0x07060302u));
    *(uint2*)&pl1r[prow] = pr;
    *(uint2*)&pl1i[prow] = pi;
  }
  __syncthreads();
  {
    bf16x8 aC = *(const bf16x8*)&Tc[arow];
    bf16x8 aS = *(const bf16x8*)&Ts[arow];
    bf16x8 aN = *(const bf16x8*)&Tsn[arow];
    bf16x8 bR = *(const bf16x8*)&pl1r[brow];
    bf16x8 bI = *(const bf16x8*)&pl1i[brow];
    f32x4 er = __builtin_amdgcn_mfma_f32_16x16x32_bf16(aC, bR, zz, 0, 0, 0);
    er = __builtin_amdgcn_mfma_f32_16x16x32_bf16(aS, bI, er, 0, 0, 0);
    f32x4 ei = __builtin_amdgcn_mfma_f32_16x16x32_bf16(aC, bI, zz, 0, 0, 0);
    ei = __builtin_amdgcn_mfma_f32_16x16x32_bf16(aN, bR, ei, 0, 0, 0);
    #pragma unroll
    for (int r = 0; r < 4; ++r) {
      float mk = Ms[(mt * 16 + quad * 4 + r) * 32 + nt * 16 + lane15];
      er[r] *= mk; ei[r] *= mk;
    }
    uint2 pr = make_uint2(__builtin_amdgcn_perm(f2u(er[1]), f2u(er[0]), 0x07060302u),
                          __builtin_amdgcn_perm(f2u(er[3]), f2u(er[2]), 0x07060302u));
    uint2 pi = make_uint2(__builtin_amdgcn_perm(f2u(ei[1]), f2u(ei[0]), 0x07060302u),
                          __builtin_amdgcn_perm(f2u(ei[3]), f2u(ei[2]), 0x07060302u));
    *(uint2*)&pl2r[prow] = pr;
    *(uint2*)&pl2i[prow] = pi;
  }
  __syncthreads();
  {
    bf16x8 aR = *(const bf16x8*)&pl2r[arow];
    bf16x8 aI = *(const bf16x8*)&pl2i[arow];
    bf16x8 bC = *(const bf16x8*)&Tc[brow];
    bf16x8 bS = *(const bf16x8*)&Ts[brow];
    bf16x8 bN = *(const bf16x8*)&Tsn[brow];
    f32x4 zr = __builtin_amdgcn_mfma_f32_16x16x32_bf16(aR, bC, zz, 0, 0, 0);
    zr = __builtin_amdgcn_mfma_f32_16x16x32_bf16(aI, bN, zr, 0, 0, 0);
    f32x4 zi = __builtin_amdgcn_mfma_f32_16x16x32_bf16(aI, bC, zz, 0, 0, 0);
    zi = __builtin_amdgcn_mfma_f32_16x16x32_bf16(aR, bS, zi, 0, 0, 0);
    uint2 pr = make_uint2(__builtin_amdgcn_perm(f2u(zr[1]), f2u(zr[0]), 0x07060302u),
                          __builtin_amdgcn_perm(f2u(zr[3]), f2u(zr[2]), 0x07060302u));
    uint2 pi = make_uint2(__builtin_amdgcn_perm(f2u(zi[1]), f2u(zi[0]), 0x07060302u),
                          __builtin_amdgcn_perm(f2u(zi[3]), f2u(zi[2]), 0x07060302u));
    *(uint2*)&pl3r[prow] = pr;
    *(uint2*)&pl3i[prow] = pi;
  }
  __syncthreads();
  {
    bf16x8 aC = *(const bf16x8*)&Tcw[arow];
    bf16x8 aS = *(const bf16x8*)&Tsw[arow];
    bf16x8 bR = *(const bf16x8*)&pl3r[brow];
    bf16x8 bI = *(const bf16x8*)&pl3i[brow];
    f32x4 y = __builtin_amdgcn_mfma_f32_16x16x32_bf16(aC, bR, zz, 0, 0, 0);
    y = __builtin_amdgcn_mfma_f32_16x16x32_bf16(aS, bI, y, 0, 0, 0);
    int hh = nt * 16 + lane15, w0 = mt * 16 + quad * 4;
    float4 res = *(const float4*)&p[hh * 36 + w0];
    float4 o = make_float4(y[0] + res.x, y[1] + res.y, y[2] + res.z, y[3] + res.w);
    *(float4*)&enh[base + hh * 32 + w0] = o;
  }
}

// ---------------- tokens += gamma * enh^T ----------------
__global__ __launch_bounds__(256) void k_add_t(const float* __restrict__ enh,
    const float* __restrict__ gamma, float* __restrict__ tok) {
  __shared__ float s[32][33];
  const int n0 = blockIdx.x * 32, c0 = blockIdx.y * 32, b = blockIdx.z;
  const int j = threadIdx.x & 31, i0 = threadIdx.x >> 5;
  #pragma unroll
  for (int k = 0; k < 4; ++k) {
    int i = i0 + k * 8;
    s[i][j] = enh[(size_t)(b * C_ + c0 + i) * N_ + n0 + j];
  }
  __syncthreads();
  float gv = gamma[c0 + j];
  #pragma unroll
  for (int k = 0; k < 4; ++k) {
    int i = i0 + k * 8;
    size_t o = (size_t)(b * N_ + n0 + i) * C_ + c0 + j;
    tok[o] += gv * s[j][i];
  }
}

// ---------------- final: out = tokens^T + gamma2 * enh ----------------
__global__ __launch_bounds__(256) void k_final(const float* __restrict__ tok,
    const float* __restrict__ gamma, const float* __restrict__ enh,
    float* __restrict__ out) {
  __shared__ float s[32][33];
  const int n0 = blockIdx.x * 32, c0 = blockIdx.y * 32, b = blockIdx.z;
  const int j = threadIdx.x & 31, i0 = threadIdx.x >> 5;
  #pragma unroll
  for (int k = 0; k < 4; ++k) {
    int i = i0 + k * 8;
    s[i][j] = tok[(size_t)(b * N_ + n0 + i) * C_ + c0 + j];
  }
  __syncthreads();
  #pragma unroll
  for (int k = 0; k < 4; ++k) {
    int i = i0 + k * 8;   // c-local
    size_t o = (size_t)(b * C_ + c0 + i) * N_ + n0 + j;
    out[o] = s[j][i] + gamma[c0 + i] * enh[o];
  }
}

// =============================== launch ===============================
extern "C" void kernel_launch(void* const* d_in, const int* in_sizes, int n_in,
                              void* d_out, int out_size, void* d_ws, size_t ws_size,
                              hipStream_t stream) {
  (void)in_sizes; (void)n_in; (void)out_size; (void)ws_size;
  const float* x      = (const float*)d_in[0];
  const float* n1w    = (const float*)d_in[1];
  const float* n1b    = (const float*)d_in[2];
  const float* qkv_w  = (const float*)d_in[3];
  const float* proj_w = (const float*)d_in[4];
  const float* proj_b = (const float*)d_in[5];
  const float* pa_s   = (const float*)d_in[6];
  const float* pa_b   = (const float*)d_in[7];
  const float* lf_w   = (const float*)d_in[8];
  const float* lf_b   = (const float*)d_in[9];
  const float* hf_w   = (const float*)d_in[10];
  const float* hf_b   = (const float*)d_in[11];
  const float* lf_g   = (const float*)d_in[12];
  const float* hf_g   = (const float*)d_in[13];
  const float* f1rw1w = (const float*)d_in[14];
  const float* f1rw1s = (const float*)d_in[15];
  const float* f1rw1b = (const float*)d_in[16];
  const float* f1rw2w = (const float*)d_in[17];
  const float* f1fw   = (const float*)d_in[18];
  const float* gamma1 = (const float*)d_in[19];
  const float* n2w    = (const float*)d_in[20];
  const float* n2b    = (const float*)d_in[21];
  const float* fc1w   = (const float*)d_in[22];
  const float* fc1b   = (const float*)d_in[23];
  const float* fc2w   = (const float*)d_in[24];
  const float* fc2b   = (const float*)d_in[25];
  const float* f2rw1w = (const float*)d_in[26];
  const float* f2rw1s = (const float*)d_in[27];
  const float* f2rw1b = (const float*)d_in[28];
  const float* f2rw2w = (const float*)d_in[29];
  const float* f2fw   = (const float*)d_in[30];
  const float* gamma2 = (const float*)d_in[31];

  char* ws = (char*)d_ws;
  float*          tokens = (float*)(ws + 0);
  float*          f1buf  = (float*)(ws + 33554432ULL);
  float*          f2buf  = (float*)(ws + 67108864ULL);
  float*          f3buf  = (float*)(ws + 100663296ULL);
  unsigned short* regA   = (unsigned short*)(ws + 134217728ULL);
  unsigned short* abuf   = (unsigned short*)(ws + 201326592ULL);
  float*          lfbuf  = (float*)(ws + 218103808ULL);
  float*          hfbuf  = (float*)(ws + 218628096ULL);
  float*          pooled = (float*)(ws + 219152384ULL);
  float*          routing= (float*)(ws + 219185152ULL);
  unsigned short* wq     = (unsigned short*)(ws + 219189248ULL);
  unsigned short* wp     = (unsigned short*)(ws + 220762112ULL);
  unsigned short* w1     = (unsigned short*)(ws + 221286400ULL);
  unsigned short* w2     = (unsigned short*)(ws + 223383552ULL);
  unsigned short* gtab   = (unsigned short*)(ws + 225480704ULL);
  unsigned short* vtg    = (unsigned short*)f1buf;   // 32 MB region reused for V^T

  // weights -> bf16, twiddle tables
  k_f2b<<<3072, 256, 0, stream>>>(qkv_w, wq, 786432);
  k_f2b<<<1024, 256, 0, stream>>>(proj_w, wp, 262144);
  k_f2b<<<4096, 256, 0, stream>>>(fc1w, w1, 1048576);
  k_f2b<<<4096, 256, 0, stream>>>(fc2w, w2, 1048576);
  k_twid<<<25, 256, 0, stream>>>(gtab);

  k_transpose_cn<<<dim3(32, 16, 16), 256, 0, stream>>>(x, tokens);
  k_ln<true><<<4096, 256, 0, stream>>>(tokens, n1w, n1b, lf_w, lf_b, hf_w, hf_b,
                                       pa_s, pa_b, abuf, lfbuf, hfbuf);
  k_gemm<0><<<dim3(12, 128), 256, 0, stream>>>(abuf, wq, n1b, regA, vtg, C3_, C_);
  // flash v4 (128-q tiles) + fused gates -> abuf bf16
  k_flash<<<dim3(8, 8, 16), 256, 0, stream>>>(regA, vtg, lfbuf, hfbuf, lf_g, hf_g, abuf);
  k_gemm<1><<<dim3(4, 128), 256, 0, stream>>>(abuf, wp, proj_b, f2buf, nullptr, C_, C_);
  k_pool<<<2048, 256, 0, stream>>>(f2buf, pooled);
  k_routing<<<16, 256, 0, stream>>>(pooled, f1rw1w, f1rw1s, f1rw1b, f1rw2w, routing);
  k_freq<<<dim3(512, 16), 256, 0, stream>>>(f2buf, routing, f1fw, gtab, f3buf);
  k_add_t<<<dim3(32, 16, 16), 256, 0, stream>>>(f3buf, gamma1, tokens);
  k_ln<false><<<4096, 256, 0, stream>>>(tokens, n2w, n2b, nullptr, nullptr, nullptr,
                                        nullptr, nullptr, nullptr, abuf, nullptr, nullptr);
  k_gemm<2><<<dim3(16, 128), 256, 0, stream>>>(abuf, w1, fc1b, regA, nullptr, CH_, C_);
  k_gemm<3><<<dim3(4, 128), 256, 0, stream>>>(regA, w2, fc2b, f2buf, nullptr, C_, CH_);
  k_pool<<<2048, 256, 0, stream>>>(f2buf, pooled);
  k_routing<<<16, 256, 0, stream>>>(pooled, f2rw1w, f2rw1s, f2rw1b, f2rw2w, routing);
  k_freq<<<dim3(512, 16), 256, 0, stream>>>(f2buf, routing, f2fw, gtab, f3buf);
  k_final<<<dim3(32, 16, 16), 256, 0, stream>>>(tokens, gamma2, f3buf, (float*)d_out);
}

// Round 7
// 548.862 us; speedup vs baseline: 1.5961x; 1.0112x over previous
//
#include <hip/hip_runtime.h>
#include <cstdint>
#include <cstddef>

#define B_   16
#define C_   512
#define N_   1024
#define M_   (B_*N_)
#define NH_  8
#define HD_  64
#define C3_  1536
#define CH_  2048

typedef __attribute__((ext_vector_type(8))) short bf16x8;
typedef __attribute__((ext_vector_type(4))) float f32x4;
typedef __attribute__((ext_vector_type(4))) unsigned short u16x4;

__device__ __forceinline__ unsigned short f2bf(float f) {
  union { float f; unsigned u; } v; v.f = f;
  unsigned r = v.u + 0x7fffu + ((v.u >> 16) & 1u);
  return (unsigned short)(r >> 16);
}
__device__ __forceinline__ float bf2f(unsigned short h) {
  union { unsigned u; float f; } v; v.u = ((unsigned)h) << 16;
  return v.f;
}
__device__ __forceinline__ unsigned f2u(float f) {
  union { float f; unsigned u; } v; v.f = f; return v.u;
}

// ---------------- fused float -> bf16 conversion for all 4 weight mats ----------------
__global__ __launch_bounds__(256) void k_f2b4(
    const float* __restrict__ s0, unsigned short* __restrict__ d0,
    const float* __restrict__ s1, unsigned short* __restrict__ d1,
    const float* __restrict__ s2, unsigned short* __restrict__ d2,
    const float* __restrict__ s3, unsigned short* __restrict__ d3) {
  int blk = blockIdx.x, t = threadIdx.x;
  const float* s; unsigned short* d; int off;
  if (blk < 3072)      { s = s0; d = d0; off = blk * 256; }
  else if (blk < 4096) { s = s1; d = d1; off = (blk - 3072) * 256; }
  else if (blk < 8192) { s = s2; d = d2; off = (blk - 4096) * 256; }
  else                 { s = s3; d = d3; off = (blk - 8192) * 256; }
  int i = off + t;
  d[i] = f2bf(s[i]);
}

// ---------------- twiddle tables (bf16, stride 40), 5 tables of 32x40 ----------------
__global__ __launch_bounds__(256) void k_twid(unsigned short* __restrict__ gtab) {
  int idx = blockIdx.x * 256 + threadIdx.x;
  if (idx >= 6400) return;
  int tab = idx / 1280, rem = idx % 1280;
  int i = rem / 40, j = rem % 40;
  float v = 0.f;
  if (j < 32) {
    float th = 0.19634954084936207f * (float)((i * j) & 31);
    float s, c;
    __sincosf(th, &s, &c);
    if (tab == 0) v = c;
    else if (tab == 1) v = s;
    else if (tab == 2) v = -s;
    else {
      float wg = (j == 0 || j == 16) ? 1.f : 2.f;
      if (j >= 17) wg = 0.f;
      v = (tab == 3) ? wg * c : -wg * s;
    }
  }
  gtab[idx] = f2bf(v);
}

// ---------------- transpose (B,C,N) f32 -> (B,N,C) f32 ----------------
__global__ __launch_bounds__(256) void k_transpose_cn(const float* __restrict__ x,
                                                      float* __restrict__ tok) {
  __shared__ float s[32][33];
  const int n0 = blockIdx.x * 32, c0 = blockIdx.y * 32, b = blockIdx.z;
  const int j = threadIdx.x & 31, i0 = threadIdx.x >> 5;
  #pragma unroll
  for (int k = 0; k < 4; ++k) {
    int i = i0 + k * 8;
    s[i][j] = x[(size_t)(b * C_ + c0 + i) * N_ + n0 + j];
  }
  __syncthreads();
  #pragma unroll
  for (int k = 0; k < 4; ++k) {
    int i = i0 + k * 8;
    tok[(size_t)(b * N_ + n0 + i) * C_ + c0 + j] = s[j][i];
  }
}

// ---------------- LayerNorm (+ optional lf/hf head gates) ----------------
template<bool WITH>
__global__ __launch_bounds__(256) void k_ln(const float* __restrict__ tok,
    const float* __restrict__ w, const float* __restrict__ bia,
    const float* __restrict__ lfw, const float* __restrict__ lfb,
    const float* __restrict__ hfw, const float* __restrict__ hfb,
    const float* __restrict__ pa_s, const float* __restrict__ pa_b,
    unsigned short* __restrict__ lnout, float* __restrict__ lfout,
    float* __restrict__ hfout) {
  const int t = threadIdx.x, wv = t >> 6, l = t & 63;
  const int row = blockIdx.x * 4 + wv;
  const float* p = tok + (size_t)row * C_;
  float v[8];
  *(float4*)&v[0] = *(const float4*)(p + 4 * l);
  *(float4*)&v[4] = *(const float4*)(p + 256 + 4 * l);
  float s = 0.f, q = 0.f;
  #pragma unroll
  for (int i = 0; i < 8; ++i) { s += v[i]; q += v[i] * v[i]; }
  #pragma unroll
  for (int off = 1; off < 64; off <<= 1) { s += __shfl_xor(s, off); q += __shfl_xor(q, off); }
  float mu = s * (1.f / 512.f);
  float var = q * (1.f / 512.f) - mu * mu;
  float rstd = rsqrtf(var + 1e-5f);
  float wv8[8], bv8[8];
  *(float4*)&wv8[0] = *(const float4*)(w + 4 * l);
  *(float4*)&wv8[4] = *(const float4*)(w + 256 + 4 * l);
  *(float4*)&bv8[0] = *(const float4*)(bia + 4 * l);
  *(float4*)&bv8[4] = *(const float4*)(bia + 256 + 4 * l);
  float ln[8];
  #pragma unroll
  for (int i = 0; i < 8; ++i) ln[i] = (v[i] - mu) * rstd * wv8[i] + bv8[i];
  u16x4 o0 = { f2bf(ln[0]), f2bf(ln[1]), f2bf(ln[2]), f2bf(ln[3]) };
  u16x4 o1 = { f2bf(ln[4]), f2bf(ln[5]), f2bf(ln[6]), f2bf(ln[7]) };
  *(u16x4*)(lnout + (size_t)row * C_ + 4 * l) = o0;
  *(u16x4*)(lnout + (size_t)row * C_ + 256 + 4 * l) = o1;
  if (WITH) {
    float ps = pa_s[0], pb = pa_b[0];
    float d[8];
    #pragma unroll
    for (int i = 0; i < 8; ++i) { float r = fmaxf(ln[i], 0.f); d[i] = ps * r * r + pb; }
    float lacc[8], hacc[8];
    #pragma unroll
    for (int h = 0; h < 8; ++h) {
      float lw[8], hw[8];
      *(float4*)&lw[0] = *(const float4*)(lfw + h * C_ + 4 * l);
      *(float4*)&lw[4] = *(const float4*)(lfw + h * C_ + 256 + 4 * l);
      *(float4*)&hw[0] = *(const float4*)(hfw + h * C_ + 4 * l);
      *(float4*)&hw[4] = *(const float4*)(hfw + h * C_ + 256 + 4 * l);
      float la = 0.f, ha = 0.f;
      #pragma unroll
      for (int i = 0; i < 8; ++i) { la += d[i] * lw[i]; ha += d[i] * hw[i]; }
      lacc[h] = la; hacc[h] = ha;
    }
    #pragma unroll
    for (int h = 0; h < 8; ++h)
      #pragma unroll
      for (int off = 1; off < 64; off <<= 1) {
        lacc[h] += __shfl_xor(lacc[h], off);
        hacc[h] += __shfl_xor(hacc[h], off);
      }
    float lv = lacc[0], hv = hacc[0];
    #pragma unroll
    for (int h = 1; h < 8; ++h) { if (l == h) { lv = lacc[h]; hv = hacc[h]; } }
    if (l < 8) {
      lfout[(size_t)row * 8 + l] = tanhf(lv + lfb[l]);
      float z = hv + hfb[l];
      float sp = (z > 15.f) ? z : log1pf(__expf(z));
      float s2 = sp * sp;
      hfout[(size_t)row * 8 + l] = 2.f * s2 / (s2 + 0.3678f);
    }
  }
}

// ---------------- GEMM v2: reg-prefetch staging, padded LDS, fused epilogues ----------
template<int EPI>
__global__ __launch_bounds__(256) void k_gemm(const unsigned short* __restrict__ A,
    const unsigned short* __restrict__ Bt, const float* __restrict__ bias,
    void* __restrict__ outv, unsigned short* __restrict__ vtg, int Nn, int K) {
  __shared__ __align__(16) unsigned short Asm[128 * 40];
  __shared__ __align__(16) unsigned short Bsm[128 * 40];
  const int t = threadIdx.x, w = t >> 6, l = t & 63;
  const int lane15 = l & 15, quad = l >> 4;
  const int n0 = blockIdx.x * 128, m0 = blockIdx.y * 128;
  const int wm = w >> 1, wn = w & 1;
  f32x4 acc[4][4];
  #pragma unroll
  for (int i = 0; i < 4; ++i)
    #pragma unroll
    for (int j = 0; j < 4; ++j) acc[i][j] = (f32x4){0.f, 0.f, 0.f, 0.f};
  const int sr = t >> 2, sc = (t & 3) * 8;
  const unsigned short* Ab = A + (size_t)(m0 + sr) * K + sc;
  const unsigned short* Bb = Bt + (size_t)(n0 + sr) * K + sc;
  const size_t rstep = (size_t)64 * K;
  bf16x8 ga0 = *(const bf16x8*)Ab;
  bf16x8 ga1 = *(const bf16x8*)(Ab + rstep);
  bf16x8 gb0 = *(const bf16x8*)Bb;
  bf16x8 gb1 = *(const bf16x8*)(Bb + rstep);
  for (int k0 = 0; k0 < K; k0 += 32) {
    __syncthreads();
    *(bf16x8*)&Asm[sr * 40 + sc] = ga0;
    *(bf16x8*)&Asm[(sr + 64) * 40 + sc] = ga1;
    *(bf16x8*)&Bsm[sr * 40 + sc] = gb0;
    *(bf16x8*)&Bsm[(sr + 64) * 40 + sc] = gb1;
    __syncthreads();
    if (k0 + 32 < K) {
      ga0 = *(const bf16x8*)(Ab + k0 + 32);
      ga1 = *(const bf16x8*)(Ab + rstep + k0 + 32);
      gb0 = *(const bf16x8*)(Bb + k0 + 32);
      gb1 = *(const bf16x8*)(Bb + rstep + k0 + 32);
    }
    bf16x8 af[4], bg[4];
    #pragma unroll
    for (int i = 0; i < 4; ++i)
      af[i] = *(const bf16x8*)&Asm[(wm * 64 + i * 16 + lane15) * 40 + quad * 8];
    #pragma unroll
    for (int i = 0; i < 4; ++i)
      bg[i] = *(const bf16x8*)&Bsm[(wn * 64 + i * 16 + lane15) * 40 + quad * 8];
    #pragma unroll
    for (int i = 0; i < 4; ++i)
      #pragma unroll
      for (int j = 0; j < 4; ++j)
        acc[i][j] = __builtin_amdgcn_mfma_f32_16x16x32_bf16(af[i], bg[j], acc[i][j], 0, 0, 0);
  }
  #pragma unroll
  for (int i = 0; i < 4; ++i) {
    int grow = m0 + wm * 64 + i * 16 + quad * 4;
    int bq = grow >> 10, nq = grow & 1023;
    #pragma unroll
    for (int j = 0; j < 4; ++j) {
      int gcol = n0 + wn * 64 + j * 16 + lane15;
      float bs = (EPI == 0) ? 0.f : bias[gcol];
      if (EPI == 1 || EPI == 3) {
        float4 o = make_float4(acc[i][j][0] + bs, acc[i][j][1] + bs,
                               acc[i][j][2] + bs, acc[i][j][3] + bs);
        *(float4*)&((float*)outv)[((size_t)(bq * C_ + gcol) << 10) + nq] = o;
      } else if (EPI == 0) {
        u16x4 pv;
        #pragma unroll
        for (int r = 0; r < 4; ++r) {
          unsigned short hv = f2bf(acc[i][j][r]);
          pv[r] = hv;
          ((unsigned short*)outv)[(size_t)(grow + r) * Nn + gcol] = hv;
        }
        if (gcol >= 1024)
          *(u16x4*)&vtg[((size_t)(bq * C_ + gcol - 1024) << 10) + nq] = pv;
      } else {
        #pragma unroll
        for (int r = 0; r < 4; ++r) {
          float vv = acc[i][j][r] + bs;
          float e = __builtin_amdgcn_exp2f(-(2.302118073f * vv +
                                             0.1029455568f * vv * vv * vv));
          float g = vv * __builtin_amdgcn_rcpf(1.f + e);
          ((unsigned short*)outv)[(size_t)(grow + r) * Nn + gcol] = f2bf(g);
        }
      }
    }
  }
}

// ---------------- flash attention v5: 64 q rows, 128-row K/V staging ----------------
// v3 structure (64 q rows/block, grid 16x8x16) but stages 128 K/V rows per
// iteration: 8 iterations x 2 barriers = half the barrier drains of v3, and
// each staged tile feeds 2x the MFMA per wave. LDS 44KB -> 3 blocks/CU.
__global__ __launch_bounds__(256) void k_flash(const unsigned short* __restrict__ qkv,
    const unsigned short* __restrict__ vtg, const float* __restrict__ lf,
    const float* __restrict__ hf, const float* __restrict__ lgam,
    const float* __restrict__ hgam, unsigned short* __restrict__ y) {
  const int t = threadIdx.x, w = t >> 6, l = t & 63;
  const int lane15 = l & 15, quad = l >> 4;
  const int q0 = blockIdx.x * 64;
  const int h = blockIdx.y, b = blockIdx.z;
  __shared__ __align__(16) unsigned short kt[128 * 72];   // [n 128][d 64] pad 72
  __shared__ __align__(16) unsigned short vt[64 * 136];   // [d 64][n 128] pad 136
  __shared__ __align__(16) unsigned short pl[4][16 * 72];

  // Q fragment pre-scaled by 0.125*log2(e)
  bf16x8 aq0, aq1;
  {
    const unsigned short* qp = qkv + (size_t)(b * N_ + q0 + w * 16 + lane15) * C3_ + h * 64 + quad * 8;
    bf16x8 r0 = *(const bf16x8*)qp;
    bf16x8 r1 = *(const bf16x8*)(qp + 32);
    #pragma unroll
    for (int i = 0; i < 8; ++i) {
      aq0[i] = (short)f2bf(0.1803368801111713f * bf2f((unsigned short)r0[i]));
      aq1[i] = (short)f2bf(0.1803368801111713f * bf2f((unsigned short)r1[i]));
    }
  }
  f32x4 O[4];
  #pragma unroll
  for (int i = 0; i < 4; ++i) O[i] = (f32x4){0.f, 0.f, 0.f, 0.f};
  float lsum = 0.f;

  const int sr = t >> 3;             // 0..31
  const int sc = (t & 7) * 8;        // 0..56
  const unsigned short* kb = qkv + (size_t)(b * N_ + sr) * C3_ + 512 + h * 64 + sc;
  const unsigned short* vb = vtg + (size_t)((b * NH_ + h) * HD_ + sr) * N_ + sc;
  // first tile prefetch (n-block rows 0..127)
  bf16x8 gk0 = *(const bf16x8*)kb;
  bf16x8 gk1 = *(const bf16x8*)(kb + (size_t)32 * C3_);
  bf16x8 gk2 = *(const bf16x8*)(kb + (size_t)64 * C3_);
  bf16x8 gk3 = *(const bf16x8*)(kb + (size_t)96 * C3_);
  bf16x8 gv0 = *(const bf16x8*)vb;
  bf16x8 gv1 = *(const bf16x8*)(vb + 64);
  bf16x8 gv2 = *(const bf16x8*)(vb + 32 * N_);
  bf16x8 gv3 = *(const bf16x8*)(vb + 32 * N_ + 64);

  for (int kti = 0; kti < 8; ++kti) {
    __syncthreads();
    *(bf16x8*)&kt[sr * 72 + sc] = gk0;
    *(bf16x8*)&kt[(sr + 32) * 72 + sc] = gk1;
    *(bf16x8*)&kt[(sr + 64) * 72 + sc] = gk2;
    *(bf16x8*)&kt[(sr + 96) * 72 + sc] = gk3;
    *(bf16x8*)&vt[sr * 136 + sc] = gv0;
    *(bf16x8*)&vt[sr * 136 + 64 + sc] = gv1;
    *(bf16x8*)&vt[(sr + 32) * 136 + sc] = gv2;
    *(bf16x8*)&vt[(sr + 32) * 136 + 64 + sc] = gv3;
    __syncthreads();
    if (kti < 7) {
      const unsigned short* kn = kb + (size_t)((kti + 1) * 128) * C3_;
      const unsigned short* vn = vb + (kti + 1) * 128;
      gk0 = *(const bf16x8*)kn;
      gk1 = *(const bf16x8*)(kn + (size_t)32 * C3_);
      gk2 = *(const bf16x8*)(kn + (size_t)64 * C3_);
      gk3 = *(const bf16x8*)(kn + (size_t)96 * C3_);
      gv0 = *(const bf16x8*)vn;
      gv1 = *(const bf16x8*)(vn + 64);
      gv2 = *(const bf16x8*)(vn + 32 * N_);
      gv3 = *(const bf16x8*)(vn + 32 * N_ + 64);
    }

    #pragma unroll
    for (int half = 0; half < 2; ++half) {
      // S^T: D[n-local][q], n-local in [half*64, half*64+64)
      f32x4 S[4];
      #pragma unroll
      for (int nt = 0; nt < 4; ++nt) {
        const int nrow = half * 64 + nt * 16 + lane15;
        bf16x8 ak0 = *(const bf16x8*)&kt[nrow * 72 + quad * 8];
        bf16x8 ak1 = *(const bf16x8*)&kt[nrow * 72 + 32 + quad * 8];
        f32x4 z = (f32x4){0.f, 0.f, 0.f, 0.f};
        z = __builtin_amdgcn_mfma_f32_16x16x32_bf16(ak0, aq0, z, 0, 0, 0);
        z = __builtin_amdgcn_mfma_f32_16x16x32_bf16(ak1, aq1, z, 0, 0, 0);
        S[nt] = z;
      }
      #pragma unroll
      for (int nt = 0; nt < 4; ++nt)
        #pragma unroll
        for (int r = 0; r < 4; ++r) {
          float pv = __builtin_amdgcn_exp2f(S[nt][r]);
          S[nt][r] = pv;
          lsum += pv;
        }
      #pragma unroll
      for (int nt = 0; nt < 4; ++nt) {
        unsigned lo = __builtin_amdgcn_perm(f2u(S[nt][1]), f2u(S[nt][0]), 0x07060302u);
        unsigned hi = __builtin_amdgcn_perm(f2u(S[nt][3]), f2u(S[nt][2]), 0x07060302u);
        uint2 pk = make_uint2(lo, hi);
        *(uint2*)&pl[w][lane15 * 72 + nt * 16 + quad * 4] = pk;
      }
      #pragma unroll
      for (int nc = 0; nc < 2; ++nc) {
        bf16x8 ap = *(const bf16x8*)&pl[w][lane15 * 72 + nc * 32 + quad * 8];
        #pragma unroll
        for (int dt = 0; dt < 4; ++dt) {
          bf16x8 bv = *(const bf16x8*)&vt[(dt * 16 + lane15) * 136 + half * 64 + nc * 32 + quad * 8];
          O[dt] = __builtin_amdgcn_mfma_f32_16x16x32_bf16(ap, bv, O[dt], 0, 0, 0);
        }
      }
    }
  }

  lsum += __shfl_xor(lsum, 16);
  lsum += __shfl_xor(lsum, 32);
  float inv = 1.f / lsum;
  float invr[4], lfr[4], hfr[4];
  #pragma unroll
  for (int r = 0; r < 4; ++r) {
    invr[r] = __shfl(inv, quad * 4 + r);
    int grow = b * N_ + q0 + w * 16 + quad * 4 + r;
    lfr[r] = lf[grow * 8 + h];
    hfr[r] = hf[grow * 8 + h];
  }
  const size_t rowb = (size_t)(b * N_ + q0 + w * 16 + quad * 4);
  #pragma unroll
  for (int dt = 0; dt < 4; ++dt) {
    int cc = h * 64 + dt * 16 + lane15;
    float lg = lgam[cc], hg = hgam[cc];
    #pragma unroll
    for (int r = 0; r < 4; ++r) {
      float a = O[dt][r] * invr[r];
      float vval = bf2f(qkv[(rowb + r) * C3_ + 1024 + cc]);
      float res = a + a * lfr[r] * lg + hfr[r] * (vval - a) * hg;
      y[(rowb + r) * C_ + cc] = f2bf(res);
    }
  }
}

// ---------------- spatial mean pool per (b,c) row ----------------
__global__ __launch_bounds__(256) void k_pool(const float* __restrict__ feat,
                                              float* __restrict__ pooled) {
  int row = blockIdx.x * 4 + (threadIdx.x >> 6);
  int l = threadIdx.x & 63;
  const float4* p = (const float4*)(feat + (size_t)row * N_);
  float4 a = p[l], b4 = p[l + 64], c4 = p[l + 128], d4 = p[l + 192];
  float s = a.x + a.y + a.z + a.w + b4.x + b4.y + b4.z + b4.w +
            c4.x + c4.y + c4.z + c4.w + d4.x + d4.y + d4.z + d4.w;
  #pragma unroll
  for (int off = 1; off < 64; off <<= 1) s += __shfl_xor(s, off);
  if (l == 0) pooled[row] = s * (1.f / 1024.f);
}

// ---------------- routing: pooled(B,C) -> routing(B,64) ----------------
__global__ __launch_bounds__(256) void k_routing(const float* __restrict__ pooled,
    const float* __restrict__ rw1, const float* __restrict__ rw1s,
    const float* __restrict__ rw1b, const float* __restrict__ rw2,
    float* __restrict__ routing) {
  const int b = blockIdx.x, t = threadIdx.x;
  __shared__ float plds[512];
  __shared__ float tile[64][65];
  __shared__ float hl[64];
  plds[t] = pooled[b * 512 + t];
  plds[t + 256] = pooled[b * 512 + t + 256];
  __syncthreads();
  float acc = 0.f;
  for (int c0 = 0; c0 < 512; c0 += 64) {
    #pragma unroll
    for (int kk = 0; kk < 16; ++kk) {
      int idx = kk * 256 + t;
      tile[idx >> 6][idx & 63] = rw1[(size_t)(idx >> 6) * 512 + c0 + (idx & 63)];
    }
    __syncthreads();
    if (t < 64) {
      #pragma unroll
      for (int i = 0; i < 64; ++i) acc += plds[c0 + i] * tile[t][i];
    }
    __syncthreads();
  }
  if (t < 64) {
    float r = fmaxf(acc, 0.f);
    hl[t] = rw1s[0] * r * r + rw1b[0];
  }
  __syncthreads();
  if (t < 64) {
    float r2 = 0.f;
    #pragma unroll
    for (int j = 0; j < 64; ++j) r2 += hl[j] * rw2[(size_t)t * 64 + j];
    routing[b * 64 + t] = tanhf(r2);
  }
}

// ---------------- per-plane 32x32 rfft2 * dyn -> irfft2 via MFMA ----------------
__global__ __launch_bounds__(256) void k_freq(const float* __restrict__ feat,
    const float* __restrict__ routing, const float* __restrict__ fwtab,
    const unsigned short* __restrict__ gtab, float* __restrict__ enh) {
  const int c = blockIdx.x, b = blockIdx.y, t = threadIdx.x;
  const int g = c >> 5, cc = c & 31;
  const int w = t >> 6, l = t & 63;
  const int lane15 = l & 15, quad = l >> 4;
  const int mt = w & 1, nt = w >> 1;
  __shared__ __align__(16) unsigned short Xbf[32 * 40];
  __shared__ __align__(16) float p[32 * 36];
  __shared__ __align__(16) unsigned short Tabs[6400];
  __shared__ __align__(16) unsigned short pl1r[32 * 40], pl1i[32 * 40];
  __shared__ __align__(16) unsigned short pl2r[32 * 40], pl2i[32 * 40];
  __shared__ __align__(16) unsigned short pl3r[32 * 40], pl3i[32 * 40];
  __shared__ float Ms[1024];
  const size_t base = (size_t)(b * C_ + c) * N_;

  {
    float4 v = ((const float4*)(feat + base))[t];
    int hh = t >> 3, w4 = (t & 7) * 4;
    *(float4*)&p[hh * 36 + w4] = v;
    u16x4 xb = { f2bf(v.x), f2bf(v.y), f2bf(v.z), f2bf(v.w) };
    *(u16x4*)&Xbf[hh * 40 + w4] = xb;
  }
  {
    const uint4* src = (const uint4*)gtab;
    uint4* dst = (uint4*)Tabs;
    #pragma unroll
    for (int k = 0; k < 4; ++k) {
      int o = k * 256 + t;
      if (o < 800) dst[o] = src[o];
    }
  }
  {
    float r0 = routing[b * 64 + g * 4 + 0];
    float r1 = routing[b * 64 + g * 4 + 1];
    float r2 = routing[b * 64 + g * 4 + 2];
    float r3 = routing[b * 64 + g * 4 + 3];
    const float* fb = fwtab + (size_t)cc * 544;
    #pragma unroll
    for (int k = 0; k < 4; ++k) {
      int o = k * 256 + t;
      int fh = o >> 5, fw = o & 31;
      float mv = 0.f;
      if (fw < 17) {
        int fi = fh * 17 + fw;
        mv = (r0 * fb[fi] + r1 * fb[17408 + fi] + r2 * fb[34816 + fi] +
              r3 * fb[52224 + fi]) * (1.f / 1024.f);
      }
      Ms[o] = mv;
    }
  }
  __syncthreads();

  const unsigned short* Tc  = Tabs;
  const unsigned short* Ts  = Tabs + 1280;
  const unsigned short* Tsn = Tabs + 2560;
  const unsigned short* Tcw = Tabs + 3840;
  const unsigned short* Tsw = Tabs + 5120;
  const int arow = (mt * 16 + lane15) * 40 + quad * 8;
  const int brow = (nt * 16 + lane15) * 40 + quad * 8;
  const int prow = (nt * 16 + lane15) * 40 + mt * 16 + quad * 4;
  const f32x4 zz = (f32x4){0.f, 0.f, 0.f, 0.f};

  {
    bf16x8 aX = *(const bf16x8*)&Xbf[arow];
    bf16x8 bC = *(const bf16x8*)&Tc[brow];
    bf16x8 bS = *(const bf16x8*)&Tsn[brow];
    f32x4 re = __builtin_amdgcn_mfma_f32_16x16x32_bf16(aX, bC, zz, 0, 0, 0);
    f32x4 im = __builtin_amdgcn_mfma_f32_16x16x32_bf16(aX, bS, zz, 0, 0, 0);
    uint2 pr = make_uint2(__builtin_amdgcn_perm(f2u(re[1]), f2u(re[0]), 0x07060302u),
                          __builtin_amdgcn_perm(f2u(re[3]), f2u(re[2]), 0x07060302u));
    uint2 pi = make_uint2(__builtin_amdgcn_perm(f2u(im[1]), f2u(im[0]), 0x07060302u),
                          __builtin_amdgcn_perm(f2u(im[3]), f2u(im[2]), 0x07060302u));
    *(uint2*)&pl1r[prow] = pr;
    *(uint2*)&pl1i[prow] = pi;
  }
  __syncthreads();
  {
    bf16x8 aC = *(const bf16x8*)&Tc[arow];
    bf16x8 aS = *(const bf16x8*)&Ts[arow];
    bf16x8 aN = *(const bf16x8*)&Tsn[arow];
    bf16x8 bR = *(const bf16x8*)&pl1r[brow];
    bf16x8 bI = *(const bf16x8*)&pl1i[brow];
    f32x4 er = __builtin_amdgcn_mfma_f32_16x16x32_bf16(aC, bR, zz, 0, 0, 0);
    er = __builtin_amdgcn_mfma_f32_16x16x32_bf16(aS, bI, er, 0, 0, 0);
    f32x4 ei = __builtin_amdgcn_mfma_f32_16x16x32_bf16(aC, bI, zz, 0, 0, 0);
    ei = __builtin_amdgcn_mfma_f32_16x16x32_bf16(aN, bR, ei, 0, 0, 0);
    #pragma unroll
    for (int r = 0; r < 4; ++r) {
      float mk = Ms[(mt * 16 + quad * 4 + r) * 32 + nt * 16 + lane15];
      er[r] *= mk; ei[r] *= mk;
    }
    uint2 pr = make_uint2(__builtin_amdgcn_perm(f2u(er[1]), f2u(er[0]), 0x07060302u),
                          __builtin_amdgcn_perm(f2u(er[3]), f2u(er[2]), 0x07060302u));
    uint2 pi = make_uint2(__builtin_amdgcn_perm(f2u(ei[1]), f2u(ei[0]), 0x07060302u),
                          __builtin_amdgcn_perm(f2u(ei[3]), f2u(ei[2]), 0x07060302u));
    *(uint2*)&pl2r[prow] = pr;
    *(uint2*)&pl2i[prow] = pi;
  }
  __syncthreads();
  {
    bf16x8 aR = *(const bf16x8*)&pl2r[arow];
    bf16x8 aI = *(const bf16x8*)&pl2i[arow];
    bf16x8 bC = *(const bf16x8*)&Tc[brow];
    bf16x8 bS = *(const bf16x8*)&Ts[brow];
    bf16x8 bN = *(const bf16x8*)&Tsn[brow];
    f32x4 zr = __builtin_amdgcn_mfma_f32_16x16x32_bf16(aR, bC, zz, 0, 0, 0);
    zr = __builtin_amdgcn_mfma_f32_16x16x32_bf16(aI, bN, zr, 0, 0, 0);
    f32x4 zi = __builtin_amdgcn_mfma_f32_16x16x32_bf16(aI, bC, zz, 0, 0, 0);
    zi = __builtin_amdgcn_mfma_f32_16x16x32_bf16(aR, bS, zi, 0, 0, 0);
    uint2 pr = make_uint2(__builtin_amdgcn_perm(f2u(zr[1]), f2u(zr[0]), 0x07060302u),
                          __builtin_amdgcn_perm(f2u(zr[3]), f2u(zr[2]), 0x07060302u));
    uint2 pi = make_uint2(__builtin_amdgcn_perm(f2u(zi[1]), f2u(zi[0]), 0x07060302u),
                          __builtin_amdgcn_perm(f2u(zi[3]), f2u(zi[2]), 0x07060302u));
    *(uint2*)&pl3r[prow] = pr;
    *(uint2*)&pl3i[prow] = pi;
  }
  __syncthreads();
  {
    bf16x8 aC = *(const bf16x8*)&Tcw[arow];
    bf16x8 aS = *(const bf16x8*)&Tsw[arow];
    bf16x8 bR = *(const bf16x8*)&pl3r[brow];
    bf16x8 bI = *(const bf16x8*)&pl3i[brow];
    f32x4 y = __builtin_amdgcn_mfma_f32_16x16x32_bf16(aC, bR, zz, 0, 0, 0);
    y = __builtin_amdgcn_mfma_f32_16x16x32_bf16(aS, bI, y, 0, 0, 0);
    int hh = nt * 16 + lane15, w0 = mt * 16 + quad * 4;
    float4 res = *(const float4*)&p[hh * 36 + w0];
    float4 o = make_float4(y[0] + res.x, y[1] + res.y, y[2] + res.z, y[3] + res.w);
    *(float4*)&enh[base + hh * 32 + w0] = o;
  }
}

// ---------------- tokens += gamma * enh^T ----------------
__global__ __launch_bounds__(256) void k_add_t(const float* __restrict__ enh,
    const float* __restrict__ gamma, float* __restrict__ tok) {
  __shared__ float s[32][33];
  const int n0 = blockIdx.x * 32, c0 = blockIdx.y * 32, b = blockIdx.z;
  const int j = threadIdx.x & 31, i0 = threadIdx.x >> 5;
  #pragma unroll
  for (int k = 0; k < 4; ++k) {
    int i = i0 + k * 8;
    s[i][j] = enh[(size_t)(b * C_ + c0 + i) * N_ + n0 + j];
  }
  __syncthreads();
  float gv = gamma[c0 + j];
  #pragma unroll
  for (int k = 0; k < 4; ++k) {
    int i = i0 + k * 8;
    size_t o = (size_t)(b * N_ + n0 + i) * C_ + c0 + j;
    tok[o] += gv * s[j][i];
  }
}

// ---------------- final: out = tokens^T + gamma2 * enh ----------------
__global__ __launch_bounds__(256) void k_final(const float* __restrict__ tok,
    const float* __restrict__ gamma, const float* __restrict__ enh,
    float* __restrict__ out) {
  __shared__ float s[32][33];
  const int n0 = blockIdx.x * 32, c0 = blockIdx.y * 32, b = blockIdx.z;
  const int j = threadIdx.x & 31, i0 = threadIdx.x >> 5;
  #pragma unroll
  for (int k = 0; k < 4; ++k) {
    int i = i0 + k * 8;
    s[i][j] = tok[(size_t)(b * N_ + n0 + i) * C_ + c0 + j];
  }
  __syncthreads();
  #pragma unroll
  for (int k = 0; k < 4; ++k) {
    int i = i0 + k * 8;   // c-local
    size_t o = (size_t)(b * C_ + c0 + i) * N_ + n0 + j;
    out[o] = s[j][i] + gamma[c0 + i] * enh[o];
  }
}

// =============================== launch ===============================
extern "C" void kernel_launch(void* const* d_in, const int* in_sizes, int n_in,
                              void* d_out, int out_size, void* d_ws, size_t ws_size,
                              hipStream_t stream) {
  (void)in_sizes; (void)n_in; (void)out_size; (void)ws_size;
  const float* x      = (const float*)d_in[0];
  const float* n1w    = (const float*)d_in[1];
  const float* n1b    = (const float*)d_in[2];
  const float* qkv_w  = (const float*)d_in[3];
  const float* proj_w = (const float*)d_in[4];
  const float* proj_b = (const float*)d_in[5];
  const float* pa_s   = (const float*)d_in[6];
  const float* pa_b   = (const float*)d_in[7];
  const float* lf_w   = (const float*)d_in[8];
  const float* lf_b   = (const float*)d_in[9];
  const float* hf_w   = (const float*)d_in[10];
  const float* hf_b   = (const float*)d_in[11];
  const float* lf_g   = (const float*)d_in[12];
  const float* hf_g   = (const float*)d_in[13];
  const float* f1rw1w = (const float*)d_in[14];
  const float* f1rw1s = (const float*)d_in[15];
  const float* f1rw1b = (const float*)d_in[16];
  const float* f1rw2w = (const float*)d_in[17];
  const float* f1fw   = (const float*)d_in[18];
  const float* gamma1 = (const float*)d_in[19];
  const float* n2w    = (const float*)d_in[20];
  const float* n2b    = (const float*)d_in[21];
  const float* fc1w   = (const float*)d_in[22];
  const float* fc1b   = (const float*)d_in[23];
  const float* fc2w   = (const float*)d_in[24];
  const float* fc2b   = (const float*)d_in[25];
  const float* f2rw1w = (const float*)d_in[26];
  const float* f2rw1s = (const float*)d_in[27];
  const float* f2rw1b = (const float*)d_in[28];
  const float* f2rw2w = (const float*)d_in[29];
  const float* f2fw   = (const float*)d_in[30];
  const float* gamma2 = (const float*)d_in[31];

  char* ws = (char*)d_ws;
  float*          tokens = (float*)(ws + 0);
  float*          f1buf  = (float*)(ws + 33554432ULL);
  float*          f2buf  = (float*)(ws + 67108864ULL);
  float*          f3buf  = (float*)(ws + 100663296ULL);
  unsigned short* regA   = (unsigned short*)(ws + 134217728ULL);
  unsigned short* abuf   = (unsigned short*)(ws + 201326592ULL);
  float*          lfbuf  = (float*)(ws + 218103808ULL);
  float*          hfbuf  = (float*)(ws + 218628096ULL);
  float*          pooled = (float*)(ws + 219152384ULL);
  float*          routing= (float*)(ws + 219185152ULL);
  unsigned short* wq     = (unsigned short*)(ws + 219189248ULL);
  unsigned short* wp     = (unsigned short*)(ws + 220762112ULL);
  unsigned short* w1     = (unsigned short*)(ws + 221286400ULL);
  unsigned short* w2     = (unsigned short*)(ws + 223383552ULL);
  unsigned short* gtab   = (unsigned short*)(ws + 225480704ULL);
  unsigned short* vtg    = (unsigned short*)f1buf;   // 32 MB region reused for V^T

  // weights -> bf16 (single fused launch), twiddle tables
  k_f2b4<<<12288, 256, 0, stream>>>(qkv_w, wq, proj_w, wp, fc1w, w1, fc2w, w2);
  k_twid<<<25, 256, 0, stream>>>(gtab);

  k_transpose_cn<<<dim3(32, 16, 16), 256, 0, stream>>>(x, tokens);
  k_ln<true><<<4096, 256, 0, stream>>>(tokens, n1w, n1b, lf_w, lf_b, hf_w, hf_b,
                                       pa_s, pa_b, abuf, lfbuf, hfbuf);
  k_gemm<0><<<dim3(12, 128), 256, 0, stream>>>(abuf, wq, n1b, regA, vtg, C3_, C_);
  // flash v5 (64-q tiles, 128-row K/V staging) + fused gates -> abuf bf16
  k_flash<<<dim3(16, 8, 16), 256, 0, stream>>>(regA, vtg, lfbuf, hfbuf, lf_g, hf_g, abuf);
  k_gemm<1><<<dim3(4, 128), 256, 0, stream>>>(abuf, wp, proj_b, f2buf, nullptr, C_, C_);
  k_pool<<<2048, 256, 0, stream>>>(f2buf, pooled);
  k_routing<<<16, 256, 0, stream>>>(pooled, f1rw1w, f1rw1s, f1rw1b, f1rw2w, routing);
  k_freq<<<dim3(512, 16), 256, 0, stream>>>(f2buf, routing, f1fw, gtab, f3buf);
  k_add_t<<<dim3(32, 16, 16), 256, 0, stream>>>(f3buf, gamma1, tokens);
  k_ln<false><<<4096, 256, 0, stream>>>(tokens, n2w, n2b, nullptr, nullptr, nullptr,
                                        nullptr, nullptr, nullptr, abuf, nullptr, nullptr);
  k_gemm<2><<<dim3(16, 128), 256, 0, stream>>>(abuf, w1, fc1b, regA, nullptr, CH_, C_);
  k_gemm<3><<<dim3(4, 128), 256, 0, stream>>>(regA, w2, fc2b, f2buf, nullptr, C_, CH_);
  k_pool<<<2048, 256, 0, stream>>>(f2buf, pooled);
  k_routing<<<16, 256, 0, stream>>>(pooled, f2rw1w, f2rw1s, f2rw1b, f2rw2w, routing);
  k_freq<<<dim3(512, 16), 256, 0, stream>>>(f2buf, routing, f2fw, gtab, f3buf);
  k_final<<<dim3(32, 16, 16), 256, 0, stream>>>(tokens, gamma2, f3buf, (float*)d_out);
}

// Round 8
// 522.325 us; speedup vs baseline: 1.6772x; 1.0508x over previous
//
#include <hip/hip_runtime.h>
#include <cstdint>
#include <cstddef>

#define B_   16
#define C_   512
#define N_   1024
#define M_   (B_*N_)
#define NH_  8
#define HD_  64
#define C3_  1536
#define CH_  2048

typedef __attribute__((ext_vector_type(8))) short bf16x8;
typedef __attribute__((ext_vector_type(4))) float f32x4;
typedef __attribute__((ext_vector_type(4))) unsigned short u16x4;

__device__ __forceinline__ unsigned short f2bf(float f) {
  union { float f; unsigned u; } v; v.f = f;
  unsigned r = v.u + 0x7fffu + ((v.u >> 16) & 1u);
  return (unsigned short)(r >> 16);
}
__device__ __forceinline__ float bf2f(unsigned short h) {
  union { unsigned u; float f; } v; v.u = ((unsigned)h) << 16;
  return v.f;
}
__device__ __forceinline__ unsigned f2u(float f) {
  union { float f; unsigned u; } v; v.f = f; return v.u;
}

// ---------------- fused float -> bf16 conversion for all 4 weight mats ----------------
__global__ __launch_bounds__(256) void k_f2b4(
    const float* __restrict__ s0, unsigned short* __restrict__ d0,
    const float* __restrict__ s1, unsigned short* __restrict__ d1,
    const float* __restrict__ s2, unsigned short* __restrict__ d2,
    const float* __restrict__ s3, unsigned short* __restrict__ d3) {
  int blk = blockIdx.x, t = threadIdx.x;
  const float* s; unsigned short* d; int off;
  if (blk < 3072)      { s = s0; d = d0; off = blk * 256; }
  else if (blk < 4096) { s = s1; d = d1; off = (blk - 3072) * 256; }
  else if (blk < 8192) { s = s2; d = d2; off = (blk - 4096) * 256; }
  else                 { s = s3; d = d3; off = (blk - 8192) * 256; }
  int i = off + t;
  d[i] = f2bf(s[i]);
}

// ---------------- twiddle tables (bf16, stride 40), 5 tables of 32x40 ----------------
__global__ __launch_bounds__(256) void k_twid(unsigned short* __restrict__ gtab) {
  int idx = blockIdx.x * 256 + threadIdx.x;
  if (idx >= 6400) return;
  int tab = idx / 1280, rem = idx % 1280;
  int i = rem / 40, j = rem % 40;
  float v = 0.f;
  if (j < 32) {
    float th = 0.19634954084936207f * (float)((i * j) & 31);
    float s, c;
    __sincosf(th, &s, &c);
    if (tab == 0) v = c;
    else if (tab == 1) v = s;
    else if (tab == 2) v = -s;
    else {
      float wg = (j == 0 || j == 16) ? 1.f : 2.f;
      if (j >= 17) wg = 0.f;
      v = (tab == 3) ? wg * c : -wg * s;
    }
  }
  gtab[idx] = f2bf(v);
}

// ---------------- fused transpose + LayerNorm (+ optional lf/hf gates) ----------------
// Reads src in (B,C,N) f32, LN over C per (b,n) row, writes lnout (M,C) bf16.
// LDS tile [c][n] bf16 stride 34: load-writes and column reads both 2 lanes/bank.
template<bool WITH>
__global__ __launch_bounds__(256) void k_lnt(const float* __restrict__ src,
    const float* __restrict__ w, const float* __restrict__ bia,
    const float* __restrict__ lfw, const float* __restrict__ lfb,
    const float* __restrict__ hfw, const float* __restrict__ hfb,
    const float* __restrict__ pa_s, const float* __restrict__ pa_b,
    unsigned short* __restrict__ lnout, float* __restrict__ lfout,
    float* __restrict__ hfout) {
  __shared__ unsigned short s[512 * 34];
  const int t = threadIdx.x, wv = t >> 6, l = t & 63;
  const int n0 = blockIdx.x * 32, b = blockIdx.y;
  const int cl = t >> 3;
  const int nn = (t & 7) * 4;
  #pragma unroll
  for (int k = 0; k < 16; ++k) {
    int c = k * 32 + cl;
    float4 v = *(const float4*)&src[(size_t)(b * C_ + c) * N_ + n0 + nn];
    s[c * 34 + nn]     = f2bf(v.x);
    s[c * 34 + nn + 1] = f2bf(v.y);
    s[c * 34 + nn + 2] = f2bf(v.z);
    s[c * 34 + nn + 3] = f2bf(v.w);
  }
  __syncthreads();
  float wv8[8], bv8[8];
  #pragma unroll
  for (int k = 0; k < 8; ++k) { wv8[k] = w[l + 64 * k]; bv8[k] = bia[l + 64 * k]; }
  float ps = 1.f, pb = 0.f;
  if (WITH) { ps = pa_s[0]; pb = pa_b[0]; }
  for (int ri = 0; ri < 8; ++ri) {
    const int n = wv * 8 + ri;
    const int row = b * N_ + n0 + n;
    float v[8];
    #pragma unroll
    for (int k = 0; k < 8; ++k) v[k] = bf2f(s[(l + 64 * k) * 34 + n]);
    float sm = 0.f, q = 0.f;
    #pragma unroll
    for (int k = 0; k < 8; ++k) { sm += v[k]; q += v[k] * v[k]; }
    #pragma unroll
    for (int off = 1; off < 64; off <<= 1) { sm += __shfl_xor(sm, off); q += __shfl_xor(q, off); }
    float mu = sm * (1.f / 512.f);
    float var = q * (1.f / 512.f) - mu * mu;
    float rstd = rsqrtf(var + 1e-5f);
    float ln[8];
    #pragma unroll
    for (int k = 0; k < 8; ++k) ln[k] = (v[k] - mu) * rstd * wv8[k] + bv8[k];
    #pragma unroll
    for (int k = 0; k < 8; ++k)
      lnout[(size_t)row * C_ + l + 64 * k] = f2bf(ln[k]);
    if (WITH) {
      float d[8];
      #pragma unroll
      for (int k = 0; k < 8; ++k) { float r = fmaxf(ln[k], 0.f); d[k] = ps * r * r + pb; }
      float lacc[8], hacc[8];
      #pragma unroll
      for (int h = 0; h < 8; ++h) {
        float la = 0.f, ha = 0.f;
        #pragma unroll
        for (int k = 0; k < 8; ++k) {
          la += d[k] * lfw[h * C_ + l + 64 * k];
          ha += d[k] * hfw[h * C_ + l + 64 * k];
        }
        lacc[h] = la; hacc[h] = ha;
      }
      #pragma unroll
      for (int h = 0; h < 8; ++h)
        #pragma unroll
        for (int off = 1; off < 64; off <<= 1) {
          lacc[h] += __shfl_xor(lacc[h], off);
          hacc[h] += __shfl_xor(hacc[h], off);
        }
      float lv = lacc[0], hv = hacc[0];
      #pragma unroll
      for (int h = 1; h < 8; ++h) { if (l == h) { lv = lacc[h]; hv = hacc[h]; } }
      if (l < 8) {
        lfout[(size_t)row * 8 + l] = tanhf(lv + lfb[l]);
        float z = hv + hfb[l];
        float sp = (z > 15.f) ? z : log1pf(__expf(z));
        float s2 = sp * sp;
        hfout[(size_t)row * 8 + l] = 2.f * s2 / (s2 + 0.3678f);
      }
    }
  }
}

// ---------------- GEMM v2: reg-prefetch staging, padded LDS, fused epilogues ----------
template<int EPI>
__global__ __launch_bounds__(256) void k_gemm(const unsigned short* __restrict__ A,
    const unsigned short* __restrict__ Bt, const float* __restrict__ bias,
    void* __restrict__ outv, unsigned short* __restrict__ vtg, int Nn, int K) {
  __shared__ __align__(16) unsigned short Asm[128 * 40];
  __shared__ __align__(16) unsigned short Bsm[128 * 40];
  const int t = threadIdx.x, w = t >> 6, l = t & 63;
  const int lane15 = l & 15, quad = l >> 4;
  const int n0 = blockIdx.x * 128, m0 = blockIdx.y * 128;
  const int wm = w >> 1, wn = w & 1;
  f32x4 acc[4][4];
  #pragma unroll
  for (int i = 0; i < 4; ++i)
    #pragma unroll
    for (int j = 0; j < 4; ++j) acc[i][j] = (f32x4){0.f, 0.f, 0.f, 0.f};
  const int sr = t >> 2, sc = (t & 3) * 8;
  const unsigned short* Ab = A + (size_t)(m0 + sr) * K + sc;
  const unsigned short* Bb = Bt + (size_t)(n0 + sr) * K + sc;
  const size_t rstep = (size_t)64 * K;
  bf16x8 ga0 = *(const bf16x8*)Ab;
  bf16x8 ga1 = *(const bf16x8*)(Ab + rstep);
  bf16x8 gb0 = *(const bf16x8*)Bb;
  bf16x8 gb1 = *(const bf16x8*)(Bb + rstep);
  for (int k0 = 0; k0 < K; k0 += 32) {
    __syncthreads();
    *(bf16x8*)&Asm[sr * 40 + sc] = ga0;
    *(bf16x8*)&Asm[(sr + 64) * 40 + sc] = ga1;
    *(bf16x8*)&Bsm[sr * 40 + sc] = gb0;
    *(bf16x8*)&Bsm[(sr + 64) * 40 + sc] = gb1;
    __syncthreads();
    if (k0 + 32 < K) {
      ga0 = *(const bf16x8*)(Ab + k0 + 32);
      ga1 = *(const bf16x8*)(Ab + rstep + k0 + 32);
      gb0 = *(const bf16x8*)(Bb + k0 + 32);
      gb1 = *(const bf16x8*)(Bb + rstep + k0 + 32);
    }
    bf16x8 af[4], bg[4];
    #pragma unroll
    for (int i = 0; i < 4; ++i)
      af[i] = *(const bf16x8*)&Asm[(wm * 64 + i * 16 + lane15) * 40 + quad * 8];
    #pragma unroll
    for (int i = 0; i < 4; ++i)
      bg[i] = *(const bf16x8*)&Bsm[(wn * 64 + i * 16 + lane15) * 40 + quad * 8];
    #pragma unroll
    for (int i = 0; i < 4; ++i)
      #pragma unroll
      for (int j = 0; j < 4; ++j)
        acc[i][j] = __builtin_amdgcn_mfma_f32_16x16x32_bf16(af[i], bg[j], acc[i][j], 0, 0, 0);
  }
  #pragma unroll
  for (int i = 0; i < 4; ++i) {
    int grow = m0 + wm * 64 + i * 16 + quad * 4;
    int bq = grow >> 10, nq = grow & 1023;
    #pragma unroll
    for (int j = 0; j < 4; ++j) {
      int gcol = n0 + wn * 64 + j * 16 + lane15;
      float bs = (EPI == 0) ? 0.f : bias[gcol];
      if (EPI == 1 || EPI == 3) {
        float4 o = make_float4(acc[i][j][0] + bs, acc[i][j][1] + bs,
                               acc[i][j][2] + bs, acc[i][j][3] + bs);
        *(float4*)&((float*)outv)[((size_t)(bq * C_ + gcol) << 10) + nq] = o;
      } else if (EPI == 0) {
        u16x4 pv;
        #pragma unroll
        for (int r = 0; r < 4; ++r) {
          unsigned short hv = f2bf(acc[i][j][r]);
          pv[r] = hv;
          ((unsigned short*)outv)[(size_t)(grow + r) * Nn + gcol] = hv;
        }
        if (gcol >= 1024)
          *(u16x4*)&vtg[((size_t)(bq * C_ + gcol - 1024) << 10) + nq] = pv;
      } else {
        #pragma unroll
        for (int r = 0; r < 4; ++r) {
          float vv = acc[i][j][r] + bs;
          float e = __builtin_amdgcn_exp2f(-(2.302118073f * vv +
                                             0.1029455568f * vv * vv * vv));
          float g = vv * __builtin_amdgcn_rcpf(1.f + e);
          ((unsigned short*)outv)[(size_t)(grow + r) * Nn + gcol] = f2bf(g);
        }
      }
    }
  }
}

// ---------------- flash attention v5: 64 q rows, 128-row K/V staging ----------------
__global__ __launch_bounds__(256) void k_flash(const unsigned short* __restrict__ qkv,
    const unsigned short* __restrict__ vtg, const float* __restrict__ lf,
    const float* __restrict__ hf, const float* __restrict__ lgam,
    const float* __restrict__ hgam, unsigned short* __restrict__ y) {
  const int t = threadIdx.x, w = t >> 6, l = t & 63;
  const int lane15 = l & 15, quad = l >> 4;
  const int q0 = blockIdx.x * 64;
  const int h = blockIdx.y, b = blockIdx.z;
  __shared__ __align__(16) unsigned short kt[128 * 72];
  __shared__ __align__(16) unsigned short vt[64 * 136];
  __shared__ __align__(16) unsigned short pl[4][16 * 72];

  bf16x8 aq0, aq1;
  {
    const unsigned short* qp = qkv + (size_t)(b * N_ + q0 + w * 16 + lane15) * C3_ + h * 64 + quad * 8;
    bf16x8 r0 = *(const bf16x8*)qp;
    bf16x8 r1 = *(const bf16x8*)(qp + 32);
    #pragma unroll
    for (int i = 0; i < 8; ++i) {
      aq0[i] = (short)f2bf(0.1803368801111713f * bf2f((unsigned short)r0[i]));
      aq1[i] = (short)f2bf(0.1803368801111713f * bf2f((unsigned short)r1[i]));
    }
  }
  f32x4 O[4];
  #pragma unroll
  for (int i = 0; i < 4; ++i) O[i] = (f32x4){0.f, 0.f, 0.f, 0.f};
  float lsum = 0.f;

  const int sr = t >> 3;
  const int sc = (t & 7) * 8;
  const unsigned short* kb = qkv + (size_t)(b * N_ + sr) * C3_ + 512 + h * 64 + sc;
  const unsigned short* vb = vtg + (size_t)((b * NH_ + h) * HD_ + sr) * N_ + sc;
  bf16x8 gk0 = *(const bf16x8*)kb;
  bf16x8 gk1 = *(const bf16x8*)(kb + (size_t)32 * C3_);
  bf16x8 gk2 = *(const bf16x8*)(kb + (size_t)64 * C3_);
  bf16x8 gk3 = *(const bf16x8*)(kb + (size_t)96 * C3_);
  bf16x8 gv0 = *(const bf16x8*)vb;
  bf16x8 gv1 = *(const bf16x8*)(vb + 64);
  bf16x8 gv2 = *(const bf16x8*)(vb + 32 * N_);
  bf16x8 gv3 = *(const bf16x8*)(vb + 32 * N_ + 64);

  for (int kti = 0; kti < 8; ++kti) {
    __syncthreads();
    *(bf16x8*)&kt[sr * 72 + sc] = gk0;
    *(bf16x8*)&kt[(sr + 32) * 72 + sc] = gk1;
    *(bf16x8*)&kt[(sr + 64) * 72 + sc] = gk2;
    *(bf16x8*)&kt[(sr + 96) * 72 + sc] = gk3;
    *(bf16x8*)&vt[sr * 136 + sc] = gv0;
    *(bf16x8*)&vt[sr * 136 + 64 + sc] = gv1;
    *(bf16x8*)&vt[(sr + 32) * 136 + sc] = gv2;
    *(bf16x8*)&vt[(sr + 32) * 136 + 64 + sc] = gv3;
    __syncthreads();
    if (kti < 7) {
      const unsigned short* kn = kb + (size_t)((kti + 1) * 128) * C3_;
      const unsigned short* vn = vb + (kti + 1) * 128;
      gk0 = *(const bf16x8*)kn;
      gk1 = *(const bf16x8*)(kn + (size_t)32 * C3_);
      gk2 = *(const bf16x8*)(kn + (size_t)64 * C3_);
      gk3 = *(const bf16x8*)(kn + (size_t)96 * C3_);
      gv0 = *(const bf16x8*)vn;
      gv1 = *(const bf16x8*)(vn + 64);
      gv2 = *(const bf16x8*)(vn + 32 * N_);
      gv3 = *(const bf16x8*)(vn + 32 * N_ + 64);
    }

    #pragma unroll
    for (int half = 0; half < 2; ++half) {
      f32x4 S[4];
      #pragma unroll
      for (int nt = 0; nt < 4; ++nt) {
        const int nrow = half * 64 + nt * 16 + lane15;
        bf16x8 ak0 = *(const bf16x8*)&kt[nrow * 72 + quad * 8];
        bf16x8 ak1 = *(const bf16x8*)&kt[nrow * 72 + 32 + quad * 8];
        f32x4 z = (f32x4){0.f, 0.f, 0.f, 0.f};
        z = __builtin_amdgcn_mfma_f32_16x16x32_bf16(ak0, aq0, z, 0, 0, 0);
        z = __builtin_amdgcn_mfma_f32_16x16x32_bf16(ak1, aq1, z, 0, 0, 0);
        S[nt] = z;
      }
      #pragma unroll
      for (int nt = 0; nt < 4; ++nt)
        #pragma unroll
        for (int r = 0; r < 4; ++r) {
          float pv = __builtin_amdgcn_exp2f(S[nt][r]);
          S[nt][r] = pv;
          lsum += pv;
        }
      #pragma unroll
      for (int nt = 0; nt < 4; ++nt) {
        unsigned lo = __builtin_amdgcn_perm(f2u(S[nt][1]), f2u(S[nt][0]), 0x07060302u);
        unsigned hi = __builtin_amdgcn_perm(f2u(S[nt][3]), f2u(S[nt][2]), 0x07060302u);
        uint2 pk = make_uint2(lo, hi);
        *(uint2*)&pl[w][lane15 * 72 + nt * 16 + quad * 4] = pk;
      }
      #pragma unroll
      for (int nc = 0; nc < 2; ++nc) {
        bf16x8 ap = *(const bf16x8*)&pl[w][lane15 * 72 + nc * 32 + quad * 8];
        #pragma unroll
        for (int dt = 0; dt < 4; ++dt) {
          bf16x8 bv = *(const bf16x8*)&vt[(dt * 16 + lane15) * 136 + half * 64 + nc * 32 + quad * 8];
          O[dt] = __builtin_amdgcn_mfma_f32_16x16x32_bf16(ap, bv, O[dt], 0, 0, 0);
        }
      }
    }
  }

  lsum += __shfl_xor(lsum, 16);
  lsum += __shfl_xor(lsum, 32);
  float inv = 1.f / lsum;
  float invr[4], lfr[4], hfr[4];
  #pragma unroll
  for (int r = 0; r < 4; ++r) {
    invr[r] = __shfl(inv, quad * 4 + r);
    int grow = b * N_ + q0 + w * 16 + quad * 4 + r;
    lfr[r] = lf[grow * 8 + h];
    hfr[r] = hf[grow * 8 + h];
  }
  const size_t rowb = (size_t)(b * N_ + q0 + w * 16 + quad * 4);
  #pragma unroll
  for (int dt = 0; dt < 4; ++dt) {
    int cc = h * 64 + dt * 16 + lane15;
    float lg = lgam[cc], hg = hgam[cc];
    #pragma unroll
    for (int r = 0; r < 4; ++r) {
      float a = O[dt][r] * invr[r];
      float vval = bf2f(qkv[(rowb + r) * C3_ + 1024 + cc]);
      float res = a + a * lfr[r] * lg + hfr[r] * (vval - a) * hg;
      y[(rowb + r) * C_ + cc] = f2bf(res);
    }
  }
}

// ---------------- spatial mean pool per (b,c) row ----------------
__global__ __launch_bounds__(256) void k_pool(const float* __restrict__ feat,
                                              float* __restrict__ pooled) {
  int row = blockIdx.x * 4 + (threadIdx.x >> 6);
  int l = threadIdx.x & 63;
  const float4* p = (const float4*)(feat + (size_t)row * N_);
  float4 a = p[l], b4 = p[l + 64], c4 = p[l + 128], d4 = p[l + 192];
  float s = a.x + a.y + a.z + a.w + b4.x + b4.y + b4.z + b4.w +
            c4.x + c4.y + c4.z + c4.w + d4.x + d4.y + d4.z + d4.w;
  #pragma unroll
  for (int off = 1; off < 64; off <<= 1) s += __shfl_xor(s, off);
  if (l == 0) pooled[row] = s * (1.f / 1024.f);
}

// ---------------- routing: pooled(B,C) -> routing(B,64) ----------------
__global__ __launch_bounds__(256) void k_routing(const float* __restrict__ pooled,
    const float* __restrict__ rw1, const float* __restrict__ rw1s,
    const float* __restrict__ rw1b, const float* __restrict__ rw2,
    float* __restrict__ routing) {
  const int b = blockIdx.x, t = threadIdx.x;
  __shared__ float plds[512];
  __shared__ float tile[64][65];
  __shared__ float hl[64];
  plds[t] = pooled[b * 512 + t];
  plds[t + 256] = pooled[b * 512 + t + 256];
  __syncthreads();
  float acc = 0.f;
  for (int c0 = 0; c0 < 512; c0 += 64) {
    #pragma unroll
    for (int kk = 0; kk < 16; ++kk) {
      int idx = kk * 256 + t;
      tile[idx >> 6][idx & 63] = rw1[(size_t)(idx >> 6) * 512 + c0 + (idx & 63)];
    }
    __syncthreads();
    if (t < 64) {
      #pragma unroll
      for (int i = 0; i < 64; ++i) acc += plds[c0 + i] * tile[t][i];
    }
    __syncthreads();
  }
  if (t < 64) {
    float r = fmaxf(acc, 0.f);
    hl[t] = rw1s[0] * r * r + rw1b[0];
  }
  __syncthreads();
  if (t < 64) {
    float r2 = 0.f;
    #pragma unroll
    for (int j = 0; j < 64; ++j) r2 += hl[j] * rw2[(size_t)t * 64 + j];
    routing[b * 64 + t] = tanhf(r2);
  }
}

// ---------------- per-plane 32x32 rfft2 * dyn -> irfft2 via MFMA, fused residual ------
// Epilogue: out = res_plane + gamma[c] * (dft_y + feat_plane)   (all B,C,N f32)
__global__ __launch_bounds__(256) void k_freq(const float* __restrict__ feat,
    const float* __restrict__ routing, const float* __restrict__ fwtab,
    const unsigned short* __restrict__ gtab, const float* __restrict__ res,
    const float* __restrict__ gamma, float* __restrict__ outp) {
  const int c = blockIdx.x, b = blockIdx.y, t = threadIdx.x;
  const int g = c >> 5, cc = c & 31;
  const int w = t >> 6, l = t & 63;
  const int lane15 = l & 15, quad = l >> 4;
  const int mt = w & 1, nt = w >> 1;
  __shared__ __align__(16) unsigned short Xbf[32 * 40];
  __shared__ __align__(16) float p[32 * 36];
  __shared__ __align__(16) unsigned short Tabs[6400];
  __shared__ __align__(16) unsigned short pl1r[32 * 40], pl1i[32 * 40];
  __shared__ __align__(16) unsigned short pl2r[32 * 40], pl2i[32 * 40];
  __shared__ __align__(16) unsigned short pl3r[32 * 40], pl3i[32 * 40];
  __shared__ float Ms[1024];
  const size_t base = (size_t)(b * C_ + c) * N_;

  {
    float4 v = ((const float4*)(feat + base))[t];
    int hh = t >> 3, w4 = (t & 7) * 4;
    *(float4*)&p[hh * 36 + w4] = v;
    u16x4 xb = { f2bf(v.x), f2bf(v.y), f2bf(v.z), f2bf(v.w) };
    *(u16x4*)&Xbf[hh * 40 + w4] = xb;
  }
  {
    const uint4* src = (const uint4*)gtab;
    uint4* dst = (uint4*)Tabs;
    #pragma unroll
    for (int k = 0; k < 4; ++k) {
      int o = k * 256 + t;
      if (o < 800) dst[o] = src[o];
    }
  }
  {
    float r0 = routing[b * 64 + g * 4 + 0];
    float r1 = routing[b * 64 + g * 4 + 1];
    float r2 = routing[b * 64 + g * 4 + 2];
    float r3 = routing[b * 64 + g * 4 + 3];
    const float* fb = fwtab + (size_t)cc * 544;
    #pragma unroll
    for (int k = 0; k < 4; ++k) {
      int o = k * 256 + t;
      int fh = o >> 5, fw = o & 31;
      float mv = 0.f;
      if (fw < 17) {
        int fi = fh * 17 + fw;
        mv = (r0 * fb[fi] + r1 * fb[17408 + fi] + r2 * fb[34816 + fi] +
              r3 * fb[52224 + fi]) * (1.f / 1024.f);
      }
      Ms[o] = mv;
    }
  }
  __syncthreads();

  const unsigned short* Tc  = Tabs;
  const unsigned short* Ts  = Tabs + 1280;
  const unsigned short* Tsn = Tabs + 2560;
  const unsigned short* Tcw = Tabs + 3840;
  const unsigned short* Tsw = Tabs + 5120;
  const int arow = (mt * 16 + lane15) * 40 + quad * 8;
  const int brow = (nt * 16 + lane15) * 40 + quad * 8;
  const int prow = (nt * 16 + lane15) * 40 + mt * 16 + quad * 4;
  const f32x4 zz = (f32x4){0.f, 0.f, 0.f, 0.f};

  {
    bf16x8 aX = *(const bf16x8*)&Xbf[arow];
    bf16x8 bC = *(const bf16x8*)&Tc[brow];
    bf16x8 bS = *(const bf16x8*)&Tsn[brow];
    f32x4 re = __builtin_amdgcn_mfma_f32_16x16x32_bf16(aX, bC, zz, 0, 0, 0);
    f32x4 im = __builtin_amdgcn_mfma_f32_16x16x32_bf16(aX, bS, zz, 0, 0, 0);
    uint2 pr = make_uint2(__builtin_amdgcn_perm(f2u(re[1]), f2u(re[0]), 0x07060302u),
                          __builtin_amdgcn_perm(f2u(re[3]), f2u(re[2]), 0x07060302u));
    uint2 pi = make_uint2(__builtin_amdgcn_perm(f2u(im[1]), f2u(im[0]), 0x07060302u),
                          __builtin_amdgcn_perm(f2u(im[3]), f2u(im[2]), 0x07060302u));
    *(uint2*)&pl1r[prow] = pr;
    *(uint2*)&pl1i[prow] = pi;
  }
  __syncthreads();
  {
    bf16x8 aC = *(const bf16x8*)&Tc[arow];
    bf16x8 aS = *(const bf16x8*)&Ts[arow];
    bf16x8 aN = *(const bf16x8*)&Tsn[arow];
    bf16x8 bR = *(const bf16x8*)&pl1r[brow];
    bf16x8 bI = *(const bf16x8*)&pl1i[brow];
    f32x4 er = __builtin_amdgcn_mfma_f32_16x16x32_bf16(aC, bR, zz, 0, 0, 0);
    er = __builtin_amdgcn_mfma_f32_16x16x32_bf16(aS, bI, er, 0, 0, 0);
    f32x4 ei = __builtin_amdgcn_mfma_f32_16x16x32_bf16(aC, bI, zz, 0, 0, 0);
    ei = __builtin_amdgcn_mfma_f32_16x16x32_bf16(aN, bR, ei, 0, 0, 0);
    #pragma unroll
    for (int r = 0; r < 4; ++r) {
      float mk = Ms[(mt * 16 + quad * 4 + r) * 32 + nt * 16 + lane15];
      er[r] *= mk; ei[r] *= mk;
    }
    uint2 pr = make_uint2(__builtin_amdgcn_perm(f2u(er[1]), f2u(er[0]), 0x07060302u),
                          __builtin_amdgcn_perm(f2u(er[3]), f2u(er[2]), 0x07060302u));
    uint2 pi = make_uint2(__builtin_amdgcn_perm(f2u(ei[1]), f2u(ei[0]), 0x07060302u),
                          __builtin_amdgcn_perm(f2u(ei[3]), f2u(ei[2]), 0x07060302u));
    *(uint2*)&pl2r[prow] = pr;
    *(uint2*)&pl2i[prow] = pi;
  }
  __syncthreads();
  {
    bf16x8 aR = *(const bf16x8*)&pl2r[arow];
    bf16x8 aI = *(const bf16x8*)&pl2i[arow];
    bf16x8 bC = *(const bf16x8*)&Tc[brow];
    bf16x8 bS = *(const bf16x8*)&Ts[brow];
    bf16x8 bN = *(const bf16x8*)&Tsn[brow];
    f32x4 zr = __builtin_amdgcn_mfma_f32_16x16x32_bf16(aR, bC, zz, 0, 0, 0);
    zr = __builtin_amdgcn_mfma_f32_16x16x32_bf16(aI, bN, zr, 0, 0, 0);
    f32x4 zi = __builtin_amdgcn_mfma_f32_16x16x32_bf16(aI, bC, zz, 0, 0, 0);
    zi = __builtin_amdgcn_mfma_f32_16x16x32_bf16(aR, bS, zi, 0, 0, 0);
    uint2 pr = make_uint2(__builtin_amdgcn_perm(f2u(zr[1]), f2u(zr[0]), 0x07060302u),
                          __builtin_amdgcn_perm(f2u(zr[3]), f2u(zr[2]), 0x07060302u));
    uint2 pi = make_uint2(__builtin_amdgcn_perm(f2u(zi[1]), f2u(zi[0]), 0x07060302u),
                          __builtin_amdgcn_perm(f2u(zi[3]), f2u(zi[2]), 0x07060302u));
    *(uint2*)&pl3r[prow] = pr;
    *(uint2*)&pl3i[prow] = pi;
  }
  __syncthreads();
  {
    bf16x8 aC = *(const bf16x8*)&Tcw[arow];
    bf16x8 aS = *(const bf16x8*)&Tsw[arow];
    bf16x8 bR = *(const bf16x8*)&pl3r[brow];
    bf16x8 bI = *(const bf16x8*)&pl3i[brow];
    f32x4 y = __builtin_amdgcn_mfma_f32_16x16x32_bf16(aC, bR, zz, 0, 0, 0);
    y = __builtin_amdgcn_mfma_f32_16x16x32_bf16(aS, bI, y, 0, 0, 0);
    int hh = nt * 16 + lane15, w0 = mt * 16 + quad * 4;
    float4 fp = *(const float4*)&p[hh * 36 + w0];
    float4 rp = *(const float4*)&res[base + hh * 32 + w0];
    float gv = gamma[c];
    float4 o = make_float4(rp.x + gv * (y[0] + fp.x), rp.y + gv * (y[1] + fp.y),
                           rp.z + gv * (y[2] + fp.z), rp.w + gv * (y[3] + fp.w));
    *(float4*)&outp[base + hh * 32 + w0] = o;
  }
}

// =============================== launch ===============================
extern "C" void kernel_launch(void* const* d_in, const int* in_sizes, int n_in,
                              void* d_out, int out_size, void* d_ws, size_t ws_size,
                              hipStream_t stream) {
  (void)in_sizes; (void)n_in; (void)out_size; (void)ws_size;
  const float* x      = (const float*)d_in[0];
  const float* n1w    = (const float*)d_in[1];
  const float* n1b    = (const float*)d_in[2];
  const float* qkv_w  = (const float*)d_in[3];
  const float* proj_w = (const float*)d_in[4];
  const float* proj_b = (const float*)d_in[5];
  const float* pa_s   = (const float*)d_in[6];
  const float* pa_b   = (const float*)d_in[7];
  const float* lf_w   = (const float*)d_in[8];
  const float* lf_b   = (const float*)d_in[9];
  const float* hf_w   = (const float*)d_in[10];
  const float* hf_b   = (const float*)d_in[11];
  const float* lf_g   = (const float*)d_in[12];
  const float* hf_g   = (const float*)d_in[13];
  const float* f1rw1w = (const float*)d_in[14];
  const float* f1rw1s = (const float*)d_in[15];
  const float* f1rw1b = (const float*)d_in[16];
  const float* f1rw2w = (const float*)d_in[17];
  const float* f1fw   = (const float*)d_in[18];
  const float* gamma1 = (const float*)d_in[19];
  const float* n2w    = (const float*)d_in[20];
  const float* n2b    = (const float*)d_in[21];
  const float* fc1w   = (const float*)d_in[22];
  const float* fc1b   = (const float*)d_in[23];
  const float* fc2w   = (const float*)d_in[24];
  const float* fc2b   = (const float*)d_in[25];
  const float* f2rw1w = (const float*)d_in[26];
  const float* f2rw1s = (const float*)d_in[27];
  const float* f2rw1b = (const float*)d_in[28];
  const float* f2rw2w = (const float*)d_in[29];
  const float* f2fw   = (const float*)d_in[30];
  const float* gamma2 = (const float*)d_in[31];

  char* ws = (char*)d_ws;
  float*          tokens = (float*)(ws + 0);              // tokens_f1 (B,C,N)
  float*          f1buf  = (float*)(ws + 33554432ULL);
  float*          f2buf  = (float*)(ws + 67108864ULL);
  unsigned short* regA   = (unsigned short*)(ws + 134217728ULL);
  unsigned short* abuf   = (unsigned short*)(ws + 201326592ULL);
  float*          lfbuf  = (float*)(ws + 218103808ULL);
  float*          hfbuf  = (float*)(ws + 218628096ULL);
  float*          pooled = (float*)(ws + 219152384ULL);
  float*          routing= (float*)(ws + 219185152ULL);
  unsigned short* wq     = (unsigned short*)(ws + 219189248ULL);
  unsigned short* wp     = (unsigned short*)(ws + 220762112ULL);
  unsigned short* w1     = (unsigned short*)(ws + 221286400ULL);
  unsigned short* w2     = (unsigned short*)(ws + 223383552ULL);
  unsigned short* gtab   = (unsigned short*)(ws + 225480704ULL);
  unsigned short* vtg    = (unsigned short*)f1buf;

  k_f2b4<<<12288, 256, 0, stream>>>(qkv_w, wq, proj_w, wp, fc1w, w1, fc2w, w2);
  k_twid<<<25, 256, 0, stream>>>(gtab);

  // LN1 fused with transpose (reads x in B,C,N) + gates
  k_lnt<true><<<dim3(32, 16), 256, 0, stream>>>(x, n1w, n1b, lf_w, lf_b, hf_w, hf_b,
                                                pa_s, pa_b, abuf, lfbuf, hfbuf);
  k_gemm<0><<<dim3(12, 128), 256, 0, stream>>>(abuf, wq, n1b, regA, vtg, C3_, C_);
  k_flash<<<dim3(16, 8, 16), 256, 0, stream>>>(regA, vtg, lfbuf, hfbuf, lf_g, hf_g, abuf);
  k_gemm<1><<<dim3(4, 128), 256, 0, stream>>>(abuf, wp, proj_b, f2buf, nullptr, C_, C_);
  k_pool<<<2048, 256, 0, stream>>>(f2buf, pooled);
  k_routing<<<16, 256, 0, stream>>>(pooled, f1rw1w, f1rw1s, f1rw1b, f1rw2w, routing);
  // freq1 + fused residual: tokens = x + gamma1*(dft + feat)
  k_freq<<<dim3(512, 16), 256, 0, stream>>>(f2buf, routing, f1fw, gtab, x, gamma1, tokens);
  // LN2 fused with transpose (reads tokens in B,C,N)
  k_lnt<false><<<dim3(32, 16), 256, 0, stream>>>(tokens, n2w, n2b, nullptr, nullptr,
                                                 nullptr, nullptr, nullptr, nullptr,
                                                 abuf, nullptr, nullptr);
  k_gemm<2><<<dim3(16, 128), 256, 0, stream>>>(abuf, w1, fc1b, regA, nullptr, CH_, C_);
  k_gemm<3><<<dim3(4, 128), 256, 0, stream>>>(regA, w2, fc2b, f2buf, nullptr, C_, CH_);
  k_pool<<<2048, 256, 0, stream>>>(f2buf, pooled);
  k_routing<<<16, 256, 0, stream>>>(pooled, f2rw1w, f2rw1s, f2rw1b, f2rw2w, routing);
  // freq2 + fused residual: out = tokens + gamma2*(dft + feat)
  k_freq<<<dim3(512, 16), 256, 0, stream>>>(f2buf, routing, f2fw, gtab, tokens, gamma2,
                                            (float*)d_out);
}